// Round 3
// baseline (846.571 us; speedup 1.0000x reference)
//
#include <hip/hip_runtime.h>
#include <hip/hip_bf16.h>

// B=4, N=1024, E=256, H=8, D=32. Float tensors may be bf16 OR fp32 in d_in /
// d_out (detected at runtime on-device); adj is int32.
// Output: x_out [4,1024,256] then e_out [4,1024,1024] (element offsets).
//
// ws float offsets:
//   [0 .. 196608)   : 6 weight matrices, transposed, bf16, quad-interleaved
//                     matrix m at ushort offset m*65536; element (e,o) at
//                     ((e>>2)*256 + o)*4 + (e&3).  m: 0=Wcat 1=LIN 2=WQ 3=WK 4=WV 5=WO
#define BIAS_OFF 196608   // lin_b, bq, bk, bv, bo, a1, a2  (7*256 fp32)
#define S1_OFF   198400   // [h][4096]
#define S2_OFF   231168
#define CS_OFF   263936   // 32768: column partial sums+sumsq (reused twice)
#define ST1_OFF  296704   // mean[1024] + inv[1024]
#define ST2_OFF  298752
#define A_OFF    300800   // 4 MB: Wh [h][row][32]  -> later Q [row][256]
#define B_OFF    1349376  // 4 MB: rownorm(xa)      -> later K
#define C_OFF    2397952  // 4 MB: rownorm(lin out) -> later V
#define FLAG_F   3446528  // int: 1 = bf16 tensors, 0 = fp32 tensors
// end 3446529 floats = 13.8 MB

#define NEGC (-9.0e15f)

static __device__ __forceinline__ float bf2f(unsigned short u) {
  union { unsigned int i; float f; } v; v.i = ((unsigned int)u) << 16; return v.f;
}
static __device__ __forceinline__ unsigned short f2bf(float f) {
  union { float f; unsigned int u; } v; v.f = f;
  unsigned int r = (v.u + 0x7FFFu + ((v.u >> 16) & 1u)) >> 16;   // RNE
  return (unsigned short)r;
}
// read element i of a float-tensor input (bf16 or fp32 per flag)
static __device__ __forceinline__ float ldin(const void* p, long i, int bf) {
  return bf ? bf2f(((const unsigned short*)p)[i]) : ((const float*)p)[i];
}
// read element i of a weight input as bf16 bits
static __device__ __forceinline__ unsigned short rdbf(const void* p, long i, int bf) {
  if (bf) return ((const unsigned short*)p)[i];
  return f2bf(((const float*)p)[i]);
}
// store element i of output (bf16 or fp32 per flag)
static __device__ __forceinline__ void stout(void* p, long i, float v, int bf) {
  if (bf) ((unsigned short*)p)[i] = f2bf(v);
  else    ((float*)p)[i] = v;
}

// ---------------- dtype detector -------------------------------------------
__global__ __launch_bounds__(64) void detect_kernel(const unsigned short* x, int* flag) {
  int lane = threadIdx.x;                 // 64 lanes
  unsigned short u = x[2 * lane];         // even ushorts: bf16 elems OR fp32 low halves
  int e = (u >> 7) & 0xFF;
  bool good = (e >= 100 && e <= 140);     // plausible bf16 exponent for N(0,1) data
  unsigned long long m = __ballot(good);
  if (lane == 0) *flag = (__popcll(m) >= 48) ? 1 : 0;
}

// ---------------- prep: weights -> transposed quad bf16; biases -> fp32 ----
__global__ __launch_bounds__(256) void prep_kernel(
    const void* wg, const void* lin_w, const void* inp_w, const void* out_w,
    const void* lin_b, const void* inp_b, const void* out_b,
    const void* a1, const void* a2, float* ws, const int* flagp) {
  const int bf = *flagp;
  unsigned short* wbf = (unsigned short*)ws;
  int t = threadIdx.x;
  int f = blockIdx.x;           // feature index e (row of W^T)
  int m = blockIdx.y;
  int dst = m*65536 + ((f >> 2)*256 + t)*4 + (f & 3);
  if (m == 0) {
    int h = t >> 5, d = t & 31;
    wbf[dst] = rdbf(wg, h*8192 + f*32 + d, bf);   // Wcat[e][h*32+d] = Wg[h][e][d]
  } else if (m == 1) wbf[dst] = rdbf(lin_w, t*256 + f, bf);
  else if (m == 2)   wbf[dst] = rdbf(inp_w, t*256 + f, bf);
  else if (m == 3)   wbf[dst] = rdbf(inp_w, (256 + t)*256 + f, bf);
  else if (m == 4)   wbf[dst] = rdbf(inp_w, (512 + t)*256 + f, bf);
  else if (m == 5)   wbf[dst] = rdbf(out_w, t*256 + f, bf);
  else if (f == 0) {
    ws[BIAS_OFF + t]        = ldin(lin_b, t, bf);
    ws[BIAS_OFF + 256 + t]  = ldin(inp_b, t, bf);
    ws[BIAS_OFF + 512 + t]  = ldin(inp_b, 256 + t, bf);
    ws[BIAS_OFF + 768 + t]  = ldin(inp_b, 512 + t, bf);
    ws[BIAS_OFF + 1024 + t] = ldin(out_b, t, bf);
    ws[BIAS_OFF + 1280 + t] = ldin(a1, t, bf);
    ws[BIAS_OFF + 1536 + t] = ldin(a2, t, bf);
  }
}

// ---------------- Wh = x @ Wcat, plus s1/s2 head reductions ----------------
__global__ __launch_bounds__(256) void whs_kernel(const void* x, float* ws,
                                                  const int* flagp) {
  const int bf = *flagp;
  int t = threadIdx.x;
  int r0 = blockIdx.x * 8;
  __shared__ __align__(16) float U[8][256];
  #pragma unroll
  for (int r = 0; r < 8; ++r)
    U[r][t] = ldin(x, (long)(r0 + r)*256 + t, bf);
  __syncthreads();
  const ushort4* w4 = (const ushort4*)ws;      // matrix 0 (Wcat)
  float acc[8] = {0,0,0,0,0,0,0,0};
  for (int e4 = 0; e4 < 64; ++e4) {
    ushort4 u = w4[e4*256 + t];
    float w0 = bf2f(u.x), w1 = bf2f(u.y), w2 = bf2f(u.z), w3 = bf2f(u.w);
    #pragma unroll
    for (int r = 0; r < 8; ++r) {
      float4 uu = *(const float4*)&U[r][e4*4];
      acc[r] += uu.x*w0 + uu.y*w1 + uu.z*w2 + uu.w*w3;
    }
  }
  int h = t >> 5, d = t & 31;
  float a1v = ws[BIAS_OFF + 1280 + t];
  float a2v = ws[BIAS_OFF + 1536 + t];
  #pragma unroll
  for (int r = 0; r < 8; ++r) {
    int row = r0 + r;
    ws[A_OFF + h*131072 + row*32 + d] = acc[r];
    float p1 = acc[r]*a1v, p2 = acc[r]*a2v;
    #pragma unroll
    for (int off = 16; off > 0; off >>= 1) {
      p1 += __shfl_xor(p1, off, 32);
      p2 += __shfl_xor(p2, off, 32);
    }
    if (d == 0) {
      ws[S1_OFF + h*4096 + row] = p1;
      ws[S2_OFF + h*4096 + row] = p2;
    }
  }
}

// ------- graph attention + residual + fused rownorm; e_out = mean_h attn ---
__global__ __launch_bounds__(256) void attn1_kernel(const void* x, const int* adj,
                                                    float* ws, void* dout,
                                                    const int* flagp) {
  const int bf = *flagp;
  int t = threadIdx.x;
  int b = blockIdx.y;
  int n0 = blockIdx.x * 4;
  __shared__ __align__(16) float Sp[4][1024];
  __shared__ float eacc[4][1024];
  __shared__ float s2s[1024];
  __shared__ unsigned char adjm[4][1024];
  __shared__ float s1s[4];
  __shared__ float hpred[32][32];
  __shared__ __align__(16) float xrow[4][256];
  float* eaccf = &eacc[0][0];
  for (int i = t; i < 4096; i += 256) eaccf[i] = 0.0f;
  for (int r = 0; r < 4; ++r) {
    int base = (b*1024 + n0 + r) * 1024;
    for (int j = 0; j < 4; ++j) {
      int m = t + 256*j;
      adjm[r][m] = (adj[base + m] > 0) ? 1 : 0;
    }
  }
  int w = t >> 6, lane = t & 63;
  for (int h = 0; h < 8; ++h) {
    const float* s2p = ws + S2_OFF + h*4096 + b*1024;
    for (int j = 0; j < 4; ++j) s2s[t + 256*j] = s2p[t + 256*j];
    if (t < 4) s1s[t] = ws[S1_OFF + h*4096 + b*1024 + n0 + t];
    __syncthreads();
    #pragma unroll
    for (int r = 0; r < 4; ++r) {
      float s1v = s1s[r];
      for (int j = 0; j < 4; ++j) {
        int m = t + 256*j;
        float ev = s1v + s2s[m];
        ev = (ev >= 0.0f) ? ev : 0.1f*ev;
        Sp[r][m] = adjm[r][m] ? ev : NEGC;
      }
    }
    __syncthreads();
    float* Sr = Sp[w];            // wave w <-> row w
    float mx = -3.4e38f;
    for (int j = 0; j < 16; ++j) mx = fmaxf(mx, Sr[lane + 64*j]);
    #pragma unroll
    for (int off = 32; off > 0; off >>= 1) mx = fmaxf(mx, __shfl_xor(mx, off));
    float s = 0.0f;
    for (int j = 0; j < 16; ++j) {
      float p = __expf(Sr[lane + 64*j] - mx);
      Sr[lane + 64*j] = p;
      s += p;
    }
    #pragma unroll
    for (int off = 32; off > 0; off >>= 1) s += __shfl_xor(s, off);
    float rs = 1.0f / s;
    for (int j = 0; j < 16; ++j) {
      float p = Sr[lane + 64*j] * rs;
      Sr[lane + 64*j] = p;
      eacc[w][lane + 64*j] += 0.125f * p;
    }
    __syncthreads();
    int d = t & 31, c = t >> 5;
    const float* whp = ws + A_OFF + h*131072 + b*32768;
    float a0 = 0, a1r = 0, a2r = 0, a3r = 0;
    int mbase = c*128;
    for (int mm = 0; mm < 128; ++mm) {
      int m = mbase + mm;
      float wv = whp[m*32 + d];
      a0 += Sp[0][m]*wv; a1r += Sp[1][m]*wv; a2r += Sp[2][m]*wv; a3r += Sp[3][m]*wv;
    }
    hpred[c*4+0][d] = a0;  hpred[c*4+1][d] = a1r;
    hpred[c*4+2][d] = a2r; hpred[c*4+3][d] = a3r;
    __syncthreads();
    if (t < 128) {
      int r = t >> 5, dd = t & 31;
      float sum = 0.0f;
      #pragma unroll
      for (int c8 = 0; c8 < 8; ++c8) sum += hpred[c8*4 + r][dd];
      float hv = (sum >= 0.0f) ? sum : 0.01f*sum;
      long idx = (long)(b*1024 + n0 + r)*256 + h*32 + dd;
      xrow[r][h*32 + dd] = ldin(x, idx, bf) + hv;
    }
    __syncthreads();
  }
  // fused rownorm (ddof=1): wave w handles row w
  float vals[4]; float s = 0.0f;
  #pragma unroll
  for (int j = 0; j < 4; ++j) { vals[j] = xrow[w][lane + 64*j]; s += vals[j]; }
  #pragma unroll
  for (int off = 32; off > 0; off >>= 1) s += __shfl_xor(s, off);
  float mean = s * (1.0f/256.0f);
  float ss = 0.0f;
  #pragma unroll
  for (int j = 0; j < 4; ++j) { float d = vals[j] - mean; ss += d*d; }
  #pragma unroll
  for (int off = 32; off > 0; off >>= 1) ss += __shfl_xor(ss, off);
  float inv = 1.0f / (sqrtf(ss * (1.0f/255.0f)) + 1e-6f);
  float* Bp = ws + B_OFF + (b*1024 + n0 + w)*256;
  #pragma unroll
  for (int j = 0; j < 4; ++j) Bp[lane + 64*j] = (vals[j] - mean) * inv;
  // e_out at element offset 1048576
  for (int r = 0; r < 4; ++r) {
    long base = 1048576L + (long)(b*1024 + n0 + r)*1024;
    for (int j = 0; j < 4; ++j) {
      int m = t + 256*j;
      stout(dout, base + m, eacc[r][m], bf);
    }
  }
}

// ---------------- column (axis=1) stats, ddof=1 ----------------------------
__global__ __launch_bounds__(256) void colstatsA_kernel(const float* in, float* cs) {
  int t = threadIdx.x;
  int j = blockIdx.x & 15;
  int b = blockIdx.x >> 4;
  float s = 0, ss = 0;
  for (int n = j*64; n < j*64 + 64; ++n) {
    float v = in[(b*1024 + n)*256 + t];
    s += v; ss += v*v;
  }
  cs[(b*16 + j)*256 + t] = s;
  cs[16384 + (b*16 + j)*256 + t] = ss;
}

__global__ __launch_bounds__(256) void colstatsB_kernel(const float* cs, float* st) {
  int t = threadIdx.x;
  int b = blockIdx.x;
  float s = 0, ss = 0;
  for (int j = 0; j < 16; ++j) {
    s  += cs[(b*16 + j)*256 + t];
    ss += cs[16384 + (b*16 + j)*256 + t];
  }
  float mean = s * (1.0f/1024.0f);
  float var = fmaxf((ss - s*mean) * (1.0f/1023.0f), 0.0f);
  st[b*256 + t] = mean;
  st[1024 + b*256 + t] = 1.0f / (sqrtf(var) + 1e-6f);
}

// ---------------- row GEMM, bf16 quad weights ------------------------------
// IN_MODE 1: fp32 + colnorm(st); 2: float-input src permuted (n,b,e)->(b,n,e)
// RN 1: fused rownorm (ddof=1) on output
template<int IN_MODE, int RN>
__global__ __launch_bounds__(256) void gemm_kernel(const void* inp,
    const unsigned short* wmat, const float* bias, const float* st, float* outp,
    const int* flagp) {
  const int bf = *flagp;
  int t = threadIdx.x;
  int r0 = blockIdx.x * 8;
  __shared__ __align__(16) float U[8][256];
  #pragma unroll
  for (int r = 0; r < 8; ++r) {
    int row = r0 + r;
    float v;
    if (IN_MODE == 1) {
      int b = row >> 10;
      v = (((const float*)inp)[row*256 + t] - st[b*256 + t]) * st[1024 + b*256 + t];
    } else {
      int b = row >> 10, n = row & 1023;
      v = ldin(inp, (long)(n*4 + b)*256 + t, bf);
    }
    U[r][t] = v;
  }
  __syncthreads();
  float bv = bias[t];
  float acc[8];
  #pragma unroll
  for (int r = 0; r < 8; ++r) acc[r] = bv;
  const ushort4* w4 = (const ushort4*)wmat;
  for (int e4 = 0; e4 < 64; ++e4) {
    ushort4 u = w4[e4*256 + t];
    float w0 = bf2f(u.x), w1 = bf2f(u.y), w2 = bf2f(u.z), w3 = bf2f(u.w);
    #pragma unroll
    for (int r = 0; r < 8; ++r) {
      float4 uu = *(const float4*)&U[r][e4*4];
      acc[r] += uu.x*w0 + uu.y*w1 + uu.z*w2 + uu.w*w3;
    }
  }
  if (RN == 0) {
    #pragma unroll
    for (int r = 0; r < 8; ++r) outp[(r0 + r)*256 + t] = acc[r];
  } else {
    __syncthreads();                 // everyone done reading U
    #pragma unroll
    for (int r = 0; r < 8; ++r) U[r][t] = acc[r];
    __syncthreads();
    int w = t >> 6, lane = t & 63;   // wave w handles rows w and w+4
    for (int rr = w; rr < 8; rr += 4) {
      float vals[4]; float s = 0.0f;
      #pragma unroll
      for (int j = 0; j < 4; ++j) { vals[j] = U[rr][lane + 64*j]; s += vals[j]; }
      #pragma unroll
      for (int off = 32; off > 0; off >>= 1) s += __shfl_xor(s, off);
      float mean = s * (1.0f/256.0f);
      float ss = 0.0f;
      #pragma unroll
      for (int j = 0; j < 4; ++j) { float d = vals[j] - mean; ss += d*d; }
      #pragma unroll
      for (int off = 32; off > 0; off >>= 1) ss += __shfl_xor(ss, off);
      float inv = 1.0f / (sqrtf(ss * (1.0f/255.0f)) + 1e-6f);
      #pragma unroll
      for (int j = 0; j < 4; ++j)
        outp[(r0 + rr)*256 + lane + 64*j] = (vals[j] - mean) * inv;
    }
  }
}

// ---------------- standard MHA + fused out-proj ----------------------------
__global__ __launch_bounds__(256) void attn2_kernel(const float* ws, void* dout,
                                                    const int* flagp) {
  const int bf = *flagp;
  int t = threadIdx.x;
  int b = blockIdx.y;
  int n0 = blockIdx.x * 4;
  __shared__ __align__(16) float Sp[4][1024];
  __shared__ __align__(16) float qs[4][32];
  __shared__ float hpred[32][32];
  __shared__ __align__(16) float orow[4][256];
  const float* q  = ws + A_OFF;
  const float* kk = ws + B_OFF;
  const float* vv = ws + C_OFF;
  int w = t >> 6, lane = t & 63;
  const float scl = 0.17677669529663687f;  // 1/sqrt(32)
  for (int h = 0; h < 8; ++h) {
    if (t < 128) {
      int r = t >> 5, d = t & 31;
      qs[r][d] = q[(b*1024 + n0 + r)*256 + h*32 + d];
    }
    __syncthreads();
    for (int j = 0; j < 4; ++j) {
      int m = t + 256*j;
      const float4* kp = (const float4*)(kk + (b*1024 + m)*256 + h*32);
      float d0 = 0, d1 = 0, d2 = 0, d3 = 0;
      #pragma unroll
      for (int p = 0; p < 8; ++p) {
        float4 kv = kp[p];
        float4 q0 = *(const float4*)&qs[0][p*4];
        float4 q1 = *(const float4*)&qs[1][p*4];
        float4 q2 = *(const float4*)&qs[2][p*4];
        float4 q3 = *(const float4*)&qs[3][p*4];
        d0 += q0.x*kv.x + q0.y*kv.y + q0.z*kv.z + q0.w*kv.w;
        d1 += q1.x*kv.x + q1.y*kv.y + q1.z*kv.z + q1.w*kv.w;
        d2 += q2.x*kv.x + q2.y*kv.y + q2.z*kv.z + q2.w*kv.w;
        d3 += q3.x*kv.x + q3.y*kv.y + q3.z*kv.z + q3.w*kv.w;
      }
      Sp[0][m] = d0*scl; Sp[1][m] = d1*scl; Sp[2][m] = d2*scl; Sp[3][m] = d3*scl;
    }
    __syncthreads();
    float* Sr = Sp[w];
    float mx = -3.4e38f;
    for (int j = 0; j < 16; ++j) mx = fmaxf(mx, Sr[lane + 64*j]);
    #pragma unroll
    for (int off = 32; off > 0; off >>= 1) mx = fmaxf(mx, __shfl_xor(mx, off));
    float s = 0.0f;
    for (int j = 0; j < 16; ++j) {
      float p = __expf(Sr[lane + 64*j] - mx);
      Sr[lane + 64*j] = p;
      s += p;
    }
    #pragma unroll
    for (int off = 32; off > 0; off >>= 1) s += __shfl_xor(s, off);
    float rs = 1.0f / s;
    for (int j = 0; j < 16; ++j) Sr[lane + 64*j] *= rs;
    __syncthreads();
    int d = t & 31, c = t >> 5;
    const float* vp = vv + (b*1024)*256 + h*32;
    float a0 = 0, a1r = 0, a2r = 0, a3r = 0;
    int mbase = c*128;
    for (int mm = 0; mm < 128; ++mm) {
      int m = mbase + mm;
      float wv = vp[m*256 + d];
      a0 += Sp[0][m]*wv; a1r += Sp[1][m]*wv; a2r += Sp[2][m]*wv; a3r += Sp[3][m]*wv;
    }
    hpred[c*4+0][d] = a0;  hpred[c*4+1][d] = a1r;
    hpred[c*4+2][d] = a2r; hpred[c*4+3][d] = a3r;
    __syncthreads();
    if (t < 128) {
      int r = t >> 5, dd = t & 31;
      float sum = 0.0f;
      #pragma unroll
      for (int c8 = 0; c8 < 8; ++c8) sum += hpred[c8*4 + r][dd];
      orow[r][h*32 + dd] = sum;
    }
    __syncthreads();
  }
  // fused out-proj: out[r][t] = bo[t] + sum_f orow[r][f] * WO^T[f][t]
  float o0 = ws[BIAS_OFF + 1024 + t], o1 = o0, o2 = o0, o3 = o0;
  const ushort4* wo4 = (const ushort4*)((const unsigned short*)ws + 5*65536);
  for (int fq = 0; fq < 64; ++fq) {
    ushort4 u = wo4[fq*256 + t];
    float w0 = bf2f(u.x), w1 = bf2f(u.y), w2 = bf2f(u.z), w3 = bf2f(u.w);
    float4 v0 = *(const float4*)&orow[0][fq*4];
    float4 v1 = *(const float4*)&orow[1][fq*4];
    float4 v2 = *(const float4*)&orow[2][fq*4];
    float4 v3 = *(const float4*)&orow[3][fq*4];
    o0 += v0.x*w0 + v0.y*w1 + v0.z*w2 + v0.w*w3;
    o1 += v1.x*w0 + v1.y*w1 + v1.z*w2 + v1.w*w3;
    o2 += v2.x*w0 + v2.y*w1 + v2.z*w2 + v2.w*w3;
    o3 += v3.x*w0 + v3.y*w1 + v3.z*w2 + v3.w*w3;
  }
  stout(dout, (long)(b*1024 + n0 + 0)*256 + t, o0, bf);
  stout(dout, (long)(b*1024 + n0 + 1)*256 + t, o1, bf);
  stout(dout, (long)(b*1024 + n0 + 2)*256 + t, o2, bf);
  stout(dout, (long)(b*1024 + n0 + 3)*256 + t, o3, bf);
}

extern "C" void kernel_launch(void* const* d_in, const int* in_sizes, int n_in,
                              void* d_out, int out_size, void* d_ws, size_t ws_size,
                              hipStream_t stream) {
  const void* x   = d_in[0];
  const void* src = d_in[1];
  const int* adj  = (const int*)d_in[2];
  const void* wg  = d_in[3];
  const void* a1  = d_in[4];
  const void* a2  = d_in[5];
  const void* lw  = d_in[6];
  const void* lb  = d_in[7];
  const void* ipw = d_in[8];
  const void* ipb = d_in[9];
  const void* opw = d_in[10];
  const void* opb = d_in[11];
  float* ws = (float*)d_ws;
  const unsigned short* wbf = (const unsigned short*)d_ws;
  int* flagp = (int*)(ws + FLAG_F);

  detect_kernel<<<1, 64, 0, stream>>>((const unsigned short*)x, flagp);
  prep_kernel<<<dim3(256, 7), 256, 0, stream>>>(wg, lw, ipw, opw, lb, ipb, opb,
                                                a1, a2, ws, flagp);
  whs_kernel<<<512, 256, 0, stream>>>(x, ws, flagp);
  attn1_kernel<<<dim3(256, 4), 256, 0, stream>>>(x, adj, ws, d_out, flagp);
  colstatsA_kernel<<<64, 256, 0, stream>>>(ws + B_OFF, ws + CS_OFF);
  colstatsB_kernel<<<4, 256, 0, stream>>>(ws + CS_OFF, ws + ST1_OFF);
  gemm_kernel<1,1><<<512, 256, 0, stream>>>(ws + B_OFF, wbf + 1*65536,
      ws + BIAS_OFF, ws + ST1_OFF, ws + C_OFF, flagp);
  colstatsA_kernel<<<64, 256, 0, stream>>>(ws + C_OFF, ws + CS_OFF);
  colstatsB_kernel<<<4, 256, 0, stream>>>(ws + CS_OFF, ws + ST2_OFF);
  gemm_kernel<1,0><<<512, 256, 0, stream>>>(ws + C_OFF, wbf + 2*65536,
      ws + BIAS_OFF + 256, ws + ST2_OFF, ws + A_OFF, flagp);   // Q
  gemm_kernel<1,0><<<512, 256, 0, stream>>>(ws + C_OFF, wbf + 3*65536,
      ws + BIAS_OFF + 512, ws + ST2_OFF, ws + B_OFF, flagp);   // K
  gemm_kernel<2,0><<<512, 256, 0, stream>>>(src, wbf + 4*65536,
      ws + BIAS_OFF + 768, nullptr, ws + C_OFF, flagp);        // V
  attn2_kernel<<<dim3(256, 4), 256, 0, stream>>>(ws, d_out, flagp);
}

// Round 4
// 824.035 us; speedup vs baseline: 1.0273x; 1.0273x over previous
//
#include <hip/hip_runtime.h>
#include <hip/hip_bf16.h>

// B=4, N=1024, E=256, H=8, D=32. Float tensors may be bf16 OR fp32 in d_in /
// d_out (detected at runtime on-device); adj is int32.
// Output: x_out [4,1024,256] then e_out [4,1024,1024] (element offsets).
//
// ws float offsets:
//   [0 .. 196608)   : 6 weight matrices, transposed, bf16, quad-interleaved
//                     matrix m at ushort offset m*65536; element (e,o) at
//                     ((e>>2)*256 + o)*4 + (e&3).  m: 0=Wcat 1=LIN 2=WQ 3=WK 4=WV 5=WO
#define BIAS_OFF 196608   // lin_b, bq, bk, bv, bo, a1, a2  (7*256 fp32)
#define S1_OFF   198400   // [h][4096]
#define S2_OFF   231168
#define CS_OFF   263936   // 32768: column partial sums+sumsq (reused twice)
#define ST1_OFF  296704   // mean[1024] + inv[1024]
#define ST2_OFF  298752
#define A_OFF    300800   // 4 MB: Wh [h][row][32]  -> later Q [row][256] -> o
#define B_OFF    1349376  // 4 MB: rownorm(xa)      -> later K
#define C_OFF    2397952  // 4 MB: rownorm(lin out) -> later V
#define FLAG_F   3446528  // int: 1 = bf16 tensors, 0 = fp32 tensors
// end 3446529 floats = 13.8 MB

#define NEGC (-9.0e15f)

static __device__ __forceinline__ float bf2f(unsigned short u) {
  union { unsigned int i; float f; } v; v.i = ((unsigned int)u) << 16; return v.f;
}
static __device__ __forceinline__ unsigned short f2bf(float f) {
  union { float f; unsigned int u; } v; v.f = f;
  unsigned int r = (v.u + 0x7FFFu + ((v.u >> 16) & 1u)) >> 16;   // RNE
  return (unsigned short)r;
}
static __device__ __forceinline__ float ldin(const void* p, long i, int bf) {
  return bf ? bf2f(((const unsigned short*)p)[i]) : ((const float*)p)[i];
}
static __device__ __forceinline__ unsigned short rdbf(const void* p, long i, int bf) {
  if (bf) return ((const unsigned short*)p)[i];
  return f2bf(((const float*)p)[i]);
}
static __device__ __forceinline__ void stout(void* p, long i, float v, int bf) {
  if (bf) ((unsigned short*)p)[i] = f2bf(v);
  else    ((float*)p)[i] = v;
}

// ---------------- dtype detector -------------------------------------------
__global__ __launch_bounds__(64) void detect_kernel(const unsigned short* x, int* flag) {
  int lane = threadIdx.x;
  unsigned short u = x[2 * lane];
  int e = (u >> 7) & 0xFF;
  bool good = (e >= 100 && e <= 140);
  unsigned long long m = __ballot(good);
  if (lane == 0) *flag = (__popcll(m) >= 48) ? 1 : 0;
}

// ---------------- prep: weights -> transposed quad bf16; biases -> fp32 ----
__global__ __launch_bounds__(256) void prep_kernel(
    const void* wg, const void* lin_w, const void* inp_w, const void* out_w,
    const void* lin_b, const void* inp_b, const void* out_b,
    const void* a1, const void* a2, float* ws, const int* flagp) {
  const int bf = *flagp;
  unsigned short* wbf = (unsigned short*)ws;
  int t = threadIdx.x;
  int f = blockIdx.x;
  int m = blockIdx.y;
  int dst = m*65536 + ((f >> 2)*256 + t)*4 + (f & 3);
  if (m == 0) {
    int h = t >> 5, d = t & 31;
    wbf[dst] = rdbf(wg, h*8192 + f*32 + d, bf);
  } else if (m == 1) wbf[dst] = rdbf(lin_w, t*256 + f, bf);
  else if (m == 2)   wbf[dst] = rdbf(inp_w, t*256 + f, bf);
  else if (m == 3)   wbf[dst] = rdbf(inp_w, (256 + t)*256 + f, bf);
  else if (m == 4)   wbf[dst] = rdbf(inp_w, (512 + t)*256 + f, bf);
  else if (m == 5)   wbf[dst] = rdbf(out_w, t*256 + f, bf);
  else if (f == 0) {
    ws[BIAS_OFF + t]        = ldin(lin_b, t, bf);
    ws[BIAS_OFF + 256 + t]  = ldin(inp_b, t, bf);
    ws[BIAS_OFF + 512 + t]  = ldin(inp_b, 256 + t, bf);
    ws[BIAS_OFF + 768 + t]  = ldin(inp_b, 512 + t, bf);
    ws[BIAS_OFF + 1024 + t] = ldin(out_b, t, bf);
    ws[BIAS_OFF + 1280 + t] = ldin(a1, t, bf);
    ws[BIAS_OFF + 1536 + t] = ldin(a2, t, bf);
  }
}

// ---------------- Wh = x @ Wcat, plus s1/s2 head reductions ----------------
__global__ __launch_bounds__(256) void whs_kernel(const void* x, float* ws,
                                                  const int* flagp) {
  const int bf = *flagp;
  int t = threadIdx.x;
  int r0 = blockIdx.x * 8;
  __shared__ __align__(16) float U[8][256];
  #pragma unroll
  for (int r = 0; r < 8; ++r)
    U[r][t] = ldin(x, (long)(r0 + r)*256 + t, bf);
  __syncthreads();
  const ushort4* w4 = (const ushort4*)ws;
  float acc[8] = {0,0,0,0,0,0,0,0};
  for (int e4 = 0; e4 < 64; ++e4) {
    ushort4 u = w4[e4*256 + t];
    float w0 = bf2f(u.x), w1 = bf2f(u.y), w2 = bf2f(u.z), w3 = bf2f(u.w);
    #pragma unroll
    for (int r = 0; r < 8; ++r) {
      float4 uu = *(const float4*)&U[r][e4*4];
      acc[r] += uu.x*w0 + uu.y*w1 + uu.z*w2 + uu.w*w3;
    }
  }
  int h = t >> 5, d = t & 31;
  float a1v = ws[BIAS_OFF + 1280 + t];
  float a2v = ws[BIAS_OFF + 1536 + t];
  #pragma unroll
  for (int r = 0; r < 8; ++r) {
    int row = r0 + r;
    ws[A_OFF + h*131072 + row*32 + d] = acc[r];
    float p1 = acc[r]*a1v, p2 = acc[r]*a2v;
    #pragma unroll
    for (int off = 16; off > 0; off >>= 1) {
      p1 += __shfl_xor(p1, off, 32);
      p2 += __shfl_xor(p2, off, 32);
    }
    if (d == 0) {
      ws[S1_OFF + h*4096 + row] = p1;
      ws[S2_OFF + h*4096 + row] = p2;
    }
  }
}

// ------- graph attention + residual + fused rownorm; e_out = mean_h attn ---
__global__ __launch_bounds__(256) void attn1_kernel(const void* x, const int* adj,
                                                    float* ws, void* dout,
                                                    const int* flagp) {
  const int bf = *flagp;
  int t = threadIdx.x;
  int b = blockIdx.y;
  int n0 = blockIdx.x * 4;
  __shared__ __align__(16) float Sp[4][1024];
  __shared__ float eacc[4][1024];
  __shared__ float s2s[1024];
  __shared__ unsigned char adjm[4][1024];
  __shared__ float s1s[4];
  __shared__ float hpred[32][32];
  __shared__ __align__(16) float xrow[4][256];
  float* eaccf = &eacc[0][0];
  for (int i = t; i < 4096; i += 256) eaccf[i] = 0.0f;
  for (int r = 0; r < 4; ++r) {
    int base = (b*1024 + n0 + r) * 1024;
    for (int j = 0; j < 4; ++j) {
      int m = t + 256*j;
      adjm[r][m] = (adj[base + m] > 0) ? 1 : 0;
    }
  }
  int w = t >> 6, lane = t & 63;
  for (int h = 0; h < 8; ++h) {
    const float* s2p = ws + S2_OFF + h*4096 + b*1024;
    for (int j = 0; j < 4; ++j) s2s[t + 256*j] = s2p[t + 256*j];
    if (t < 4) s1s[t] = ws[S1_OFF + h*4096 + b*1024 + n0 + t];
    __syncthreads();
    #pragma unroll
    for (int r = 0; r < 4; ++r) {
      float s1v = s1s[r];
      for (int j = 0; j < 4; ++j) {
        int m = t + 256*j;
        float ev = s1v + s2s[m];
        ev = (ev >= 0.0f) ? ev : 0.1f*ev;
        Sp[r][m] = adjm[r][m] ? ev : NEGC;
      }
    }
    __syncthreads();
    float* Sr = Sp[w];
    float mx = -3.4e38f;
    for (int j = 0; j < 16; ++j) mx = fmaxf(mx, Sr[lane + 64*j]);
    #pragma unroll
    for (int off = 32; off > 0; off >>= 1) mx = fmaxf(mx, __shfl_xor(mx, off));
    float s = 0.0f;
    for (int j = 0; j < 16; ++j) {
      float p = __expf(Sr[lane + 64*j] - mx);
      Sr[lane + 64*j] = p;
      s += p;
    }
    #pragma unroll
    for (int off = 32; off > 0; off >>= 1) s += __shfl_xor(s, off);
    float rs = 1.0f / s;
    for (int j = 0; j < 16; ++j) {
      float p = Sr[lane + 64*j] * rs;
      Sr[lane + 64*j] = p;
      eacc[w][lane + 64*j] += 0.125f * p;
    }
    __syncthreads();
    int d = t & 31, c = t >> 5;
    const float* whp = ws + A_OFF + h*131072 + b*32768;
    float a0 = 0, a1r = 0, a2r = 0, a3r = 0;
    int mbase = c*128;
    #pragma unroll 4
    for (int mm = 0; mm < 128; ++mm) {
      int m = mbase + mm;
      float wv = whp[m*32 + d];
      a0 += Sp[0][m]*wv; a1r += Sp[1][m]*wv; a2r += Sp[2][m]*wv; a3r += Sp[3][m]*wv;
    }
    hpred[c*4+0][d] = a0;  hpred[c*4+1][d] = a1r;
    hpred[c*4+2][d] = a2r; hpred[c*4+3][d] = a3r;
    __syncthreads();
    if (t < 128) {
      int r = t >> 5, dd = t & 31;
      float sum = 0.0f;
      #pragma unroll
      for (int c8 = 0; c8 < 8; ++c8) sum += hpred[c8*4 + r][dd];
      float hv = (sum >= 0.0f) ? sum : 0.01f*sum;
      long idx = (long)(b*1024 + n0 + r)*256 + h*32 + dd;
      xrow[r][h*32 + dd] = ldin(x, idx, bf) + hv;
    }
    __syncthreads();
  }
  // fused rownorm (ddof=1): wave w handles row w
  float vals[4]; float s = 0.0f;
  #pragma unroll
  for (int j = 0; j < 4; ++j) { vals[j] = xrow[w][lane + 64*j]; s += vals[j]; }
  #pragma unroll
  for (int off = 32; off > 0; off >>= 1) s += __shfl_xor(s, off);
  float mean = s * (1.0f/256.0f);
  float ss = 0.0f;
  #pragma unroll
  for (int j = 0; j < 4; ++j) { float d = vals[j] - mean; ss += d*d; }
  #pragma unroll
  for (int off = 32; off > 0; off >>= 1) ss += __shfl_xor(ss, off);
  float inv = 1.0f / (sqrtf(ss * (1.0f/255.0f)) + 1e-6f);
  float* Bp = ws + B_OFF + (b*1024 + n0 + w)*256;
  #pragma unroll
  for (int j = 0; j < 4; ++j) Bp[lane + 64*j] = (vals[j] - mean) * inv;
  for (int r = 0; r < 4; ++r) {
    long base = 1048576L + (long)(b*1024 + n0 + r)*1024;
    for (int j = 0; j < 4; ++j) {
      int m = t + 256*j;
      stout(dout, base + m, eacc[r][m], bf);
    }
  }
}

// ---------------- column (axis=1) stats, ddof=1 ----------------------------
__global__ __launch_bounds__(256) void colstatsA_kernel(const float* in, float* cs) {
  int t = threadIdx.x;
  int j = blockIdx.x & 15;
  int b = blockIdx.x >> 4;
  float s = 0, ss = 0;
  for (int n = j*64; n < j*64 + 64; ++n) {
    float v = in[(b*1024 + n)*256 + t];
    s += v; ss += v*v;
  }
  cs[(b*16 + j)*256 + t] = s;
  cs[16384 + (b*16 + j)*256 + t] = ss;
}

__global__ __launch_bounds__(256) void colstatsB_kernel(const float* cs, float* st) {
  int t = threadIdx.x;
  int b = blockIdx.x;
  float s = 0, ss = 0;
  for (int j = 0; j < 16; ++j) {
    s  += cs[(b*16 + j)*256 + t];
    ss += cs[16384 + (b*16 + j)*256 + t];
  }
  float mean = s * (1.0f/1024.0f);
  float var = fmaxf((ss - s*mean) * (1.0f/1023.0f), 0.0f);
  st[b*256 + t] = mean;
  st[1024 + b*256 + t] = 1.0f / (sqrtf(var) + 1e-6f);
}

// ---------------- row GEMM, bf16 quad weights ------------------------------
// IN_MODE 0: plain fp32; 1: fp32 + colnorm(st); 2: float-input src permuted
// RN 1: fused rownorm on output.  OUT 1: store to d_out (dtype per flag)
template<int IN_MODE, int RN, int OUT>
__global__ __launch_bounds__(256) void gemm_kernel(const void* inp,
    const unsigned short* wmat, const float* bias, const float* st, void* outp,
    const int* flagp) {
  const int bf = *flagp;
  int t = threadIdx.x;
  int r0 = blockIdx.x * 8;
  __shared__ __align__(16) float U[8][256];
  #pragma unroll
  for (int r = 0; r < 8; ++r) {
    int row = r0 + r;
    float v;
    if (IN_MODE == 0) {
      v = ((const float*)inp)[row*256 + t];
    } else if (IN_MODE == 1) {
      int b = row >> 10;
      v = (((const float*)inp)[row*256 + t] - st[b*256 + t]) * st[1024 + b*256 + t];
    } else {
      int b = row >> 10, n = row & 1023;
      v = ldin(inp, (long)(n*4 + b)*256 + t, bf);
    }
    U[r][t] = v;
  }
  __syncthreads();
  float bv = bias[t];
  float acc[8];
  #pragma unroll
  for (int r = 0; r < 8; ++r) acc[r] = bv;
  const ushort4* w4 = (const ushort4*)wmat;
  for (int e4 = 0; e4 < 64; ++e4) {
    ushort4 u = w4[e4*256 + t];
    float w0 = bf2f(u.x), w1 = bf2f(u.y), w2 = bf2f(u.z), w3 = bf2f(u.w);
    #pragma unroll
    for (int r = 0; r < 8; ++r) {
      float4 uu = *(const float4*)&U[r][e4*4];
      acc[r] += uu.x*w0 + uu.y*w1 + uu.z*w2 + uu.w*w3;
    }
  }
  if (RN == 0) {
    #pragma unroll
    for (int r = 0; r < 8; ++r) {
      if (OUT == 0) ((float*)outp)[(r0 + r)*256 + t] = acc[r];
      else stout(outp, (long)(r0 + r)*256 + t, acc[r], bf);
    }
  } else {
    __syncthreads();
    #pragma unroll
    for (int r = 0; r < 8; ++r) U[r][t] = acc[r];
    __syncthreads();
    int w = t >> 6, lane = t & 63;
    for (int rr = w; rr < 8; rr += 4) {
      float vals[4]; float s = 0.0f;
      #pragma unroll
      for (int j = 0; j < 4; ++j) { vals[j] = U[rr][lane + 64*j]; s += vals[j]; }
      #pragma unroll
      for (int off = 32; off > 0; off >>= 1) s += __shfl_xor(s, off);
      float mean = s * (1.0f/256.0f);
      float ss = 0.0f;
      #pragma unroll
      for (int j = 0; j < 4; ++j) { float d = vals[j] - mean; ss += d*d; }
      #pragma unroll
      for (int off = 32; off > 0; off >>= 1) ss += __shfl_xor(ss, off);
      float inv = 1.0f / (sqrtf(ss * (1.0f/255.0f)) + 1e-6f);
      #pragma unroll
      for (int j = 0; j < 4; ++j)
        ((float*)outp)[(r0 + rr)*256 + lane + 64*j] = (vals[j] - mean) * inv;
    }
  }
}

// ---------------- standard MHA, one block per (4 q-rows, batch, head) ------
// Writes o in-place over this block's own q slots (exclusive ownership).
__global__ __launch_bounds__(256) void attn2_kernel(float* ws) {
  int t = threadIdx.x;
  int b = blockIdx.y;
  int h = blockIdx.z;
  int n0 = blockIdx.x * 4;
  __shared__ __align__(16) float Sp[4][1024];
  __shared__ __align__(16) float qs[4][32];
  __shared__ float hpred[32][32];
  float* qq = ws + A_OFF;                 // q, overwritten by o at the end
  const float* kk = ws + B_OFF;
  const float* vv = ws + C_OFF;
  int w = t >> 6, lane = t & 63;
  const float scl = 0.17677669529663687f; // 1/sqrt(32)
  if (t < 128) {
    int r = t >> 5, d = t & 31;
    qs[r][d] = qq[(b*1024 + n0 + r)*256 + h*32 + d];
  }
  __syncthreads();
  #pragma unroll
  for (int j = 0; j < 4; ++j) {
    int m = t + 256*j;
    const float4* kp = (const float4*)(kk + (b*1024 + m)*256 + h*32);
    float d0 = 0, d1 = 0, d2 = 0, d3 = 0;
    #pragma unroll
    for (int p = 0; p < 8; ++p) {
      float4 kv = kp[p];
      float4 q0 = *(const float4*)&qs[0][p*4];
      float4 q1 = *(const float4*)&qs[1][p*4];
      float4 q2 = *(const float4*)&qs[2][p*4];
      float4 q3 = *(const float4*)&qs[3][p*4];
      d0 += q0.x*kv.x + q0.y*kv.y + q0.z*kv.z + q0.w*kv.w;
      d1 += q1.x*kv.x + q1.y*kv.y + q1.z*kv.z + q1.w*kv.w;
      d2 += q2.x*kv.x + q2.y*kv.y + q2.z*kv.z + q2.w*kv.w;
      d3 += q3.x*kv.x + q3.y*kv.y + q3.z*kv.z + q3.w*kv.w;
    }
    Sp[0][m] = d0*scl; Sp[1][m] = d1*scl; Sp[2][m] = d2*scl; Sp[3][m] = d3*scl;
  }
  __syncthreads();
  float* Sr = Sp[w];
  float mx = -3.4e38f;
  #pragma unroll
  for (int j = 0; j < 16; ++j) mx = fmaxf(mx, Sr[lane + 64*j]);
  #pragma unroll
  for (int off = 32; off > 0; off >>= 1) mx = fmaxf(mx, __shfl_xor(mx, off));
  float s = 0.0f;
  #pragma unroll
  for (int j = 0; j < 16; ++j) {
    float p = __expf(Sr[lane + 64*j] - mx);
    Sr[lane + 64*j] = p;
    s += p;
  }
  #pragma unroll
  for (int off = 32; off > 0; off >>= 1) s += __shfl_xor(s, off);
  float rs = 1.0f / s;
  #pragma unroll
  for (int j = 0; j < 16; ++j) Sr[lane + 64*j] *= rs;
  __syncthreads();
  int d = t & 31, c = t >> 5;
  const float* vp = vv + (b*1024)*256 + h*32;
  float a0 = 0, a1r = 0, a2r = 0, a3r = 0;
  int mbase = c*128;
  #pragma unroll 4
  for (int mm = 0; mm < 128; ++mm) {
    int m = mbase + mm;
    float wv = vp[m*256 + d];
    a0 += Sp[0][m]*wv; a1r += Sp[1][m]*wv; a2r += Sp[2][m]*wv; a3r += Sp[3][m]*wv;
  }
  hpred[c*4+0][d] = a0;  hpred[c*4+1][d] = a1r;
  hpred[c*4+2][d] = a2r; hpred[c*4+3][d] = a3r;
  __syncthreads();
  if (t < 128) {
    int r = t >> 5, dd = t & 31;
    float sum = 0.0f;
    #pragma unroll
    for (int c8 = 0; c8 < 8; ++c8) sum += hpred[c8*4 + r][dd];
    qq[(b*1024 + n0 + r)*256 + h*32 + dd] = sum;   // o over q (own slots)
  }
}

extern "C" void kernel_launch(void* const* d_in, const int* in_sizes, int n_in,
                              void* d_out, int out_size, void* d_ws, size_t ws_size,
                              hipStream_t stream) {
  const void* x   = d_in[0];
  const void* src = d_in[1];
  const int* adj  = (const int*)d_in[2];
  const void* wg  = d_in[3];
  const void* a1  = d_in[4];
  const void* a2  = d_in[5];
  const void* lw  = d_in[6];
  const void* lb  = d_in[7];
  const void* ipw = d_in[8];
  const void* ipb = d_in[9];
  const void* opw = d_in[10];
  const void* opb = d_in[11];
  float* ws = (float*)d_ws;
  const unsigned short* wbf = (const unsigned short*)d_ws;
  int* flagp = (int*)(ws + FLAG_F);

  detect_kernel<<<1, 64, 0, stream>>>((const unsigned short*)x, flagp);
  prep_kernel<<<dim3(256, 7), 256, 0, stream>>>(wg, lw, ipw, opw, lb, ipb, opb,
                                                a1, a2, ws, flagp);
  whs_kernel<<<512, 256, 0, stream>>>(x, ws, flagp);
  attn1_kernel<<<dim3(256, 4), 256, 0, stream>>>(x, adj, ws, d_out, flagp);
  colstatsA_kernel<<<64, 256, 0, stream>>>(ws + B_OFF, ws + CS_OFF);
  colstatsB_kernel<<<4, 256, 0, stream>>>(ws + CS_OFF, ws + ST1_OFF);
  gemm_kernel<1,1,0><<<512, 256, 0, stream>>>(ws + B_OFF, wbf + 1*65536,
      ws + BIAS_OFF, ws + ST1_OFF, ws + C_OFF, flagp);
  colstatsA_kernel<<<64, 256, 0, stream>>>(ws + C_OFF, ws + CS_OFF);
  colstatsB_kernel<<<4, 256, 0, stream>>>(ws + CS_OFF, ws + ST2_OFF);
  gemm_kernel<1,0,0><<<512, 256, 0, stream>>>(ws + C_OFF, wbf + 2*65536,
      ws + BIAS_OFF + 256, ws + ST2_OFF, ws + A_OFF, flagp);   // Q
  gemm_kernel<1,0,0><<<512, 256, 0, stream>>>(ws + C_OFF, wbf + 3*65536,
      ws + BIAS_OFF + 512, ws + ST2_OFF, ws + B_OFF, flagp);   // K
  gemm_kernel<2,0,0><<<512, 256, 0, stream>>>(src, wbf + 4*65536,
      ws + BIAS_OFF + 768, nullptr, ws + C_OFF, flagp);        // V
  attn2_kernel<<<dim3(256, 4, 8), 256, 0, stream>>>(ws);       // o -> A_OFF
  gemm_kernel<0,0,1><<<512, 256, 0, stream>>>(ws + A_OFF, wbf + 5*65536,
      ws + BIAS_OFF + 1024, nullptr, d_out, flagp);            // out-proj
}

// Round 5
// 807.236 us; speedup vs baseline: 1.0487x; 1.0208x over previous
//
#include <hip/hip_runtime.h>
#include <hip/hip_bf16.h>

// B=4, N=1024, E=256, H=8, D=32. Float tensors may be bf16 OR fp32 in d_in /
// d_out (detected at runtime on-device); adj is int32.
// Output: x_out [4,1024,256] then e_out [4,1024,1024] (element offsets).
//
// ws float offsets:
//   [0 .. 196608)   : 6 weight matrices, transposed, bf16, quad-interleaved
//                     matrix m at ushort offset m*65536; element (e,o) at
//                     ((e>>2)*256 + o)*4 + (e&3).  m: 0=Wcat 1=LIN 2=WQ 3=WK 4=WV 5=WO
#define BIAS_OFF 196608   // lin_b, bq, bk, bv, bo, a1, a2  (7*256 fp32)
#define S1_OFF   198400   // [h][4096]
#define S2_OFF   231168
#define CS_OFF   263936   // 32768: column partial sums+sumsq (reused twice)
#define ST1_OFF  296704   // mean[1024] + inv[1024]
#define ST2_OFF  298752
#define A_OFF    300800   // 4 MB: Wh [h][row][32] -> later Q,o head-major [b][h][n][32]
#define B_OFF    1349376  // 4 MB: rownorm(xa)     -> later K head-major
#define C_OFF    2397952  // 4 MB: rownorm(lin)    -> later V head-major
#define FLAG_F   3446528  // int: 1 = bf16 tensors, 0 = fp32 tensors
// end 3446529 floats = 13.8 MB

#define NEGC (-9.0e15f)

static __device__ __forceinline__ float bf2f(unsigned short u) {
  union { unsigned int i; float f; } v; v.i = ((unsigned int)u) << 16; return v.f;
}
static __device__ __forceinline__ unsigned short f2bf(float f) {
  union { float f; unsigned int u; } v; v.f = f;
  unsigned int r = (v.u + 0x7FFFu + ((v.u >> 16) & 1u)) >> 16;   // RNE
  return (unsigned short)r;
}
static __device__ __forceinline__ float ldin(const void* p, long i, int bf) {
  return bf ? bf2f(((const unsigned short*)p)[i]) : ((const float*)p)[i];
}
static __device__ __forceinline__ unsigned short rdbf(const void* p, long i, int bf) {
  if (bf) return ((const unsigned short*)p)[i];
  return f2bf(((const float*)p)[i]);
}
static __device__ __forceinline__ void stout(void* p, long i, float v, int bf) {
  if (bf) ((unsigned short*)p)[i] = f2bf(v);
  else    ((float*)p)[i] = v;
}

// ---------------- dtype detector -------------------------------------------
__global__ __launch_bounds__(64) void detect_kernel(const unsigned short* x, int* flag) {
  int lane = threadIdx.x;
  unsigned short u = x[2 * lane];
  int e = (u >> 7) & 0xFF;
  bool good = (e >= 100 && e <= 140);
  unsigned long long m = __ballot(good);
  if (lane == 0) *flag = (__popcll(m) >= 48) ? 1 : 0;
}

// ---------------- prep: weights -> transposed quad bf16; biases -> fp32 ----
__global__ __launch_bounds__(256) void prep_kernel(
    const void* wg, const void* lin_w, const void* inp_w, const void* out_w,
    const void* lin_b, const void* inp_b, const void* out_b,
    const void* a1, const void* a2, float* ws, const int* flagp) {
  const int bf = *flagp;
  unsigned short* wbf = (unsigned short*)ws;
  int t = threadIdx.x;
  int f = blockIdx.x;
  int m = blockIdx.y;
  int dst = m*65536 + ((f >> 2)*256 + t)*4 + (f & 3);
  if (m == 0) {
    int h = t >> 5, d = t & 31;
    wbf[dst] = rdbf(wg, h*8192 + f*32 + d, bf);
  } else if (m == 1) wbf[dst] = rdbf(lin_w, t*256 + f, bf);
  else if (m == 2)   wbf[dst] = rdbf(inp_w, t*256 + f, bf);
  else if (m == 3)   wbf[dst] = rdbf(inp_w, (256 + t)*256 + f, bf);
  else if (m == 4)   wbf[dst] = rdbf(inp_w, (512 + t)*256 + f, bf);
  else if (m == 5)   wbf[dst] = rdbf(out_w, t*256 + f, bf);
  else if (f == 0) {
    ws[BIAS_OFF + t]        = ldin(lin_b, t, bf);
    ws[BIAS_OFF + 256 + t]  = ldin(inp_b, t, bf);
    ws[BIAS_OFF + 512 + t]  = ldin(inp_b, 256 + t, bf);
    ws[BIAS_OFF + 768 + t]  = ldin(inp_b, 512 + t, bf);
    ws[BIAS_OFF + 1024 + t] = ldin(out_b, t, bf);
    ws[BIAS_OFF + 1280 + t] = ldin(a1, t, bf);
    ws[BIAS_OFF + 1536 + t] = ldin(a2, t, bf);
  }
}

// ---------------- Wh = x @ Wcat, plus s1/s2 head reductions ----------------
__global__ __launch_bounds__(256) void whs_kernel(const void* x, float* ws,
                                                  const int* flagp) {
  const int bf = *flagp;
  int t = threadIdx.x;
  int r0 = blockIdx.x * 8;
  __shared__ __align__(16) float U[8][256];
  #pragma unroll
  for (int r = 0; r < 8; ++r)
    U[r][t] = ldin(x, (long)(r0 + r)*256 + t, bf);
  __syncthreads();
  const ushort4* w4 = (const ushort4*)ws;
  float acc[8] = {0,0,0,0,0,0,0,0};
  for (int e4 = 0; e4 < 64; ++e4) {
    ushort4 u = w4[e4*256 + t];
    float w0 = bf2f(u.x), w1 = bf2f(u.y), w2 = bf2f(u.z), w3 = bf2f(u.w);
    #pragma unroll
    for (int r = 0; r < 8; ++r) {
      float4 uu = *(const float4*)&U[r][e4*4];
      acc[r] += uu.x*w0 + uu.y*w1 + uu.z*w2 + uu.w*w3;
    }
  }
  int h = t >> 5, d = t & 31;
  float a1v = ws[BIAS_OFF + 1280 + t];
  float a2v = ws[BIAS_OFF + 1536 + t];
  #pragma unroll
  for (int r = 0; r < 8; ++r) {
    int row = r0 + r;
    ws[A_OFF + h*131072 + row*32 + d] = acc[r];
    float p1 = acc[r]*a1v, p2 = acc[r]*a2v;
    #pragma unroll
    for (int off = 16; off > 0; off >>= 1) {
      p1 += __shfl_xor(p1, off, 32);
      p2 += __shfl_xor(p2, off, 32);
    }
    if (d == 0) {
      ws[S1_OFF + h*4096 + row] = p1;
      ws[S2_OFF + h*4096 + row] = p2;
    }
  }
}

// ------- graph attention + residual + fused rownorm; e_out = mean_h attn ---
__global__ __launch_bounds__(256) void attn1_kernel(const void* x, const int* adj,
                                                    float* ws, void* dout,
                                                    const int* flagp) {
  const int bf = *flagp;
  int t = threadIdx.x;
  int b = blockIdx.y;
  int n0 = blockIdx.x * 4;
  __shared__ __align__(16) float Sp[4][1024];
  __shared__ float eacc[4][1024];
  __shared__ float s2s[1024];
  __shared__ unsigned char adjm[4][1024];
  __shared__ float s1s[4];
  __shared__ float hpred[32][32];
  __shared__ __align__(16) float xrow[4][256];
  float* eaccf = &eacc[0][0];
  for (int i = t; i < 4096; i += 256) eaccf[i] = 0.0f;
  for (int r = 0; r < 4; ++r) {
    int base = (b*1024 + n0 + r) * 1024;
    for (int j = 0; j < 4; ++j) {
      int m = t + 256*j;
      adjm[r][m] = (adj[base + m] > 0) ? 1 : 0;
    }
  }
  int w = t >> 6, lane = t & 63;
  for (int h = 0; h < 8; ++h) {
    const float* s2p = ws + S2_OFF + h*4096 + b*1024;
    for (int j = 0; j < 4; ++j) s2s[t + 256*j] = s2p[t + 256*j];
    if (t < 4) s1s[t] = ws[S1_OFF + h*4096 + b*1024 + n0 + t];
    __syncthreads();
    #pragma unroll
    for (int r = 0; r < 4; ++r) {
      float s1v = s1s[r];
      for (int j = 0; j < 4; ++j) {
        int m = t + 256*j;
        float ev = s1v + s2s[m];
        ev = (ev >= 0.0f) ? ev : 0.1f*ev;
        Sp[r][m] = adjm[r][m] ? ev : NEGC;
      }
    }
    __syncthreads();
    float* Sr = Sp[w];
    float mx = -3.4e38f;
    for (int j = 0; j < 16; ++j) mx = fmaxf(mx, Sr[lane + 64*j]);
    #pragma unroll
    for (int off = 32; off > 0; off >>= 1) mx = fmaxf(mx, __shfl_xor(mx, off));
    float s = 0.0f;
    for (int j = 0; j < 16; ++j) {
      float p = __expf(Sr[lane + 64*j] - mx);
      Sr[lane + 64*j] = p;
      s += p;
    }
    #pragma unroll
    for (int off = 32; off > 0; off >>= 1) s += __shfl_xor(s, off);
    float rs = 1.0f / s;
    for (int j = 0; j < 16; ++j) {
      float p = Sr[lane + 64*j] * rs;
      Sr[lane + 64*j] = p;
      eacc[w][lane + 64*j] += 0.125f * p;
    }
    __syncthreads();
    int d = t & 31, c = t >> 5;
    const float* whp = ws + A_OFF + h*131072 + b*32768;
    float a0 = 0, a1r = 0, a2r = 0, a3r = 0;
    int mbase = c*128;
    #pragma unroll 4
    for (int mm = 0; mm < 128; ++mm) {
      int m = mbase + mm;
      float wv = whp[m*32 + d];
      a0 += Sp[0][m]*wv; a1r += Sp[1][m]*wv; a2r += Sp[2][m]*wv; a3r += Sp[3][m]*wv;
    }
    hpred[c*4+0][d] = a0;  hpred[c*4+1][d] = a1r;
    hpred[c*4+2][d] = a2r; hpred[c*4+3][d] = a3r;
    __syncthreads();
    if (t < 128) {
      int r = t >> 5, dd = t & 31;
      float sum = 0.0f;
      #pragma unroll
      for (int c8 = 0; c8 < 8; ++c8) sum += hpred[c8*4 + r][dd];
      float hv = (sum >= 0.0f) ? sum : 0.01f*sum;
      long idx = (long)(b*1024 + n0 + r)*256 + h*32 + dd;
      xrow[r][h*32 + dd] = ldin(x, idx, bf) + hv;
    }
    __syncthreads();
  }
  // fused rownorm (ddof=1): wave w handles row w
  float vals[4]; float s = 0.0f;
  #pragma unroll
  for (int j = 0; j < 4; ++j) { vals[j] = xrow[w][lane + 64*j]; s += vals[j]; }
  #pragma unroll
  for (int off = 32; off > 0; off >>= 1) s += __shfl_xor(s, off);
  float mean = s * (1.0f/256.0f);
  float ss = 0.0f;
  #pragma unroll
  for (int j = 0; j < 4; ++j) { float d = vals[j] - mean; ss += d*d; }
  #pragma unroll
  for (int off = 32; off > 0; off >>= 1) ss += __shfl_xor(ss, off);
  float inv = 1.0f / (sqrtf(ss * (1.0f/255.0f)) + 1e-6f);
  float* Bp = ws + B_OFF + (b*1024 + n0 + w)*256;
  #pragma unroll
  for (int j = 0; j < 4; ++j) Bp[lane + 64*j] = (vals[j] - mean) * inv;
  for (int r = 0; r < 4; ++r) {
    long base = 1048576L + (long)(b*1024 + n0 + r)*1024;
    for (int j = 0; j < 4; ++j) {
      int m = t + 256*j;
      stout(dout, base + m, eacc[r][m], bf);
    }
  }
}

// ---------------- column (axis=1) stats, ddof=1 ----------------------------
__global__ __launch_bounds__(256) void colstatsA_kernel(const float* in, float* cs) {
  int t = threadIdx.x;
  int j = blockIdx.x & 15;
  int b = blockIdx.x >> 4;
  float s = 0, ss = 0;
  for (int n = j*64; n < j*64 + 64; ++n) {
    float v = in[(b*1024 + n)*256 + t];
    s += v; ss += v*v;
  }
  cs[(b*16 + j)*256 + t] = s;
  cs[16384 + (b*16 + j)*256 + t] = ss;
}

__global__ __launch_bounds__(256) void colstatsB_kernel(const float* cs, float* st) {
  int t = threadIdx.x;
  int b = blockIdx.x;
  float s = 0, ss = 0;
  for (int j = 0; j < 16; ++j) {
    s  += cs[(b*16 + j)*256 + t];
    ss += cs[16384 + (b*16 + j)*256 + t];
  }
  float mean = s * (1.0f/1024.0f);
  float var = fmaxf((ss - s*mean) * (1.0f/1023.0f), 0.0f);
  st[b*256 + t] = mean;
  st[1024 + b*256 + t] = 1.0f / (sqrtf(var) + 1e-6f);
}

// ---------------- row GEMM, bf16 quad weights ------------------------------
// IN_MODE 0: plain fp32 [row][256]; 1: fp32 + colnorm(st); 2: float-input src
//   permuted (n,b,e)->(b,n,e); 3: fp32 head-major [b][h][n][32]
// RN 1: fused rownorm on output
// OUTM 0: fp32 [row][256]; 1: d_out (dtype per flag); 2: fp32 head-major
template<int IN_MODE, int RN, int OUTM>
__global__ __launch_bounds__(256) void gemm_kernel(const void* inp,
    const unsigned short* wmat, const float* bias, const float* st, void* outp,
    const int* flagp) {
  const int bf = *flagp;
  int t = threadIdx.x;
  int r0 = blockIdx.x * 8;
  __shared__ __align__(16) float U[8][256];
  #pragma unroll
  for (int r = 0; r < 8; ++r) {
    int row = r0 + r;
    float v;
    if (IN_MODE == 0) {
      v = ((const float*)inp)[row*256 + t];
    } else if (IN_MODE == 1) {
      int b = row >> 10;
      v = (((const float*)inp)[row*256 + t] - st[b*256 + t]) * st[1024 + b*256 + t];
    } else if (IN_MODE == 2) {
      int b = row >> 10, n = row & 1023;
      v = ldin(inp, (long)(n*4 + b)*256 + t, bf);
    } else {
      int b = row >> 10, n = row & 1023;
      v = ((const float*)inp)[((b*8 + (t >> 5))*1024 + n)*32 + (t & 31)];
    }
    U[r][t] = v;
  }
  __syncthreads();
  float bv = bias[t];
  float acc[8];
  #pragma unroll
  for (int r = 0; r < 8; ++r) acc[r] = bv;
  const ushort4* w4 = (const ushort4*)wmat;
  for (int e4 = 0; e4 < 64; ++e4) {
    ushort4 u = w4[e4*256 + t];
    float w0 = bf2f(u.x), w1 = bf2f(u.y), w2 = bf2f(u.z), w3 = bf2f(u.w);
    #pragma unroll
    for (int r = 0; r < 8; ++r) {
      float4 uu = *(const float4*)&U[r][e4*4];
      acc[r] += uu.x*w0 + uu.y*w1 + uu.z*w2 + uu.w*w3;
    }
  }
  if (RN == 0) {
    #pragma unroll
    for (int r = 0; r < 8; ++r) {
      int row = r0 + r;
      if (OUTM == 0) ((float*)outp)[row*256 + t] = acc[r];
      else if (OUTM == 1) stout(outp, (long)row*256 + t, acc[r], bf);
      else {
        int b = row >> 10, n = row & 1023;
        ((float*)outp)[((b*8 + (t >> 5))*1024 + n)*32 + (t & 31)] = acc[r];
      }
    }
  } else {
    __syncthreads();
    #pragma unroll
    for (int r = 0; r < 8; ++r) U[r][t] = acc[r];
    __syncthreads();
    int w = t >> 6, lane = t & 63;
    for (int rr = w; rr < 8; rr += 4) {
      float vals[4]; float s = 0.0f;
      #pragma unroll
      for (int j = 0; j < 4; ++j) { vals[j] = U[rr][lane + 64*j]; s += vals[j]; }
      #pragma unroll
      for (int off = 32; off > 0; off >>= 1) s += __shfl_xor(s, off);
      float mean = s * (1.0f/256.0f);
      float ss = 0.0f;
      #pragma unroll
      for (int j = 0; j < 4; ++j) { float d = vals[j] - mean; ss += d*d; }
      #pragma unroll
      for (int off = 32; off > 0; off >>= 1) ss += __shfl_xor(ss, off);
      float inv = 1.0f / (sqrtf(ss * (1.0f/255.0f)) + 1e-6f);
      #pragma unroll
      for (int j = 0; j < 4; ++j)
        ((float*)outp)[(r0 + rr)*256 + lane + 64*j] = (vals[j] - mean) * inv;
    }
  }
}

// ---------------- standard MHA, head-major q/k/v/o -------------------------
// One block per (4 q-rows, batch, head). q,k,v at [b][h][n][32]; o over q.
__global__ __launch_bounds__(256) void attn2_kernel(float* ws) {
  int t = threadIdx.x;
  int b = blockIdx.y;
  int h = blockIdx.z;
  int n0 = blockIdx.x * 4;
  __shared__ __align__(16) float Sp[4][1024];
  __shared__ __align__(16) float qs[4][32];
  __shared__ float hpred[32][32];
  float* qq = ws + A_OFF;
  const float* kk = ws + B_OFF;
  const float* vv = ws + C_OFF;
  int base_bh = (b*8 + h)*1024;
  int w = t >> 6, lane = t & 63;
  const float scl = 0.17677669529663687f; // 1/sqrt(32)
  if (t < 128) {
    int r = t >> 5, d = t & 31;
    qs[r][d] = qq[(base_bh + n0 + r)*32 + d];
  }
  __syncthreads();
  #pragma unroll
  for (int j = 0; j < 4; ++j) {
    int m = t + 256*j;
    const float4* kp = (const float4*)(kk + (base_bh + m)*32);
    float d0 = 0, d1 = 0, d2 = 0, d3 = 0;
    #pragma unroll
    for (int p = 0; p < 8; ++p) {
      float4 kv = kp[p];
      float4 q0 = *(const float4*)&qs[0][p*4];
      float4 q1 = *(const float4*)&qs[1][p*4];
      float4 q2 = *(const float4*)&qs[2][p*4];
      float4 q3 = *(const float4*)&qs[3][p*4];
      d0 += q0.x*kv.x + q0.y*kv.y + q0.z*kv.z + q0.w*kv.w;
      d1 += q1.x*kv.x + q1.y*kv.y + q1.z*kv.z + q1.w*kv.w;
      d2 += q2.x*kv.x + q2.y*kv.y + q2.z*kv.z + q2.w*kv.w;
      d3 += q3.x*kv.x + q3.y*kv.y + q3.z*kv.z + q3.w*kv.w;
    }
    Sp[0][m] = d0*scl; Sp[1][m] = d1*scl; Sp[2][m] = d2*scl; Sp[3][m] = d3*scl;
  }
  __syncthreads();
  float* Sr = Sp[w];
  float mx = -3.4e38f;
  #pragma unroll
  for (int j = 0; j < 16; ++j) mx = fmaxf(mx, Sr[lane + 64*j]);
  #pragma unroll
  for (int off = 32; off > 0; off >>= 1) mx = fmaxf(mx, __shfl_xor(mx, off));
  float s = 0.0f;
  #pragma unroll
  for (int j = 0; j < 16; ++j) {
    float p = __expf(Sr[lane + 64*j] - mx);
    Sr[lane + 64*j] = p;
    s += p;
  }
  #pragma unroll
  for (int off = 32; off > 0; off >>= 1) s += __shfl_xor(s, off);
  float rs = 1.0f / s;
  #pragma unroll
  for (int j = 0; j < 16; ++j) Sr[lane + 64*j] *= rs;
  __syncthreads();
  int d = t & 31, c = t >> 5;
  const float* vp = vv + base_bh*32;
  float a0 = 0, a1r = 0, a2r = 0, a3r = 0;
  int mbase = c*128;
  #pragma unroll 4
  for (int mm = 0; mm < 128; ++mm) {
    int m = mbase + mm;
    float wv = vp[m*32 + d];
    a0 += Sp[0][m]*wv; a1r += Sp[1][m]*wv; a2r += Sp[2][m]*wv; a3r += Sp[3][m]*wv;
  }
  hpred[c*4+0][d] = a0;  hpred[c*4+1][d] = a1r;
  hpred[c*4+2][d] = a2r; hpred[c*4+3][d] = a3r;
  __syncthreads();
  if (t < 128) {
    int r = t >> 5, dd = t & 31;
    float sum = 0.0f;
    #pragma unroll
    for (int c8 = 0; c8 < 8; ++c8) sum += hpred[c8*4 + r][dd];
    qq[(base_bh + n0 + r)*32 + dd] = sum;   // o over q (own slots)
  }
}

extern "C" void kernel_launch(void* const* d_in, const int* in_sizes, int n_in,
                              void* d_out, int out_size, void* d_ws, size_t ws_size,
                              hipStream_t stream) {
  const void* x   = d_in[0];
  const void* src = d_in[1];
  const int* adj  = (const int*)d_in[2];
  const void* wg  = d_in[3];
  const void* a1  = d_in[4];
  const void* a2  = d_in[5];
  const void* lw  = d_in[6];
  const void* lb  = d_in[7];
  const void* ipw = d_in[8];
  const void* ipb = d_in[9];
  const void* opw = d_in[10];
  const void* opb = d_in[11];
  float* ws = (float*)d_ws;
  const unsigned short* wbf = (const unsigned short*)d_ws;
  int* flagp = (int*)(ws + FLAG_F);

  detect_kernel<<<1, 64, 0, stream>>>((const unsigned short*)x, flagp);
  prep_kernel<<<dim3(256, 7), 256, 0, stream>>>(wg, lw, ipw, opw, lb, ipb, opb,
                                                a1, a2, ws, flagp);
  whs_kernel<<<512, 256, 0, stream>>>(x, ws, flagp);
  attn1_kernel<<<dim3(256, 4), 256, 0, stream>>>(x, adj, ws, d_out, flagp);
  colstatsA_kernel<<<64, 256, 0, stream>>>(ws + B_OFF, ws + CS_OFF);
  colstatsB_kernel<<<4, 256, 0, stream>>>(ws + CS_OFF, ws + ST1_OFF);
  gemm_kernel<1,1,0><<<512, 256, 0, stream>>>(ws + B_OFF, wbf + 1*65536,
      ws + BIAS_OFF, ws + ST1_OFF, ws + C_OFF, flagp);
  colstatsA_kernel<<<64, 256, 0, stream>>>(ws + C_OFF, ws + CS_OFF);
  colstatsB_kernel<<<4, 256, 0, stream>>>(ws + CS_OFF, ws + ST2_OFF);
  gemm_kernel<1,0,2><<<512, 256, 0, stream>>>(ws + C_OFF, wbf + 2*65536,
      ws + BIAS_OFF + 256, ws + ST2_OFF, ws + A_OFF, flagp);   // Q head-major
  gemm_kernel<1,0,2><<<512, 256, 0, stream>>>(ws + C_OFF, wbf + 3*65536,
      ws + BIAS_OFF + 512, ws + ST2_OFF, ws + B_OFF, flagp);   // K head-major
  gemm_kernel<2,0,2><<<512, 256, 0, stream>>>(src, wbf + 4*65536,
      ws + BIAS_OFF + 768, nullptr, ws + C_OFF, flagp);        // V head-major
  attn2_kernel<<<dim3(256, 4, 8), 256, 0, stream>>>(ws);       // o -> A_OFF
  gemm_kernel<3,0,1><<<512, 256, 0, stream>>>(ws + A_OFF, wbf + 5*65536,
      ws + BIAS_OFF + 1024, nullptr, d_out, flagp);            // out-proj
}

// Round 6
// 615.319 us; speedup vs baseline: 1.3758x; 1.3119x over previous
//
#include <hip/hip_runtime.h>
#include <hip/hip_bf16.h>

// B=4, N=1024, E=256, H=8, D=32. Float tensors may be bf16 OR fp32 in d_in /
// d_out (detected at runtime on-device); adj is int32.
// Output: x_out [4,1024,256] then e_out [4,1024,1024] (element offsets).
//
// ws float offsets:
//   [0 .. 196608)   : 6 weight matrices, transposed, bf16, quad-interleaved
//                     matrix m at ushort offset m*65536; element (e,o) at
//                     ((e>>2)*256 + o)*4 + (e&3).  m: 0=Wcat 1=LIN 2=WQ 3=WK 4=WV 5=WO
#define BIAS_OFF 196608   // lin_b, bq, bk, bv, bo, a1, a2  (7*256 fp32)
#define S1_OFF   198400   // [h][4096]
#define S2_OFF   231168
#define CS_OFF   263936   // 32768: column partial sums+sumsq (reused twice)
#define ST1_OFF  296704   // mean[1024] + inv[1024]
#define ST2_OFF  298752
#define A_OFF    300800   // 4 MB: Wh [h][row][32] -> later Q,o head-major [b][h][n][32]
#define B_OFF    1349376  // 4 MB: rownorm(xa)     -> later K head-major
#define C_OFF    2397952  // 4 MB: rownorm(lin)    -> later V head-major
#define FLAG_F   3446528  // int: 1 = bf16 tensors, 0 = fp32 tensors
// end 3446529 floats = 13.8 MB

#define NEGC (-9.0e15f)

static __device__ __forceinline__ float bf2f(unsigned short u) {
  union { unsigned int i; float f; } v; v.i = ((unsigned int)u) << 16; return v.f;
}
static __device__ __forceinline__ unsigned short f2bf(float f) {
  union { float f; unsigned int u; } v; v.f = f;
  unsigned int r = (v.u + 0x7FFFu + ((v.u >> 16) & 1u)) >> 16;   // RNE
  return (unsigned short)r;
}
static __device__ __forceinline__ float ldin(const void* p, long i, int bf) {
  return bf ? bf2f(((const unsigned short*)p)[i]) : ((const float*)p)[i];
}
static __device__ __forceinline__ unsigned short rdbf(const void* p, long i, int bf) {
  if (bf) return ((const unsigned short*)p)[i];
  return f2bf(((const float*)p)[i]);
}
static __device__ __forceinline__ void stout(void* p, long i, float v, int bf) {
  if (bf) ((unsigned short*)p)[i] = f2bf(v);
  else    ((float*)p)[i] = v;
}

// ---------------- dtype detector -------------------------------------------
__global__ __launch_bounds__(64) void detect_kernel(const unsigned short* x, int* flag) {
  int lane = threadIdx.x;
  unsigned short u = x[2 * lane];
  int e = (u >> 7) & 0xFF;
  bool good = (e >= 100 && e <= 140);
  unsigned long long m = __ballot(good);
  if (lane == 0) *flag = (__popcll(m) >= 48) ? 1 : 0;
}

// ---------------- prep: weights -> transposed quad bf16; biases -> fp32 ----
__global__ __launch_bounds__(256) void prep_kernel(
    const void* wg, const void* lin_w, const void* inp_w, const void* out_w,
    const void* lin_b, const void* inp_b, const void* out_b,
    const void* a1, const void* a2, float* ws, const int* flagp) {
  const int bf = *flagp;
  unsigned short* wbf = (unsigned short*)ws;
  int t = threadIdx.x;
  int f = blockIdx.x;
  int m = blockIdx.y;
  int dst = m*65536 + ((f >> 2)*256 + t)*4 + (f & 3);
  if (m == 0) {
    int h = t >> 5, d = t & 31;
    wbf[dst] = rdbf(wg, h*8192 + f*32 + d, bf);
  } else if (m == 1) wbf[dst] = rdbf(lin_w, t*256 + f, bf);
  else if (m == 2)   wbf[dst] = rdbf(inp_w, t*256 + f, bf);
  else if (m == 3)   wbf[dst] = rdbf(inp_w, (256 + t)*256 + f, bf);
  else if (m == 4)   wbf[dst] = rdbf(inp_w, (512 + t)*256 + f, bf);
  else if (m == 5)   wbf[dst] = rdbf(out_w, t*256 + f, bf);
  else if (f == 0) {
    ws[BIAS_OFF + t]        = ldin(lin_b, t, bf);
    ws[BIAS_OFF + 256 + t]  = ldin(inp_b, t, bf);
    ws[BIAS_OFF + 512 + t]  = ldin(inp_b, 256 + t, bf);
    ws[BIAS_OFF + 768 + t]  = ldin(inp_b, 512 + t, bf);
    ws[BIAS_OFF + 1024 + t] = ldin(out_b, t, bf);
    ws[BIAS_OFF + 1280 + t] = ldin(a1, t, bf);
    ws[BIAS_OFF + 1536 + t] = ldin(a2, t, bf);
  }
}

// ---------------- Wh = x @ Wcat, plus s1/s2 head reductions ----------------
__global__ __launch_bounds__(256) void whs_kernel(const void* x, float* ws,
                                                  const int* flagp) {
  const int bf = *flagp;
  int t = threadIdx.x;
  int r0 = blockIdx.x * 8;
  __shared__ __align__(16) float U[8][256];
  #pragma unroll
  for (int r = 0; r < 8; ++r)
    U[r][t] = ldin(x, (long)(r0 + r)*256 + t, bf);
  __syncthreads();
  const ushort4* w4 = (const ushort4*)ws;
  float acc[8] = {0,0,0,0,0,0,0,0};
  for (int e4 = 0; e4 < 64; ++e4) {
    ushort4 u = w4[e4*256 + t];
    float w0 = bf2f(u.x), w1 = bf2f(u.y), w2 = bf2f(u.z), w3 = bf2f(u.w);
    #pragma unroll
    for (int r = 0; r < 8; ++r) {
      float4 uu = *(const float4*)&U[r][e4*4];
      acc[r] += uu.x*w0 + uu.y*w1 + uu.z*w2 + uu.w*w3;
    }
  }
  int h = t >> 5, d = t & 31;
  float a1v = ws[BIAS_OFF + 1280 + t];
  float a2v = ws[BIAS_OFF + 1536 + t];
  #pragma unroll
  for (int r = 0; r < 8; ++r) {
    int row = r0 + r;
    ws[A_OFF + h*131072 + row*32 + d] = acc[r];
    float p1 = acc[r]*a1v, p2 = acc[r]*a2v;
    #pragma unroll
    for (int off = 16; off > 0; off >>= 1) {
      p1 += __shfl_xor(p1, off, 32);
      p2 += __shfl_xor(p2, off, 32);
    }
    if (d == 0) {
      ws[S1_OFF + h*4096 + row] = p1;
      ws[S2_OFF + h*4096 + row] = p2;
    }
  }
}

// ------- graph attention + residual + fused rownorm; e_out = mean_h attn ---
// 1-D grid, XCD-swizzled: low 3 bits = (b*2 + n0-parity) so each XCD's L2
// serves one batch's Wh working set (~1 MB << 4 MB).
__global__ __launch_bounds__(256) void attn1_kernel(const void* x, const int* adj,
                                                    float* ws, void* dout,
                                                    const int* flagp) {
  const int bf = *flagp;
  int t = threadIdx.x;
  int gid = blockIdx.x;
  int b = (gid >> 1) & 3;
  int n0 = ((((gid >> 3) << 1) | (gid & 1))) * 4;
  __shared__ __align__(16) float Sp[4][1024];
  __shared__ float eacc[4][1024];
  __shared__ float s2s[1024];
  __shared__ unsigned char adjm[4][1024];
  __shared__ float s1s[4];
  __shared__ float hpred[32][32];
  __shared__ __align__(16) float xrow[4][256];
  float* eaccf = &eacc[0][0];
  for (int i = t; i < 4096; i += 256) eaccf[i] = 0.0f;
  for (int r = 0; r < 4; ++r) {
    int base = (b*1024 + n0 + r) * 1024;
    for (int j = 0; j < 4; ++j) {
      int m = t + 256*j;
      adjm[r][m] = (adj[base + m] > 0) ? 1 : 0;
    }
  }
  int w = t >> 6, lane = t & 63;
  for (int h = 0; h < 8; ++h) {
    const float* s2p = ws + S2_OFF + h*4096 + b*1024;
    for (int j = 0; j < 4; ++j) s2s[t + 256*j] = s2p[t + 256*j];
    if (t < 4) s1s[t] = ws[S1_OFF + h*4096 + b*1024 + n0 + t];
    __syncthreads();
    #pragma unroll
    for (int r = 0; r < 4; ++r) {
      float s1v = s1s[r];
      for (int j = 0; j < 4; ++j) {
        int m = t + 256*j;
        float ev = s1v + s2s[m];
        ev = (ev >= 0.0f) ? ev : 0.1f*ev;
        Sp[r][m] = adjm[r][m] ? ev : NEGC;
      }
    }
    __syncthreads();
    float* Sr = Sp[w];
    float mx = -3.4e38f;
    for (int j = 0; j < 16; ++j) mx = fmaxf(mx, Sr[lane + 64*j]);
    #pragma unroll
    for (int off = 32; off > 0; off >>= 1) mx = fmaxf(mx, __shfl_xor(mx, off));
    float s = 0.0f;
    for (int j = 0; j < 16; ++j) {
      float p = __expf(Sr[lane + 64*j] - mx);
      Sr[lane + 64*j] = p;
      s += p;
    }
    #pragma unroll
    for (int off = 32; off > 0; off >>= 1) s += __shfl_xor(s, off);
    float rs = 1.0f / s;
    for (int j = 0; j < 16; ++j) {
      float p = Sr[lane + 64*j] * rs;
      Sr[lane + 64*j] = p;
      eacc[w][lane + 64*j] += 0.125f * p;
    }
    __syncthreads();
    int d = t & 31, c = t >> 5;
    const float* whp = ws + A_OFF + h*131072 + b*32768;
    float a0 = 0, a1r = 0, a2r = 0, a3r = 0;
    int mbase = c*128;
    #pragma unroll 4
    for (int mq = 0; mq < 32; ++mq) {
      int m = mbase + mq*4;
      float4 s0 = *(const float4*)&Sp[0][m];
      float4 s1 = *(const float4*)&Sp[1][m];
      float4 s2 = *(const float4*)&Sp[2][m];
      float4 s3 = *(const float4*)&Sp[3][m];
      float w0 = whp[(m+0)*32 + d];
      float w1 = whp[(m+1)*32 + d];
      float w2 = whp[(m+2)*32 + d];
      float w3 = whp[(m+3)*32 + d];
      a0  += s0.x*w0 + s0.y*w1 + s0.z*w2 + s0.w*w3;
      a1r += s1.x*w0 + s1.y*w1 + s1.z*w2 + s1.w*w3;
      a2r += s2.x*w0 + s2.y*w1 + s2.z*w2 + s2.w*w3;
      a3r += s3.x*w0 + s3.y*w1 + s3.z*w2 + s3.w*w3;
    }
    hpred[c*4+0][d] = a0;  hpred[c*4+1][d] = a1r;
    hpred[c*4+2][d] = a2r; hpred[c*4+3][d] = a3r;
    __syncthreads();
    if (t < 128) {
      int r = t >> 5, dd = t & 31;
      float sum = 0.0f;
      #pragma unroll
      for (int c8 = 0; c8 < 8; ++c8) sum += hpred[c8*4 + r][dd];
      float hv = (sum >= 0.0f) ? sum : 0.01f*sum;
      long idx = (long)(b*1024 + n0 + r)*256 + h*32 + dd;
      xrow[r][h*32 + dd] = ldin(x, idx, bf) + hv;
    }
    __syncthreads();
  }
  // fused rownorm (ddof=1): wave w handles row w
  float vals[4]; float s = 0.0f;
  #pragma unroll
  for (int j = 0; j < 4; ++j) { vals[j] = xrow[w][lane + 64*j]; s += vals[j]; }
  #pragma unroll
  for (int off = 32; off > 0; off >>= 1) s += __shfl_xor(s, off);
  float mean = s * (1.0f/256.0f);
  float ss = 0.0f;
  #pragma unroll
  for (int j = 0; j < 4; ++j) { float d = vals[j] - mean; ss += d*d; }
  #pragma unroll
  for (int off = 32; off > 0; off >>= 1) ss += __shfl_xor(ss, off);
  float inv = 1.0f / (sqrtf(ss * (1.0f/255.0f)) + 1e-6f);
  float* Bp = ws + B_OFF + (b*1024 + n0 + w)*256;
  #pragma unroll
  for (int j = 0; j < 4; ++j) Bp[lane + 64*j] = (vals[j] - mean) * inv;
  for (int r = 0; r < 4; ++r) {
    long base = 1048576L + (long)(b*1024 + n0 + r)*1024;
    for (int j = 0; j < 4; ++j) {
      int m = t + 256*j;
      stout(dout, base + m, eacc[r][m], bf);
    }
  }
}

// ---------------- column (axis=1) stats, ddof=1 ----------------------------
__global__ __launch_bounds__(256) void colstatsA_kernel(const float* in, float* cs) {
  int t = threadIdx.x;
  int j = blockIdx.x & 15;
  int b = blockIdx.x >> 4;
  float s = 0, ss = 0;
  for (int n = j*64; n < j*64 + 64; ++n) {
    float v = in[(b*1024 + n)*256 + t];
    s += v; ss += v*v;
  }
  cs[(b*16 + j)*256 + t] = s;
  cs[16384 + (b*16 + j)*256 + t] = ss;
}

__global__ __launch_bounds__(256) void colstatsB_kernel(const float* cs, float* st) {
  int t = threadIdx.x;
  int b = blockIdx.x;
  float s = 0, ss = 0;
  for (int j = 0; j < 16; ++j) {
    s  += cs[(b*16 + j)*256 + t];
    ss += cs[16384 + (b*16 + j)*256 + t];
  }
  float mean = s * (1.0f/1024.0f);
  float var = fmaxf((ss - s*mean) * (1.0f/1023.0f), 0.0f);
  st[b*256 + t] = mean;
  st[1024 + b*256 + t] = 1.0f / (sqrtf(var) + 1e-6f);
}

// ---------------- row GEMM, bf16 quad weights ------------------------------
// IN_MODE 0: plain fp32 [row][256]; 1: fp32 + colnorm(st); 2: float-input src
//   permuted (n,b,e)->(b,n,e); 3: fp32 head-major [b][h][n][32]
// RN 1: fused rownorm on output
// OUTM 0: fp32 [row][256]; 1: d_out (dtype per flag); 2: fp32 head-major
template<int IN_MODE, int RN, int OUTM>
__global__ __launch_bounds__(256) void gemm_kernel(const void* inp,
    const unsigned short* wmat, const float* bias, const float* st, void* outp,
    const int* flagp) {
  const int bf = *flagp;
  int t = threadIdx.x;
  int r0 = blockIdx.x * 8;
  __shared__ __align__(16) float U[8][256];
  #pragma unroll
  for (int r = 0; r < 8; ++r) {
    int row = r0 + r;
    float v;
    if (IN_MODE == 0) {
      v = ((const float*)inp)[row*256 + t];
    } else if (IN_MODE == 1) {
      int b = row >> 10;
      v = (((const float*)inp)[row*256 + t] - st[b*256 + t]) * st[1024 + b*256 + t];
    } else if (IN_MODE == 2) {
      int b = row >> 10, n = row & 1023;
      v = ldin(inp, (long)(n*4 + b)*256 + t, bf);
    } else {
      int b = row >> 10, n = row & 1023;
      v = ((const float*)inp)[((b*8 + (t >> 5))*1024 + n)*32 + (t & 31)];
    }
    U[r][t] = v;
  }
  __syncthreads();
  float bv = bias[t];
  float acc[8];
  #pragma unroll
  for (int r = 0; r < 8; ++r) acc[r] = bv;
  const ushort4* w4 = (const ushort4*)wmat;
  for (int e4 = 0; e4 < 64; ++e4) {
    ushort4 u = w4[e4*256 + t];
    float w0 = bf2f(u.x), w1 = bf2f(u.y), w2 = bf2f(u.z), w3 = bf2f(u.w);
    #pragma unroll
    for (int r = 0; r < 8; ++r) {
      float4 uu = *(const float4*)&U[r][e4*4];
      acc[r] += uu.x*w0 + uu.y*w1 + uu.z*w2 + uu.w*w3;
    }
  }
  if (RN == 0) {
    #pragma unroll
    for (int r = 0; r < 8; ++r) {
      int row = r0 + r;
      if (OUTM == 0) ((float*)outp)[row*256 + t] = acc[r];
      else if (OUTM == 1) stout(outp, (long)row*256 + t, acc[r], bf);
      else {
        int b = row >> 10, n = row & 1023;
        ((float*)outp)[((b*8 + (t >> 5))*1024 + n)*32 + (t & 31)] = acc[r];
      }
    }
  } else {
    __syncthreads();
    #pragma unroll
    for (int r = 0; r < 8; ++r) U[r][t] = acc[r];
    __syncthreads();
    int w = t >> 6, lane = t & 63;
    for (int rr = w; rr < 8; rr += 4) {
      float vals[4]; float s = 0.0f;
      #pragma unroll
      for (int j = 0; j < 4; ++j) { vals[j] = U[rr][lane + 64*j]; s += vals[j]; }
      #pragma unroll
      for (int off = 32; off > 0; off >>= 1) s += __shfl_xor(s, off);
      float mean = s * (1.0f/256.0f);
      float ss = 0.0f;
      #pragma unroll
      for (int j = 0; j < 4; ++j) { float d = vals[j] - mean; ss += d*d; }
      #pragma unroll
      for (int off = 32; off > 0; off >>= 1) ss += __shfl_xor(ss, off);
      float inv = 1.0f / (sqrtf(ss * (1.0f/255.0f)) + 1e-6f);
      #pragma unroll
      for (int j = 0; j < 4; ++j)
        ((float*)outp)[(r0 + rr)*256 + lane + 64*j] = (vals[j] - mean) * inv;
    }
  }
}

// ---------------- standard MHA, head-major q/k/v/o -------------------------
// 1-D grid, XCD-swizzled: low 3 bits = head, so each XCD's L2 serves one
// head's K/V (4 batches x 256 KB = 1 MB << 4 MB). o written over q slots.
__global__ __launch_bounds__(256) void attn2_kernel(float* ws) {
  int t = threadIdx.x;
  int gid = blockIdx.x;
  int h = gid & 7;
  int b = (gid >> 3) & 3;
  int n0 = (gid >> 5) << 2;
  __shared__ __align__(16) float Sp[4][1024];
  __shared__ __align__(16) float qs[4][32];
  __shared__ float hpred[32][32];
  float* qq = ws + A_OFF;
  const float* kk = ws + B_OFF;
  const float* vv = ws + C_OFF;
  int base_bh = (b*8 + h)*1024;
  int w = t >> 6, lane = t & 63;
  const float scl = 0.17677669529663687f; // 1/sqrt(32)
  if (t < 128) {
    int r = t >> 5, d = t & 31;
    qs[r][d] = qq[(base_bh + n0 + r)*32 + d];
  }
  __syncthreads();
  #pragma unroll
  for (int j = 0; j < 4; ++j) {
    int m = t + 256*j;
    const float4* kp = (const float4*)(kk + (base_bh + m)*32);
    float d0 = 0, d1 = 0, d2 = 0, d3 = 0;
    #pragma unroll
    for (int p = 0; p < 8; ++p) {
      float4 kv = kp[p];
      float4 q0 = *(const float4*)&qs[0][p*4];
      float4 q1 = *(const float4*)&qs[1][p*4];
      float4 q2 = *(const float4*)&qs[2][p*4];
      float4 q3 = *(const float4*)&qs[3][p*4];
      d0 += q0.x*kv.x + q0.y*kv.y + q0.z*kv.z + q0.w*kv.w;
      d1 += q1.x*kv.x + q1.y*kv.y + q1.z*kv.z + q1.w*kv.w;
      d2 += q2.x*kv.x + q2.y*kv.y + q2.z*kv.z + q2.w*kv.w;
      d3 += q3.x*kv.x + q3.y*kv.y + q3.z*kv.z + q3.w*kv.w;
    }
    Sp[0][m] = d0*scl; Sp[1][m] = d1*scl; Sp[2][m] = d2*scl; Sp[3][m] = d3*scl;
  }
  __syncthreads();
  float* Sr = Sp[w];
  float mx = -3.4e38f;
  #pragma unroll
  for (int j = 0; j < 16; ++j) mx = fmaxf(mx, Sr[lane + 64*j]);
  #pragma unroll
  for (int off = 32; off > 0; off >>= 1) mx = fmaxf(mx, __shfl_xor(mx, off));
  float s = 0.0f;
  #pragma unroll
  for (int j = 0; j < 16; ++j) {
    float p = __expf(Sr[lane + 64*j] - mx);
    Sr[lane + 64*j] = p;
    s += p;
  }
  #pragma unroll
  for (int off = 32; off > 0; off >>= 1) s += __shfl_xor(s, off);
  float rs = 1.0f / s;
  #pragma unroll
  for (int j = 0; j < 16; ++j) Sr[lane + 64*j] *= rs;
  __syncthreads();
  int d = t & 31, c = t >> 5;
  const float* vp = vv + base_bh*32;
  float a0 = 0, a1r = 0, a2r = 0, a3r = 0;
  int mbase = c*128;
  #pragma unroll 4
  for (int mq = 0; mq < 32; ++mq) {
    int m = mbase + mq*4;
    float4 s0 = *(const float4*)&Sp[0][m];
    float4 s1 = *(const float4*)&Sp[1][m];
    float4 s2 = *(const float4*)&Sp[2][m];
    float4 s3 = *(const float4*)&Sp[3][m];
    float w0 = vp[(m+0)*32 + d];
    float w1 = vp[(m+1)*32 + d];
    float w2 = vp[(m+2)*32 + d];
    float w3 = vp[(m+3)*32 + d];
    a0  += s0.x*w0 + s0.y*w1 + s0.z*w2 + s0.w*w3;
    a1r += s1.x*w0 + s1.y*w1 + s1.z*w2 + s1.w*w3;
    a2r += s2.x*w0 + s2.y*w1 + s2.z*w2 + s2.w*w3;
    a3r += s3.x*w0 + s3.y*w1 + s3.z*w2 + s3.w*w3;
  }
  hpred[c*4+0][d] = a0;  hpred[c*4+1][d] = a1r;
  hpred[c*4+2][d] = a2r; hpred[c*4+3][d] = a3r;
  __syncthreads();
  if (t < 128) {
    int r = t >> 5, dd = t & 31;
    float sum = 0.0f;
    #pragma unroll
    for (int c8 = 0; c8 < 8; ++c8) sum += hpred[c8*4 + r][dd];
    qq[(base_bh + n0 + r)*32 + dd] = sum;   // o over q (own slots)
  }
}

extern "C" void kernel_launch(void* const* d_in, const int* in_sizes, int n_in,
                              void* d_out, int out_size, void* d_ws, size_t ws_size,
                              hipStream_t stream) {
  const void* x   = d_in[0];
  const void* src = d_in[1];
  const int* adj  = (const int*)d_in[2];
  const void* wg  = d_in[3];
  const void* a1  = d_in[4];
  const void* a2  = d_in[5];
  const void* lw  = d_in[6];
  const void* lb  = d_in[7];
  const void* ipw = d_in[8];
  const void* ipb = d_in[9];
  const void* opw = d_in[10];
  const void* opb = d_in[11];
  float* ws = (float*)d_ws;
  const unsigned short* wbf = (const unsigned short*)d_ws;
  int* flagp = (int*)(ws + FLAG_F);

  detect_kernel<<<1, 64, 0, stream>>>((const unsigned short*)x, flagp);
  prep_kernel<<<dim3(256, 7), 256, 0, stream>>>(wg, lw, ipw, opw, lb, ipb, opb,
                                                a1, a2, ws, flagp);
  whs_kernel<<<512, 256, 0, stream>>>(x, ws, flagp);
  attn1_kernel<<<1024, 256, 0, stream>>>(x, adj, ws, d_out, flagp);
  colstatsA_kernel<<<64, 256, 0, stream>>>(ws + B_OFF, ws + CS_OFF);
  colstatsB_kernel<<<4, 256, 0, stream>>>(ws + CS_OFF, ws + ST1_OFF);
  gemm_kernel<1,1,0><<<512, 256, 0, stream>>>(ws + B_OFF, wbf + 1*65536,
      ws + BIAS_OFF, ws + ST1_OFF, ws + C_OFF, flagp);
  colstatsA_kernel<<<64, 256, 0, stream>>>(ws + C_OFF, ws + CS_OFF);
  colstatsB_kernel<<<4, 256, 0, stream>>>(ws + CS_OFF, ws + ST2_OFF);
  gemm_kernel<1,0,2><<<512, 256, 0, stream>>>(ws + C_OFF, wbf + 2*65536,
      ws + BIAS_OFF + 256, ws + ST2_OFF, ws + A_OFF, flagp);   // Q head-major
  gemm_kernel<1,0,2><<<512, 256, 0, stream>>>(ws + C_OFF, wbf + 3*65536,
      ws + BIAS_OFF + 512, ws + ST2_OFF, ws + B_OFF, flagp);   // K head-major
  gemm_kernel<2,0,2><<<512, 256, 0, stream>>>(src, wbf + 4*65536,
      ws + BIAS_OFF + 768, nullptr, ws + C_OFF, flagp);        // V head-major
  attn2_kernel<<<8192, 256, 0, stream>>>(ws);                  // o -> A_OFF
  gemm_kernel<3,0,1><<<512, 256, 0, stream>>>(ws + A_OFF, wbf + 5*65536,
      ws + BIAS_OFF + 1024, nullptr, d_out, flagp);            // out-proj
}

// Round 7
// 519.959 us; speedup vs baseline: 1.6281x; 1.1834x over previous
//
#include <hip/hip_runtime.h>
#include <hip/hip_bf16.h>

// B=4, N=1024, E=256, H=8, D=32. Float tensors may be bf16 OR fp32 in d_in /
// d_out (detected at runtime on-device); adj is int32.
// Output: x_out [4,1024,256] then e_out [4,1024,1024] (element offsets).
//
// ws float offsets:
//   [0 .. 196608)   : 6 weight matrices, transposed, bf16, quad-interleaved
//                     matrix m at ushort offset m*65536; element (e,o) at
//                     ((e>>2)*256 + o)*4 + (e&3).  m: 0=Wcat 1=LIN 2=WQ 3=WK 4=WV 5=WO
#define BIAS_OFF 196608   // lin_b, bq, bk, bv, bo, a1, a2  (7*256 fp32)
#define S1_OFF   198400   // [h][4096]
#define S2_OFF   231168
#define CS_OFF   263936   // 32768: column partial sums+sumsq (reused twice)
#define ST1_OFF  296704   // mean[1024] + inv[1024]
#define ST2_OFF  298752
#define A_OFF    300800   // 4 MB: Wh [h][row][32] -> later Q,o head-major [b][h][n][32]
#define B_OFF    1349376  // 4 MB: rownorm(xa)     -> later K head-major
#define C_OFF    2397952  // 4 MB: rownorm(lin)    -> later V head-major
#define FLAG_F   3446528  // int: 1 = bf16 tensors, 0 = fp32 tensors
// end 3446529 floats = 13.8 MB

#define NEGC (-9.0e15f)

static __device__ __forceinline__ float bf2f(unsigned short u) {
  union { unsigned int i; float f; } v; v.i = ((unsigned int)u) << 16; return v.f;
}
static __device__ __forceinline__ unsigned short f2bf(float f) {
  union { float f; unsigned int u; } v; v.f = f;
  unsigned int r = (v.u + 0x7FFFu + ((v.u >> 16) & 1u)) >> 16;   // RNE
  return (unsigned short)r;
}
static __device__ __forceinline__ float ldin(const void* p, long i, int bf) {
  return bf ? bf2f(((const unsigned short*)p)[i]) : ((const float*)p)[i];
}
static __device__ __forceinline__ unsigned short rdbf(const void* p, long i, int bf) {
  if (bf) return ((const unsigned short*)p)[i];
  return f2bf(((const float*)p)[i]);
}
static __device__ __forceinline__ void stout(void* p, long i, float v, int bf) {
  if (bf) ((unsigned short*)p)[i] = f2bf(v);
  else    ((float*)p)[i] = v;
}

// ---------------- dtype detector -------------------------------------------
__global__ __launch_bounds__(64) void detect_kernel(const unsigned short* x, int* flag) {
  int lane = threadIdx.x;
  unsigned short u = x[2 * lane];
  int e = (u >> 7) & 0xFF;
  bool good = (e >= 100 && e <= 140);
  unsigned long long m = __ballot(good);
  if (lane == 0) *flag = (__popcll(m) >= 48) ? 1 : 0;
}

// ---------------- prep: weights -> transposed quad bf16; biases -> fp32 ----
__global__ __launch_bounds__(256) void prep_kernel(
    const void* wg, const void* lin_w, const void* inp_w, const void* out_w,
    const void* lin_b, const void* inp_b, const void* out_b,
    const void* a1, const void* a2, float* ws, const int* flagp) {
  const int bf = *flagp;
  unsigned short* wbf = (unsigned short*)ws;
  int t = threadIdx.x;
  int f = blockIdx.x;
  int m = blockIdx.y;
  int dst = m*65536 + ((f >> 2)*256 + t)*4 + (f & 3);
  if (m == 0) {
    int h = t >> 5, d = t & 31;
    wbf[dst] = rdbf(wg, h*8192 + f*32 + d, bf);
  } else if (m == 1) wbf[dst] = rdbf(lin_w, t*256 + f, bf);
  else if (m == 2)   wbf[dst] = rdbf(inp_w, t*256 + f, bf);
  else if (m == 3)   wbf[dst] = rdbf(inp_w, (256 + t)*256 + f, bf);
  else if (m == 4)   wbf[dst] = rdbf(inp_w, (512 + t)*256 + f, bf);
  else if (m == 5)   wbf[dst] = rdbf(out_w, t*256 + f, bf);
  else if (f == 0) {
    ws[BIAS_OFF + t]        = ldin(lin_b, t, bf);
    ws[BIAS_OFF + 256 + t]  = ldin(inp_b, t, bf);
    ws[BIAS_OFF + 512 + t]  = ldin(inp_b, 256 + t, bf);
    ws[BIAS_OFF + 768 + t]  = ldin(inp_b, 512 + t, bf);
    ws[BIAS_OFF + 1024 + t] = ldin(out_b, t, bf);
    ws[BIAS_OFF + 1280 + t] = ldin(a1, t, bf);
    ws[BIAS_OFF + 1536 + t] = ldin(a2, t, bf);
  }
}

// ---------------- Wh = x @ Wcat, plus s1/s2 head reductions ----------------
__global__ __launch_bounds__(256) void whs_kernel(const void* x, float* ws,
                                                  const int* flagp) {
  const int bf = *flagp;
  int t = threadIdx.x;
  int r0 = blockIdx.x * 8;
  __shared__ __align__(16) float U[8][256];
  #pragma unroll
  for (int r = 0; r < 8; ++r)
    U[r][t] = ldin(x, (long)(r0 + r)*256 + t, bf);
  __syncthreads();
  const ushort4* w4 = (const ushort4*)ws;
  float acc[8] = {0,0,0,0,0,0,0,0};
  for (int e4 = 0; e4 < 64; ++e4) {
    ushort4 u = w4[e4*256 + t];
    float w0 = bf2f(u.x), w1 = bf2f(u.y), w2 = bf2f(u.z), w3 = bf2f(u.w);
    #pragma unroll
    for (int r = 0; r < 8; ++r) {
      float4 uu = *(const float4*)&U[r][e4*4];
      acc[r] += uu.x*w0 + uu.y*w1 + uu.z*w2 + uu.w*w3;
    }
  }
  int h = t >> 5, d = t & 31;
  float a1v = ws[BIAS_OFF + 1280 + t];
  float a2v = ws[BIAS_OFF + 1536 + t];
  #pragma unroll
  for (int r = 0; r < 8; ++r) {
    int row = r0 + r;
    ws[A_OFF + h*131072 + row*32 + d] = acc[r];
    float p1 = acc[r]*a1v, p2 = acc[r]*a2v;
    #pragma unroll
    for (int off = 16; off > 0; off >>= 1) {
      p1 += __shfl_xor(p1, off, 32);
      p2 += __shfl_xor(p2, off, 32);
    }
    if (d == 0) {
      ws[S1_OFF + h*4096 + row] = p1;
      ws[S2_OFF + h*4096 + row] = p2;
    }
  }
}

// ------- graph attention + residual + fused rownorm; e_out = mean_h attn ---
// 1-D grid, XCD-swizzled: low 3 bits = (b*2 + n0-parity) so each XCD's L2
// serves one batch's Wh working set (~1 MB << 4 MB).
__global__ __launch_bounds__(256) void attn1_kernel(const void* x, const int* adj,
                                                    float* ws, void* dout,
                                                    const int* flagp) {
  const int bf = *flagp;
  int t = threadIdx.x;
  int gid = blockIdx.x;
  int b = (gid >> 1) & 3;
  int n0 = ((((gid >> 3) << 1) | (gid & 1))) * 4;
  __shared__ __align__(16) float Sp[4][1024];
  __shared__ float eacc[4][1024];
  __shared__ float s2s[1024];
  __shared__ unsigned char adjm[4][1024];
  __shared__ float s1s[4];
  __shared__ float hpred[32][32];
  __shared__ __align__(16) float xrow[4][256];
  float* eaccf = &eacc[0][0];
  for (int i = t; i < 4096; i += 256) eaccf[i] = 0.0f;
  for (int r = 0; r < 4; ++r) {
    int base = (b*1024 + n0 + r) * 1024;
    for (int j = 0; j < 4; ++j) {
      int m = t + 256*j;
      adjm[r][m] = (adj[base + m] > 0) ? 1 : 0;
    }
  }
  int w = t >> 6, lane = t & 63;
  for (int h = 0; h < 8; ++h) {
    const float* s2p = ws + S2_OFF + h*4096 + b*1024;
    for (int j = 0; j < 4; ++j) s2s[t + 256*j] = s2p[t + 256*j];
    if (t < 4) s1s[t] = ws[S1_OFF + h*4096 + b*1024 + n0 + t];
    __syncthreads();
    #pragma unroll
    for (int r = 0; r < 4; ++r) {
      float s1v = s1s[r];
      for (int j = 0; j < 4; ++j) {
        int m = t + 256*j;
        float ev = s1v + s2s[m];
        ev = (ev >= 0.0f) ? ev : 0.1f*ev;
        Sp[r][m] = adjm[r][m] ? ev : NEGC;
      }
    }
    __syncthreads();
    float* Sr = Sp[w];
    float mx = -3.4e38f;
    for (int j = 0; j < 16; ++j) mx = fmaxf(mx, Sr[lane + 64*j]);
    #pragma unroll
    for (int off = 32; off > 0; off >>= 1) mx = fmaxf(mx, __shfl_xor(mx, off));
    float s = 0.0f;
    for (int j = 0; j < 16; ++j) {
      float p = __expf(Sr[lane + 64*j] - mx);
      Sr[lane + 64*j] = p;
      s += p;
    }
    #pragma unroll
    for (int off = 32; off > 0; off >>= 1) s += __shfl_xor(s, off);
    float rs = 1.0f / s;
    for (int j = 0; j < 16; ++j) {
      float p = Sr[lane + 64*j] * rs;
      Sr[lane + 64*j] = p;
      eacc[w][lane + 64*j] += 0.125f * p;
    }
    __syncthreads();
    int d = t & 31, c = t >> 5;
    const float* whp = ws + A_OFF + h*131072 + b*32768;
    float a0 = 0, a1r = 0, a2r = 0, a3r = 0;
    int mbase = c*128;
    #pragma unroll 4
    for (int mq = 0; mq < 32; ++mq) {
      int m = mbase + mq*4;
      float4 s0 = *(const float4*)&Sp[0][m];
      float4 s1 = *(const float4*)&Sp[1][m];
      float4 s2 = *(const float4*)&Sp[2][m];
      float4 s3 = *(const float4*)&Sp[3][m];
      float w0 = whp[(m+0)*32 + d];
      float w1 = whp[(m+1)*32 + d];
      float w2 = whp[(m+2)*32 + d];
      float w3 = whp[(m+3)*32 + d];
      a0  += s0.x*w0 + s0.y*w1 + s0.z*w2 + s0.w*w3;
      a1r += s1.x*w0 + s1.y*w1 + s1.z*w2 + s1.w*w3;
      a2r += s2.x*w0 + s2.y*w1 + s2.z*w2 + s2.w*w3;
      a3r += s3.x*w0 + s3.y*w1 + s3.z*w2 + s3.w*w3;
    }
    hpred[c*4+0][d] = a0;  hpred[c*4+1][d] = a1r;
    hpred[c*4+2][d] = a2r; hpred[c*4+3][d] = a3r;
    __syncthreads();
    if (t < 128) {
      int r = t >> 5, dd = t & 31;
      float sum = 0.0f;
      #pragma unroll
      for (int c8 = 0; c8 < 8; ++c8) sum += hpred[c8*4 + r][dd];
      float hv = (sum >= 0.0f) ? sum : 0.01f*sum;
      long idx = (long)(b*1024 + n0 + r)*256 + h*32 + dd;
      xrow[r][h*32 + dd] = ldin(x, idx, bf) + hv;
    }
    __syncthreads();
  }
  // fused rownorm (ddof=1): wave w handles row w
  float vals[4]; float s = 0.0f;
  #pragma unroll
  for (int j = 0; j < 4; ++j) { vals[j] = xrow[w][lane + 64*j]; s += vals[j]; }
  #pragma unroll
  for (int off = 32; off > 0; off >>= 1) s += __shfl_xor(s, off);
  float mean = s * (1.0f/256.0f);
  float ss = 0.0f;
  #pragma unroll
  for (int j = 0; j < 4; ++j) { float d = vals[j] - mean; ss += d*d; }
  #pragma unroll
  for (int off = 32; off > 0; off >>= 1) ss += __shfl_xor(ss, off);
  float inv = 1.0f / (sqrtf(ss * (1.0f/255.0f)) + 1e-6f);
  float* Bp = ws + B_OFF + (b*1024 + n0 + w)*256;
  #pragma unroll
  for (int j = 0; j < 4; ++j) Bp[lane + 64*j] = (vals[j] - mean) * inv;
  for (int r = 0; r < 4; ++r) {
    long base = 1048576L + (long)(b*1024 + n0 + r)*1024;
    for (int j = 0; j < 4; ++j) {
      int m = t + 256*j;
      stout(dout, base + m, eacc[r][m], bf);
    }
  }
}

// ---------------- column (axis=1) stats, ddof=1 ----------------------------
__global__ __launch_bounds__(256) void colstatsA_kernel(const float* in, float* cs) {
  int t = threadIdx.x;
  int j = blockIdx.x & 15;
  int b = blockIdx.x >> 4;
  float s = 0, ss = 0;
  for (int n = j*64; n < j*64 + 64; ++n) {
    float v = in[(b*1024 + n)*256 + t];
    s += v; ss += v*v;
  }
  cs[(b*16 + j)*256 + t] = s;
  cs[16384 + (b*16 + j)*256 + t] = ss;
}

__global__ __launch_bounds__(256) void colstatsB_kernel(const float* cs, float* st) {
  int t = threadIdx.x;
  int b = blockIdx.x;
  float s = 0, ss = 0;
  for (int j = 0; j < 16; ++j) {
    s  += cs[(b*16 + j)*256 + t];
    ss += cs[16384 + (b*16 + j)*256 + t];
  }
  float mean = s * (1.0f/1024.0f);
  float var = fmaxf((ss - s*mean) * (1.0f/1023.0f), 0.0f);
  st[b*256 + t] = mean;
  st[1024 + b*256 + t] = 1.0f / (sqrtf(var) + 1e-6f);
}

// ---------------- row GEMM, bf16 quad weights ------------------------------
// IN_MODE 0: plain fp32 [row][256]; 1: fp32 + colnorm(st); 2: float-input src
//   permuted (n,b,e)->(b,n,e); 3: fp32 head-major [b][h][n][32]
// RN 1: fused rownorm on output
// OUTM 0: fp32 [row][256]; 1: d_out (dtype per flag); 2: fp32 head-major
template<int IN_MODE, int RN, int OUTM>
__global__ __launch_bounds__(256) void gemm_kernel(const void* inp,
    const unsigned short* wmat, const float* bias, const float* st, void* outp,
    const int* flagp) {
  const int bf = *flagp;
  int t = threadIdx.x;
  int r0 = blockIdx.x * 8;
  __shared__ __align__(16) float U[8][256];
  #pragma unroll
  for (int r = 0; r < 8; ++r) {
    int row = r0 + r;
    float v;
    if (IN_MODE == 0) {
      v = ((const float*)inp)[row*256 + t];
    } else if (IN_MODE == 1) {
      int b = row >> 10;
      v = (((const float*)inp)[row*256 + t] - st[b*256 + t]) * st[1024 + b*256 + t];
    } else if (IN_MODE == 2) {
      int b = row >> 10, n = row & 1023;
      v = ldin(inp, (long)(n*4 + b)*256 + t, bf);
    } else {
      int b = row >> 10, n = row & 1023;
      v = ((const float*)inp)[((b*8 + (t >> 5))*1024 + n)*32 + (t & 31)];
    }
    U[r][t] = v;
  }
  __syncthreads();
  float bv = bias[t];
  float acc[8];
  #pragma unroll
  for (int r = 0; r < 8; ++r) acc[r] = bv;
  const ushort4* w4 = (const ushort4*)wmat;
  for (int e4 = 0; e4 < 64; ++e4) {
    ushort4 u = w4[e4*256 + t];
    float w0 = bf2f(u.x), w1 = bf2f(u.y), w2 = bf2f(u.z), w3 = bf2f(u.w);
    #pragma unroll
    for (int r = 0; r < 8; ++r) {
      float4 uu = *(const float4*)&U[r][e4*4];
      acc[r] += uu.x*w0 + uu.y*w1 + uu.z*w2 + uu.w*w3;
    }
  }
  if (RN == 0) {
    #pragma unroll
    for (int r = 0; r < 8; ++r) {
      int row = r0 + r;
      if (OUTM == 0) ((float*)outp)[row*256 + t] = acc[r];
      else if (OUTM == 1) stout(outp, (long)row*256 + t, acc[r], bf);
      else {
        int b = row >> 10, n = row & 1023;
        ((float*)outp)[((b*8 + (t >> 5))*1024 + n)*32 + (t & 31)] = acc[r];
      }
    }
  } else {
    __syncthreads();
    #pragma unroll
    for (int r = 0; r < 8; ++r) U[r][t] = acc[r];
    __syncthreads();
    int w = t >> 6, lane = t & 63;
    for (int rr = w; rr < 8; rr += 4) {
      float vals[4]; float s = 0.0f;
      #pragma unroll
      for (int j = 0; j < 4; ++j) { vals[j] = U[rr][lane + 64*j]; s += vals[j]; }
      #pragma unroll
      for (int off = 32; off > 0; off >>= 1) s += __shfl_xor(s, off);
      float mean = s * (1.0f/256.0f);
      float ss = 0.0f;
      #pragma unroll
      for (int j = 0; j < 4; ++j) { float d = vals[j] - mean; ss += d*d; }
      #pragma unroll
      for (int off = 32; off > 0; off >>= 1) ss += __shfl_xor(ss, off);
      float inv = 1.0f / (sqrtf(ss * (1.0f/255.0f)) + 1e-6f);
      #pragma unroll
      for (int j = 0; j < 4; ++j)
        ((float*)outp)[(r0 + rr)*256 + lane + 64*j] = (vals[j] - mean) * inv;
    }
  }
}

// ---------------- standard MHA, head-major q/k/v/o -------------------------
// 1-D grid, XCD-swizzled (low 3 bits = head). 4 q-rows per block.
// QK: key-unrolled x4 (q LDS reads amortized). PV: (key-chunk, dim-quad)
// mapping with float4 V loads. Sp padded (chunk stride 40) and hp padded
// (stride 136) so all patterns are <=2-way bank aliasing (free).
#define SP_CS 40      // Sp chunk stride (words), 32 chunks
#define SP_RS 1280    // Sp row stride = 32*SP_CS
#define HP_CS 136     // hp per-chunk stride (4 rows * 32 dims + 8 pad)
__global__ __launch_bounds__(256) void attn2_kernel(float* ws) {
  int t = threadIdx.x;
  int gid = blockIdx.x;
  int h = gid & 7;
  int b = (gid >> 3) & 3;
  int n0 = (gid >> 5) << 2;
  __shared__ __align__(16) float Sp[4*SP_RS];
  __shared__ __align__(16) float hp[32*HP_CS];
  __shared__ __align__(16) float qs[4][32];
  float* qq = ws + A_OFF;
  const float* kk = ws + B_OFF;
  const float* vv = ws + C_OFF;
  int base_bh = (b*8 + h)*1024;
  int w = t >> 6, lane = t & 63;
  const float scl = 0.17677669529663687f; // 1/sqrt(32)
  if (t < 128) {
    int r = t >> 5, d = t & 31;
    qs[r][d] = qq[(base_bh + n0 + r)*32 + d];
  }
  __syncthreads();
  // ---- QK: thread owns keys {t, t+256, t+512, t+768} -----------------------
  {
    const float4* kp0 = (const float4*)(kk + (base_bh + t      )*32);
    const float4* kp1 = (const float4*)(kk + (base_bh + t + 256)*32);
    const float4* kp2 = (const float4*)(kk + (base_bh + t + 512)*32);
    const float4* kp3 = (const float4*)(kk + (base_bh + t + 768)*32);
    float acc[4][4] = {};
    #pragma unroll
    for (int p = 0; p < 8; ++p) {
      float4 k0 = kp0[p], k1 = kp1[p], k2 = kp2[p], k3 = kp3[p];
      #pragma unroll
      for (int r = 0; r < 4; ++r) {
        float4 q = *(const float4*)&qs[r][p*4];
        acc[0][r] += q.x*k0.x + q.y*k0.y + q.z*k0.z + q.w*k0.w;
        acc[1][r] += q.x*k1.x + q.y*k1.y + q.z*k1.z + q.w*k1.w;
        acc[2][r] += q.x*k2.x + q.y*k2.y + q.z*k2.z + q.w*k2.w;
        acc[3][r] += q.x*k3.x + q.y*k3.y + q.z*k3.z + q.w*k3.w;
      }
    }
    #pragma unroll
    for (int j = 0; j < 4; ++j) {
      int base = ((t >> 5) + 8*j)*SP_CS + (t & 31);
      #pragma unroll
      for (int r = 0; r < 4; ++r) Sp[r*SP_RS + base] = acc[j][r] * scl;
    }
  }
  __syncthreads();
  // ---- softmax: wave w <-> row w ------------------------------------------
  {
    float* Sr = Sp + w*SP_RS;
    float mx = -3.4e38f;
    #pragma unroll
    for (int j = 0; j < 16; ++j) {
      int m = lane + 64*j;
      mx = fmaxf(mx, Sr[(m >> 5)*SP_CS + (m & 31)]);
    }
    #pragma unroll
    for (int off = 32; off > 0; off >>= 1) mx = fmaxf(mx, __shfl_xor(mx, off));
    float s = 0.0f;
    #pragma unroll
    for (int j = 0; j < 16; ++j) {
      int m = lane + 64*j;
      int a = (m >> 5)*SP_CS + (m & 31);
      float p = __expf(Sr[a] - mx);
      Sr[a] = p;
      s += p;
    }
    #pragma unroll
    for (int off = 32; off > 0; off >>= 1) s += __shfl_xor(s, off);
    float rs = 1.0f / s;
    #pragma unroll
    for (int j = 0; j < 16; ++j) {
      int m = lane + 64*j;
      Sr[(m >> 5)*SP_CS + (m & 31)] *= rs;
    }
  }
  __syncthreads();
  // ---- PV: thread = (chunk c of 32 keys, dim-quad d4) ---------------------
  {
    int d4 = t & 7, c = t >> 3;
    const float* vbase = vv + base_bh*32 + d4*4;
    float4 o[4];
    #pragma unroll
    for (int r = 0; r < 4; ++r) { o[r].x = 0; o[r].y = 0; o[r].z = 0; o[r].w = 0; }
    #pragma unroll
    for (int mq = 0; mq < 8; ++mq) {
      int m = c*32 + mq*4;
      float4 v0 = *(const float4*)(vbase + (m+0)*32);
      float4 v1 = *(const float4*)(vbase + (m+1)*32);
      float4 v2 = *(const float4*)(vbase + (m+2)*32);
      float4 v3 = *(const float4*)(vbase + (m+3)*32);
      #pragma unroll
      for (int r = 0; r < 4; ++r) {
        float4 s = *(const float4*)&Sp[r*SP_RS + c*SP_CS + mq*4];
        o[r].x += s.x*v0.x + s.y*v1.x + s.z*v2.x + s.w*v3.x;
        o[r].y += s.x*v0.y + s.y*v1.y + s.z*v2.y + s.w*v3.y;
        o[r].z += s.x*v0.z + s.y*v1.z + s.z*v2.z + s.w*v3.z;
        o[r].w += s.x*v0.w + s.y*v1.w + s.z*v2.w + s.w*v3.w;
      }
    }
    #pragma unroll
    for (int r = 0; r < 4; ++r)
      *(float4*)&hp[c*HP_CS + r*32 + d4*4] = o[r];
  }
  __syncthreads();
  if (t < 128) {
    float sum = 0.0f;
    #pragma unroll 8
    for (int c2 = 0; c2 < 32; ++c2) sum += hp[c2*HP_CS + t];
    int r = t >> 5, d = t & 31;
    qq[(base_bh + n0 + r)*32 + d] = sum;   // o over q (own slots)
  }
}

extern "C" void kernel_launch(void* const* d_in, const int* in_sizes, int n_in,
                              void* d_out, int out_size, void* d_ws, size_t ws_size,
                              hipStream_t stream) {
  const void* x   = d_in[0];
  const void* src = d_in[1];
  const int* adj  = (const int*)d_in[2];
  const void* wg  = d_in[3];
  const void* a1  = d_in[4];
  const void* a2  = d_in[5];
  const void* lw  = d_in[6];
  const void* lb  = d_in[7];
  const void* ipw = d_in[8];
  const void* ipb = d_in[9];
  const void* opw = d_in[10];
  const void* opb = d_in[11];
  float* ws = (float*)d_ws;
  const unsigned short* wbf = (const unsigned short*)d_ws;
  int* flagp = (int*)(ws + FLAG_F);

  detect_kernel<<<1, 64, 0, stream>>>((const unsigned short*)x, flagp);
  prep_kernel<<<dim3(256, 7), 256, 0, stream>>>(wg, lw, ipw, opw, lb, ipb, opb,
                                                a1, a2, ws, flagp);
  whs_kernel<<<512, 256, 0, stream>>>(x, ws, flagp);
  attn1_kernel<<<1024, 256, 0, stream>>>(x, adj, ws, d_out, flagp);
  colstatsA_kernel<<<64, 256, 0, stream>>>(ws + B_OFF, ws + CS_OFF);
  colstatsB_kernel<<<4, 256, 0, stream>>>(ws + CS_OFF, ws + ST1_OFF);
  gemm_kernel<1,1,0><<<512, 256, 0, stream>>>(ws + B_OFF, wbf + 1*65536,
      ws + BIAS_OFF, ws + ST1_OFF, ws + C_OFF, flagp);
  colstatsA_kernel<<<64, 256, 0, stream>>>(ws + C_OFF, ws + CS_OFF);
  colstatsB_kernel<<<4, 256, 0, stream>>>(ws + CS_OFF, ws + ST2_OFF);
  gemm_kernel<1,0,2><<<512, 256, 0, stream>>>(ws + C_OFF, wbf + 2*65536,
      ws + BIAS_OFF + 256, ws + ST2_OFF, ws + A_OFF, flagp);   // Q head-major
  gemm_kernel<1,0,2><<<512, 256, 0, stream>>>(ws + C_OFF, wbf + 3*65536,
      ws + BIAS_OFF + 512, ws + ST2_OFF, ws + B_OFF, flagp);   // K head-major
  gemm_kernel<2,0,2><<<512, 256, 0, stream>>>(src, wbf + 4*65536,
      ws + BIAS_OFF + 768, nullptr, ws + C_OFF, flagp);        // V head-major
  attn2_kernel<<<8192, 256, 0, stream>>>(ws);                  // o -> A_OFF
  gemm_kernel<3,0,1><<<512, 256, 0, stream>>>(ws + A_OFF, wbf + 5*65536,
      ws + BIAS_OFF + 1024, nullptr, d_out, flagp);            // out-proj
}

// Round 10
// 431.037 us; speedup vs baseline: 1.9640x; 1.2063x over previous
//
#include <hip/hip_runtime.h>
#include <hip/hip_bf16.h>

// B=4, N=1024, E=256, H=8, D=32. Float tensors may be bf16 OR fp32 in d_in /
// d_out (detected at runtime on-device); adj is int32.
// Output: x_out [4,1024,256] then e_out [4,1024,1024] (element offsets).
//
// ws float offsets:
//   [0 .. 196608)   : 6 weight matrices, transposed, bf16, quad-interleaved
//                     matrix m at ushort offset m*65536; element (e,o) at
//                     ((e>>2)*256 + o)*4 + (e&3).  m: 0=Wcat 1=LIN 2=WQ 3=WK 4=WV 5=WO
#define BIAS_OFF 196608   // lin_b, bq, bk, bv, bo, a1, a2  (7*256 fp32)
#define S1_OFF   198400   // [h][4096]
#define S2_OFF   231168
#define CS_OFF   263936   // 32768: column partial sums+sumsq (reused twice)
#define ST1_OFF  296704   // mean[1024] + inv[1024]
#define ST2_OFF  298752
#define A_OFF    300800   // 4 MB: Wh [h][row][32] -> later Q,o fp32 head-major
#define B_OFF    1349376  // 4 MB: rownorm(xa)     -> later K bf16 head-major
#define C_OFF    2397952  // 4 MB: rownorm(lin)    -> later V bf16 head-major
#define FLAG_F   3446528  // int: 1 = bf16 tensors, 0 = fp32 tensors
// end 3446529 floats = 13.8 MB

#define NEGC (-9.0e15f)

static __device__ __forceinline__ float bf2f(unsigned short u) {
  union { unsigned int i; float f; } v; v.i = ((unsigned int)u) << 16; return v.f;
}
static __device__ __forceinline__ unsigned short f2bf(float f) {
  union { float f; unsigned int u; } v; v.f = f;
  unsigned int r = (v.u + 0x7FFFu + ((v.u >> 16) & 1u)) >> 16;   // RNE
  return (unsigned short)r;
}
static __device__ __forceinline__ float ldin(const void* p, long i, int bf) {
  return bf ? bf2f(((const unsigned short*)p)[i]) : ((const float*)p)[i];
}
static __device__ __forceinline__ unsigned short rdbf(const void* p, long i, int bf) {
  if (bf) return ((const unsigned short*)p)[i];
  return f2bf(((const float*)p)[i]);
}
static __device__ __forceinline__ void stout(void* p, long i, float v, int bf) {
  if (bf) ((unsigned short*)p)[i] = f2bf(v);
  else    ((float*)p)[i] = v;
}

// ---------------- dtype detector -------------------------------------------
__global__ __launch_bounds__(64) void detect_kernel(const unsigned short* x, int* flag) {
  int lane = threadIdx.x;
  unsigned short u = x[2 * lane];
  int e = (u >> 7) & 0xFF;
  bool good = (e >= 100 && e <= 140);
  unsigned long long m = __ballot(good);
  if (lane == 0) *flag = (__popcll(m) >= 48) ? 1 : 0;
}

// ---------------- prep: weights -> transposed quad bf16; biases -> fp32 ----
__global__ __launch_bounds__(256) void prep_kernel(
    const void* wg, const void* lin_w, const void* inp_w, const void* out_w,
    const void* lin_b, const void* inp_b, const void* out_b,
    const void* a1, const void* a2, float* ws, const int* flagp) {
  const int bf = *flagp;
  unsigned short* wbf = (unsigned short*)ws;
  int t = threadIdx.x;
  int f = blockIdx.x;
  int m = blockIdx.y;
  int dst = m*65536 + ((f >> 2)*256 + t)*4 + (f & 3);
  if (m == 0) {
    int h = t >> 5, d = t & 31;
    wbf[dst] = rdbf(wg, h*8192 + f*32 + d, bf);
  } else if (m == 1) wbf[dst] = rdbf(lin_w, t*256 + f, bf);
  else if (m == 2)   wbf[dst] = rdbf(inp_w, t*256 + f, bf);
  else if (m == 3)   wbf[dst] = rdbf(inp_w, (256 + t)*256 + f, bf);
  else if (m == 4)   wbf[dst] = rdbf(inp_w, (512 + t)*256 + f, bf);
  else if (m == 5)   wbf[dst] = rdbf(out_w, t*256 + f, bf);
  else if (f == 0) {
    ws[BIAS_OFF + t]        = ldin(lin_b, t, bf);
    ws[BIAS_OFF + 256 + t]  = ldin(inp_b, t, bf);
    ws[BIAS_OFF + 512 + t]  = ldin(inp_b, 256 + t, bf);
    ws[BIAS_OFF + 768 + t]  = ldin(inp_b, 512 + t, bf);
    ws[BIAS_OFF + 1024 + t] = ldin(out_b, t, bf);
    ws[BIAS_OFF + 1280 + t] = ldin(a1, t, bf);
    ws[BIAS_OFF + 1536 + t] = ldin(a2, t, bf);
  }
}

// ---------------- Wh = x @ Wcat, plus s1/s2 head reductions ----------------
__global__ __launch_bounds__(256) void whs_kernel(const void* x, float* ws,
                                                  const int* flagp) {
  const int bf = *flagp;
  int t = threadIdx.x;
  int r0 = blockIdx.x * 8;
  __shared__ __align__(16) float U[8][256];
  #pragma unroll
  for (int r = 0; r < 8; ++r)
    U[r][t] = ldin(x, (long)(r0 + r)*256 + t, bf);
  __syncthreads();
  const ushort4* w4 = (const ushort4*)ws;
  float acc[8] = {0,0,0,0,0,0,0,0};
  for (int e4 = 0; e4 < 64; ++e4) {
    ushort4 u = w4[e4*256 + t];
    float w0 = bf2f(u.x), w1 = bf2f(u.y), w2 = bf2f(u.z), w3 = bf2f(u.w);
    #pragma unroll
    for (int r = 0; r < 8; ++r) {
      float4 uu = *(const float4*)&U[r][e4*4];
      acc[r] += uu.x*w0 + uu.y*w1 + uu.z*w2 + uu.w*w3;
    }
  }
  int h = t >> 5, d = t & 31;
  float a1v = ws[BIAS_OFF + 1280 + t];
  float a2v = ws[BIAS_OFF + 1536 + t];
  #pragma unroll
  for (int r = 0; r < 8; ++r) {
    int row = r0 + r;
    ws[A_OFF + h*131072 + row*32 + d] = acc[r];
    float p1 = acc[r]*a1v, p2 = acc[r]*a2v;
    #pragma unroll
    for (int off = 16; off > 0; off >>= 1) {
      p1 += __shfl_xor(p1, off, 32);
      p2 += __shfl_xor(p2, off, 32);
    }
    if (d == 0) {
      ws[S1_OFF + h*4096 + row] = p1;
      ws[S2_OFF + h*4096 + row] = p2;
    }
  }
}

// ------- graph attention + residual + fused rownorm; e_out = mean_h attn ---
// 1-D grid, XCD-swizzled: low 3 bits = (b*2 + n0-parity) so each XCD's L2
// serves one batch's Wh working set (~1 MB << 4 MB).
__global__ __launch_bounds__(256) void attn1_kernel(const void* x, const int* adj,
                                                    float* ws, void* dout,
                                                    const int* flagp) {
  const int bf = *flagp;
  int t = threadIdx.x;
  int gid = blockIdx.x;
  int b = (gid >> 1) & 3;
  int n0 = ((((gid >> 3) << 1) | (gid & 1))) * 4;
  __shared__ __align__(16) float Sp[4][1024];
  __shared__ float eacc[4][1024];
  __shared__ float s2s[1024];
  __shared__ unsigned char adjm[4][1024];
  __shared__ float s1s[4];
  __shared__ float hpred[32][32];
  __shared__ __align__(16) float xrow[4][256];
  float* eaccf = &eacc[0][0];
  for (int i = t; i < 4096; i += 256) eaccf[i] = 0.0f;
  for (int r = 0; r < 4; ++r) {
    int base = (b*1024 + n0 + r) * 1024;
    for (int j = 0; j < 4; ++j) {
      int m = t + 256*j;
      adjm[r][m] = (adj[base + m] > 0) ? 1 : 0;
    }
  }
  int w = t >> 6, lane = t & 63;
  for (int h = 0; h < 8; ++h) {
    const float* s2p = ws + S2_OFF + h*4096 + b*1024;
    for (int j = 0; j < 4; ++j) s2s[t + 256*j] = s2p[t + 256*j];
    if (t < 4) s1s[t] = ws[S1_OFF + h*4096 + b*1024 + n0 + t];
    __syncthreads();
    #pragma unroll
    for (int r = 0; r < 4; ++r) {
      float s1v = s1s[r];
      for (int j = 0; j < 4; ++j) {
        int m = t + 256*j;
        float ev = s1v + s2s[m];
        ev = (ev >= 0.0f) ? ev : 0.1f*ev;
        Sp[r][m] = adjm[r][m] ? ev : NEGC;
      }
    }
    __syncthreads();
    float* Sr = Sp[w];
    float mx = -3.4e38f;
    for (int j = 0; j < 16; ++j) mx = fmaxf(mx, Sr[lane + 64*j]);
    #pragma unroll
    for (int off = 32; off > 0; off >>= 1) mx = fmaxf(mx, __shfl_xor(mx, off));
    float s = 0.0f;
    for (int j = 0; j < 16; ++j) {
      float p = __expf(Sr[lane + 64*j] - mx);
      Sr[lane + 64*j] = p;
      s += p;
    }
    #pragma unroll
    for (int off = 32; off > 0; off >>= 1) s += __shfl_xor(s, off);
    float rs = 1.0f / s;
    for (int j = 0; j < 16; ++j) {
      float p = Sr[lane + 64*j] * rs;
      Sr[lane + 64*j] = p;
      eacc[w][lane + 64*j] += 0.125f * p;
    }
    __syncthreads();
    int d = t & 31, c = t >> 5;
    const float* whp = ws + A_OFF + h*131072 + b*32768;
    float a0 = 0, a1r = 0, a2r = 0, a3r = 0;
    int mbase = c*128;
    #pragma unroll 4
    for (int mq = 0; mq < 32; ++mq) {
      int m = mbase + mq*4;
      float4 s0 = *(const float4*)&Sp[0][m];
      float4 s1 = *(const float4*)&Sp[1][m];
      float4 s2 = *(const float4*)&Sp[2][m];
      float4 s3 = *(const float4*)&Sp[3][m];
      float w0 = whp[(m+0)*32 + d];
      float w1 = whp[(m+1)*32 + d];
      float w2 = whp[(m+2)*32 + d];
      float w3 = whp[(m+3)*32 + d];
      a0  += s0.x*w0 + s0.y*w1 + s0.z*w2 + s0.w*w3;
      a1r += s1.x*w0 + s1.y*w1 + s1.z*w2 + s1.w*w3;
      a2r += s2.x*w0 + s2.y*w1 + s2.z*w2 + s2.w*w3;
      a3r += s3.x*w0 + s3.y*w1 + s3.z*w2 + s3.w*w3;
    }
    hpred[c*4+0][d] = a0;  hpred[c*4+1][d] = a1r;
    hpred[c*4+2][d] = a2r; hpred[c*4+3][d] = a3r;
    __syncthreads();
    if (t < 128) {
      int r = t >> 5, dd = t & 31;
      float sum = 0.0f;
      #pragma unroll
      for (int c8 = 0; c8 < 8; ++c8) sum += hpred[c8*4 + r][dd];
      float hv = (sum >= 0.0f) ? sum : 0.01f*sum;
      long idx = (long)(b*1024 + n0 + r)*256 + h*32 + dd;
      xrow[r][h*32 + dd] = ldin(x, idx, bf) + hv;
    }
    __syncthreads();
  }
  // fused rownorm (ddof=1): wave w handles row w
  float vals[4]; float s = 0.0f;
  #pragma unroll
  for (int j = 0; j < 4; ++j) { vals[j] = xrow[w][lane + 64*j]; s += vals[j]; }
  #pragma unroll
  for (int off = 32; off > 0; off >>= 1) s += __shfl_xor(s, off);
  float mean = s * (1.0f/256.0f);
  float ss = 0.0f;
  #pragma unroll
  for (int j = 0; j < 4; ++j) { float d = vals[j] - mean; ss += d*d; }
  #pragma unroll
  for (int off = 32; off > 0; off >>= 1) ss += __shfl_xor(ss, off);
  float inv = 1.0f / (sqrtf(ss * (1.0f/255.0f)) + 1e-6f);
  float* Bp = ws + B_OFF + (b*1024 + n0 + w)*256;
  #pragma unroll
  for (int j = 0; j < 4; ++j) Bp[lane + 64*j] = (vals[j] - mean) * inv;
  for (int r = 0; r < 4; ++r) {
    long base = 1048576L + (long)(b*1024 + n0 + r)*1024;
    for (int j = 0; j < 4; ++j) {
      int m = t + 256*j;
      stout(dout, base + m, eacc[r][m], bf);
    }
  }
}

// ---------------- column (axis=1) stats, ddof=1 ----------------------------
__global__ __launch_bounds__(256) void colstatsA_kernel(const float* in, float* cs) {
  int t = threadIdx.x;
  int j = blockIdx.x & 15;
  int b = blockIdx.x >> 4;
  float s = 0, ss = 0;
  for (int n = j*64; n < j*64 + 64; ++n) {
    float v = in[(b*1024 + n)*256 + t];
    s += v; ss += v*v;
  }
  cs[(b*16 + j)*256 + t] = s;
  cs[16384 + (b*16 + j)*256 + t] = ss;
}

__global__ __launch_bounds__(256) void colstatsB_kernel(const float* cs, float* st) {
  int t = threadIdx.x;
  int b = blockIdx.x;
  float s = 0, ss = 0;
  for (int j = 0; j < 16; ++j) {
    s  += cs[(b*16 + j)*256 + t];
    ss += cs[16384 + (b*16 + j)*256 + t];
  }
  float mean = s * (1.0f/1024.0f);
  float var = fmaxf((ss - s*mean) * (1.0f/1023.0f), 0.0f);
  st[b*256 + t] = mean;
  st[1024 + b*256 + t] = 1.0f / (sqrtf(var) + 1e-6f);
}

// ---------------- row GEMM, bf16 quad weights ------------------------------
// IN_MODE 0: plain fp32 [row][256]; 1: fp32 + colnorm(st); 2: float-input src
//   permuted (n,b,e)->(b,n,e); 3: fp32 head-major [b][h][n][32]
// RN 1: fused rownorm on output
// OUTM 0: fp32 [row][256]; 1: d_out (dtype per flag); 2: fp32 head-major;
//      3: bf16 head-major (ushort)
template<int IN_MODE, int RN, int OUTM>
__global__ __launch_bounds__(256) void gemm_kernel(const void* inp,
    const unsigned short* wmat, const float* bias, const float* st, void* outp,
    const int* flagp) {
  const int bf = *flagp;
  int t = threadIdx.x;
  int r0 = blockIdx.x * 8;
  __shared__ __align__(16) float U[8][256];
  #pragma unroll
  for (int r = 0; r < 8; ++r) {
    int row = r0 + r;
    float v;
    if (IN_MODE == 0) {
      v = ((const float*)inp)[row*256 + t];
    } else if (IN_MODE == 1) {
      int b = row >> 10;
      v = (((const float*)inp)[row*256 + t] - st[b*256 + t]) * st[1024 + b*256 + t];
    } else if (IN_MODE == 2) {
      int b = row >> 10, n = row & 1023;
      v = ldin(inp, (long)(n*4 + b)*256 + t, bf);
    } else {
      int b = row >> 10, n = row & 1023;
      v = ((const float*)inp)[((b*8 + (t >> 5))*1024 + n)*32 + (t & 31)];
    }
    U[r][t] = v;
  }
  __syncthreads();
  float bv = bias[t];
  float acc[8];
  #pragma unroll
  for (int r = 0; r < 8; ++r) acc[r] = bv;
  const ushort4* w4 = (const ushort4*)wmat;
  for (int e4 = 0; e4 < 64; ++e4) {
    ushort4 u = w4[e4*256 + t];
    float w0 = bf2f(u.x), w1 = bf2f(u.y), w2 = bf2f(u.z), w3 = bf2f(u.w);
    #pragma unroll
    for (int r = 0; r < 8; ++r) {
      float4 uu = *(const float4*)&U[r][e4*4];
      acc[r] += uu.x*w0 + uu.y*w1 + uu.z*w2 + uu.w*w3;
    }
  }
  if (RN == 0) {
    #pragma unroll
    for (int r = 0; r < 8; ++r) {
      int row = r0 + r;
      if (OUTM == 0) ((float*)outp)[row*256 + t] = acc[r];
      else if (OUTM == 1) stout(outp, (long)row*256 + t, acc[r], bf);
      else if (OUTM == 2) {
        int b = row >> 10, n = row & 1023;
        ((float*)outp)[((b*8 + (t >> 5))*1024 + n)*32 + (t & 31)] = acc[r];
      } else {
        int b = row >> 10, n = row & 1023;
        ((unsigned short*)outp)[((b*8 + (t >> 5))*1024 + n)*32 + (t & 31)] = f2bf(acc[r]);
      }
    }
  } else {
    __syncthreads();
    #pragma unroll
    for (int r = 0; r < 8; ++r) U[r][t] = acc[r];
    __syncthreads();
    int w = t >> 6, lane = t & 63;
    for (int rr = w; rr < 8; rr += 4) {
      float vals[4]; float s = 0.0f;
      #pragma unroll
      for (int j = 0; j < 4; ++j) { vals[j] = U[rr][lane + 64*j]; s += vals[j]; }
      #pragma unroll
      for (int off = 32; off > 0; off >>= 1) s += __shfl_xor(s, off);
      float mean = s * (1.0f/256.0f);
      float ss = 0.0f;
      #pragma unroll
      for (int j = 0; j < 4; ++j) { float d = vals[j] - mean; ss += d*d; }
      #pragma unroll
      for (int off = 32; off > 0; off >>= 1) ss += __shfl_xor(ss, off);
      float inv = 1.0f / (sqrtf(ss * (1.0f/255.0f)) + 1e-6f);
      #pragma unroll
      for (int j = 0; j < 4; ++j)
        ((float*)outp)[(r0 + rr)*256 + lane + 64*j] = (vals[j] - mean) * inv;
    }
  }
}

// ---------------- standard MHA, bf16 K/V, 8 q-rows per block ---------------
// GRID MUST BE 4096: 128 row-groups x 4 b x 8 h (R8/R9 launched 2048 ->
// rows 512..1023 got no attention output; that was the 3.4 absmax bug).
// 1-D grid, XCD-swizzled (low 3 bits = head). Q fp32 head-major at A_OFF
// (o overwrites q, exclusive slots); K,V bf16 head-major at B_OFF/C_OFF.
// SP_CS is a multiple of 4 (PV float4 reads at c*SP_CS + mq*4 stay 16B-aligned).
#define SP_CS 36      // chunk stride (words): 32 data + 4 pad
#define SP_RS 1152    // row stride = 32*SP_CS
__global__ __launch_bounds__(256) void attn2_kernel(float* ws) {
  int t = threadIdx.x;
  int gid = blockIdx.x;
  int h = gid & 7;
  int b = (gid >> 3) & 3;
  int n0 = (gid >> 5) << 3;   // 8 q-rows per block; gid>>5 in 0..127
  __shared__ __align__(16) float Sp[8*SP_RS];
  __shared__ __align__(16) float qs[8][32];
  __shared__ __align__(16) float hpw[4][8][32];
  float* qq = ws + A_OFF;
  const unsigned short* kk = (const unsigned short*)(ws + B_OFF);
  const unsigned short* vv = (const unsigned short*)(ws + C_OFF);
  int base_bh = (b*8 + h)*1024;
  int w = t >> 6, lane = t & 63;
  const float scl = 0.17677669529663687f; // 1/sqrt(32)
  qs[t >> 5][t & 31] = qq[(base_bh + n0 + (t >> 5))*32 + (t & 31)];
  __syncthreads();
  // ---- QK: thread owns keys {t, t+256, t+512, t+768} ----------------------
  {
    float acc[4][8] = {};
    #pragma unroll
    for (int p = 0; p < 8; ++p) {
      float4 kf[4];
      #pragma unroll
      for (int j = 0; j < 4; ++j) {
        ushort4 u = *(const ushort4*)(kk + (base_bh + t + 256*j)*32 + p*4);
        kf[j].x = bf2f(u.x); kf[j].y = bf2f(u.y);
        kf[j].z = bf2f(u.z); kf[j].w = bf2f(u.w);
      }
      #pragma unroll
      for (int r = 0; r < 8; ++r) {
        float4 q = *(const float4*)&qs[r][p*4];
        #pragma unroll
        for (int j = 0; j < 4; ++j)
          acc[j][r] += q.x*kf[j].x + q.y*kf[j].y + q.z*kf[j].z + q.w*kf[j].w;
      }
    }
    #pragma unroll
    for (int j = 0; j < 4; ++j) {
      int key = t + 256*j;
      int base = (key >> 5)*SP_CS + (key & 31);
      #pragma unroll
      for (int r = 0; r < 8; ++r)
        Sp[r*SP_RS + base] = acc[j][r] * scl;
    }
  }
  __syncthreads();
  // ---- softmax: wave w handles rows w and w+4 -----------------------------
  #pragma unroll
  for (int rr = 0; rr < 2; ++rr) {
    float* Sr = Sp + (w + 4*rr)*SP_RS;
    float mx = -3.4e38f;
    #pragma unroll
    for (int j = 0; j < 16; ++j) {
      int m = lane + 64*j;
      mx = fmaxf(mx, Sr[(m >> 5)*SP_CS + (m & 31)]);
    }
    #pragma unroll
    for (int off = 32; off > 0; off >>= 1) mx = fmaxf(mx, __shfl_xor(mx, off));
    float s = 0.0f;
    #pragma unroll
    for (int j = 0; j < 16; ++j) {
      int m = lane + 64*j;
      int a = (m >> 5)*SP_CS + (m & 31);
      float p = __expf(Sr[a] - mx);
      Sr[a] = p;
      s += p;
    }
    #pragma unroll
    for (int off = 32; off > 0; off >>= 1) s += __shfl_xor(s, off);
    float rs = 1.0f / s;
    #pragma unroll
    for (int j = 0; j < 16; ++j) {
      int m = lane + 64*j;
      Sr[(m >> 5)*SP_CS + (m & 31)] *= rs;
    }
  }
  __syncthreads();
  // ---- PV: thread = (chunk c of 32 keys, dim-quad d4) ---------------------
  {
    int d4 = t & 7, c = t >> 3;
    const unsigned short* vbase = vv + base_bh*32 + d4*4;
    float4 o[8] = {};
    #pragma unroll
    for (int mq = 0; mq < 8; ++mq) {
      int m = c*32 + mq*4;
      float4 v0, v1, v2, v3;
      {
        ushort4 u0 = *(const ushort4*)(vbase + (m+0)*32);
        ushort4 u1 = *(const ushort4*)(vbase + (m+1)*32);
        ushort4 u2 = *(const ushort4*)(vbase + (m+2)*32);
        ushort4 u3 = *(const ushort4*)(vbase + (m+3)*32);
        v0.x = bf2f(u0.x); v0.y = bf2f(u0.y); v0.z = bf2f(u0.z); v0.w = bf2f(u0.w);
        v1.x = bf2f(u1.x); v1.y = bf2f(u1.y); v1.z = bf2f(u1.z); v1.w = bf2f(u1.w);
        v2.x = bf2f(u2.x); v2.y = bf2f(u2.y); v2.z = bf2f(u2.z); v2.w = bf2f(u2.w);
        v3.x = bf2f(u3.x); v3.y = bf2f(u3.y); v3.z = bf2f(u3.z); v3.w = bf2f(u3.w);
      }
      #pragma unroll
      for (int r = 0; r < 8; ++r) {
        float4 s = *(const float4*)&Sp[r*SP_RS + c*SP_CS + mq*4];
        o[r].x += s.x*v0.x + s.y*v1.x + s.z*v2.x + s.w*v3.x;
        o[r].y += s.x*v0.y + s.y*v1.y + s.z*v2.y + s.w*v3.y;
        o[r].z += s.x*v0.z + s.y*v1.z + s.z*v2.z + s.w*v3.z;
        o[r].w += s.x*v0.w + s.y*v1.w + s.z*v2.w + s.w*v3.w;
      }
    }
    // butterfly over lane bits 3..5 (the 8 chunks resident in this wave)
    #pragma unroll
    for (int off = 8; off <= 32; off <<= 1) {
      #pragma unroll
      for (int r = 0; r < 8; ++r) {
        o[r].x += __shfl_xor(o[r].x, off);
        o[r].y += __shfl_xor(o[r].y, off);
        o[r].z += __shfl_xor(o[r].z, off);
        o[r].w += __shfl_xor(o[r].w, off);
      }
    }
    if (lane < 8) {     // lane == d4 for these lanes
      #pragma unroll
      for (int r = 0; r < 8; ++r)
        *(float4*)&hpw[w][r][lane*4] = o[r];
    }
  }
  __syncthreads();
  {
    int r = t >> 5, d = t & 31;
    float sum = hpw[0][r][d] + hpw[1][r][d] + hpw[2][r][d] + hpw[3][r][d];
    qq[(base_bh + n0 + r)*32 + d] = sum;   // o over q (own slots)
  }
}

extern "C" void kernel_launch(void* const* d_in, const int* in_sizes, int n_in,
                              void* d_out, int out_size, void* d_ws, size_t ws_size,
                              hipStream_t stream) {
  const void* x   = d_in[0];
  const void* src = d_in[1];
  const int* adj  = (const int*)d_in[2];
  const void* wg  = d_in[3];
  const void* a1  = d_in[4];
  const void* a2  = d_in[5];
  const void* lw  = d_in[6];
  const void* lb  = d_in[7];
  const void* ipw = d_in[8];
  const void* ipb = d_in[9];
  const void* opw = d_in[10];
  const void* opb = d_in[11];
  float* ws = (float*)d_ws;
  const unsigned short* wbf = (const unsigned short*)d_ws;
  int* flagp = (int*)(ws + FLAG_F);

  detect_kernel<<<1, 64, 0, stream>>>((const unsigned short*)x, flagp);
  prep_kernel<<<dim3(256, 7), 256, 0, stream>>>(wg, lw, ipw, opw, lb, ipb, opb,
                                                a1, a2, ws, flagp);
  whs_kernel<<<512, 256, 0, stream>>>(x, ws, flagp);
  attn1_kernel<<<1024, 256, 0, stream>>>(x, adj, ws, d_out, flagp);
  colstatsA_kernel<<<64, 256, 0, stream>>>(ws + B_OFF, ws + CS_OFF);
  colstatsB_kernel<<<4, 256, 0, stream>>>(ws + CS_OFF, ws + ST1_OFF);
  gemm_kernel<1,1,0><<<512, 256, 0, stream>>>(ws + B_OFF, wbf + 1*65536,
      ws + BIAS_OFF, ws + ST1_OFF, ws + C_OFF, flagp);
  colstatsA_kernel<<<64, 256, 0, stream>>>(ws + C_OFF, ws + CS_OFF);
  colstatsB_kernel<<<4, 256, 0, stream>>>(ws + CS_OFF, ws + ST2_OFF);
  gemm_kernel<1,0,2><<<512, 256, 0, stream>>>(ws + C_OFF, wbf + 2*65536,
      ws + BIAS_OFF + 256, ws + ST2_OFF, ws + A_OFF, flagp);   // Q fp32 hm
  gemm_kernel<1,0,3><<<512, 256, 0, stream>>>(ws + C_OFF, wbf + 3*65536,
      ws + BIAS_OFF + 512, ws + ST2_OFF, ws + B_OFF, flagp);   // K bf16 hm
  gemm_kernel<2,0,3><<<512, 256, 0, stream>>>(src, wbf + 4*65536,
      ws + BIAS_OFF + 768, nullptr, ws + C_OFF, flagp);        // V bf16 hm
  attn2_kernel<<<4096, 256, 0, stream>>>(ws);                  // o -> A_OFF
  gemm_kernel<3,0,1><<<512, 256, 0, stream>>>(ws + A_OFF, wbf + 5*65536,
      ws + BIAS_OFF + 1024, nullptr, d_out, flagp);            // out-proj
}

// Round 11
// 418.583 us; speedup vs baseline: 2.0225x; 1.0298x over previous
//
#include <hip/hip_runtime.h>
#include <hip/hip_bf16.h>

// B=4, N=1024, E=256, H=8, D=32. Float tensors may be bf16 OR fp32 in d_in /
// d_out (detected at runtime on-device); adj is int32.
// Output: x_out [4,1024,256] then e_out [4,1024,1024] (element offsets).
//
// ws float offsets:
//   [0 .. 196608)   : 6 weight matrices, transposed, bf16, quad-interleaved
//                     matrix m at ushort offset m*65536; element (e,o) at
//                     ((e>>2)*256 + o)*4 + (e&3).  m: 0=Wcat 1=LIN 2=WQ 3=WK 4=WV 5=WO
#define BIAS_OFF 196608   // lin_b, bq, bk, bv, bo, a1, a2  (7*256 fp32)
#define S1_OFF   198400   // [h][4096]
#define S2_OFF   231168
#define CS_OFF   263936   // 32768: column partial sums+sumsq (reused twice)
#define ST1_OFF  296704   // mean[1024] + inv[1024]
#define ST2_OFF  298752
#define A_OFF    300800   // 4 MB: Wh [h][row][32] -> later Q,o fp32 head-major
#define B_OFF    1349376  // 4 MB: rownorm(xa)     -> later K bf16 head-major
#define C_OFF    2397952  // 4 MB: rownorm(lin)    -> later V bf16 head-major
#define FLAG_F   3446528  // int: 1 = bf16 tensors, 0 = fp32 tensors
// end 3446529 floats = 13.8 MB

#define NEGC (-9.0e15f)

static __device__ __forceinline__ float bf2f(unsigned short u) {
  union { unsigned int i; float f; } v; v.i = ((unsigned int)u) << 16; return v.f;
}
static __device__ __forceinline__ unsigned short f2bf(float f) {
  union { float f; unsigned int u; } v; v.f = f;
  unsigned int r = (v.u + 0x7FFFu + ((v.u >> 16) & 1u)) >> 16;   // RNE
  return (unsigned short)r;
}
static __device__ __forceinline__ float ldin(const void* p, long i, int bf) {
  return bf ? bf2f(((const unsigned short*)p)[i]) : ((const float*)p)[i];
}
static __device__ __forceinline__ unsigned short rdbf(const void* p, long i, int bf) {
  if (bf) return ((const unsigned short*)p)[i];
  return f2bf(((const float*)p)[i]);
}
static __device__ __forceinline__ void stout(void* p, long i, float v, int bf) {
  if (bf) ((unsigned short*)p)[i] = f2bf(v);
  else    ((float*)p)[i] = v;
}

// ---------------- dtype detector -------------------------------------------
__global__ __launch_bounds__(64) void detect_kernel(const unsigned short* x, int* flag) {
  int lane = threadIdx.x;
  unsigned short u = x[2 * lane];
  int e = (u >> 7) & 0xFF;
  bool good = (e >= 100 && e <= 140);
  unsigned long long m = __ballot(good);
  if (lane == 0) *flag = (__popcll(m) >= 48) ? 1 : 0;
}

// ---------------- prep: weights -> transposed quad bf16; biases -> fp32 ----
__global__ __launch_bounds__(256) void prep_kernel(
    const void* wg, const void* lin_w, const void* inp_w, const void* out_w,
    const void* lin_b, const void* inp_b, const void* out_b,
    const void* a1, const void* a2, float* ws, const int* flagp) {
  const int bf = *flagp;
  unsigned short* wbf = (unsigned short*)ws;
  int t = threadIdx.x;
  int f = blockIdx.x;
  int m = blockIdx.y;
  int dst = m*65536 + ((f >> 2)*256 + t)*4 + (f & 3);
  if (m == 0) {
    int h = t >> 5, d = t & 31;
    wbf[dst] = rdbf(wg, h*8192 + f*32 + d, bf);
  } else if (m == 1) wbf[dst] = rdbf(lin_w, t*256 + f, bf);
  else if (m == 2)   wbf[dst] = rdbf(inp_w, t*256 + f, bf);
  else if (m == 3)   wbf[dst] = rdbf(inp_w, (256 + t)*256 + f, bf);
  else if (m == 4)   wbf[dst] = rdbf(inp_w, (512 + t)*256 + f, bf);
  else if (m == 5)   wbf[dst] = rdbf(out_w, t*256 + f, bf);
  else if (f == 0) {
    ws[BIAS_OFF + t]        = ldin(lin_b, t, bf);
    ws[BIAS_OFF + 256 + t]  = ldin(inp_b, t, bf);
    ws[BIAS_OFF + 512 + t]  = ldin(inp_b, 256 + t, bf);
    ws[BIAS_OFF + 768 + t]  = ldin(inp_b, 512 + t, bf);
    ws[BIAS_OFF + 1024 + t] = ldin(out_b, t, bf);
    ws[BIAS_OFF + 1280 + t] = ldin(a1, t, bf);
    ws[BIAS_OFF + 1536 + t] = ldin(a2, t, bf);
  }
}

// ---------------- Wh = x @ Wcat, plus s1/s2 head reductions ----------------
__global__ __launch_bounds__(256) void whs_kernel(const void* x, float* ws,
                                                  const int* flagp) {
  const int bf = *flagp;
  int t = threadIdx.x;
  int r0 = blockIdx.x * 8;
  __shared__ __align__(16) float U[8][256];
  #pragma unroll
  for (int r = 0; r < 8; ++r)
    U[r][t] = ldin(x, (long)(r0 + r)*256 + t, bf);
  __syncthreads();
  const ushort4* w4 = (const ushort4*)ws;
  float acc[8] = {0,0,0,0,0,0,0,0};
  for (int e4 = 0; e4 < 64; ++e4) {
    ushort4 u = w4[e4*256 + t];
    float w0 = bf2f(u.x), w1 = bf2f(u.y), w2 = bf2f(u.z), w3 = bf2f(u.w);
    #pragma unroll
    for (int r = 0; r < 8; ++r) {
      float4 uu = *(const float4*)&U[r][e4*4];
      acc[r] += uu.x*w0 + uu.y*w1 + uu.z*w2 + uu.w*w3;
    }
  }
  int h = t >> 5, d = t & 31;
  float a1v = ws[BIAS_OFF + 1280 + t];
  float a2v = ws[BIAS_OFF + 1536 + t];
  #pragma unroll
  for (int r = 0; r < 8; ++r) {
    int row = r0 + r;
    ws[A_OFF + h*131072 + row*32 + d] = acc[r];
    float p1 = acc[r]*a1v, p2 = acc[r]*a2v;
    #pragma unroll
    for (int off = 16; off > 0; off >>= 1) {
      p1 += __shfl_xor(p1, off, 32);
      p2 += __shfl_xor(p2, off, 32);
    }
    if (d == 0) {
      ws[S1_OFF + h*4096 + row] = p1;
      ws[S2_OFF + h*4096 + row] = p2;
    }
  }
}

// ------- graph attention + residual + fused rownorm; e_out = mean_h attn ---
// 1-D grid (1024), XCD-swizzled: low 3 bits = (b*2 + n0-parity).
// Sp padded (chunk stride 36, 16B-aligned float4s). e_out accumulated in
// registers (wave w owns row w). PV uses (chunk c, dim-quad d4) mapping
// with float4 Wh loads + shfl_xor butterfly (attn2-proven structure).
#define A1_CS 36
#define A1_RS 1152   // 32*A1_CS
__global__ __launch_bounds__(256) void attn1_kernel(const void* x, const int* adj,
                                                    float* ws, void* dout,
                                                    const int* flagp) {
  const int bf = *flagp;
  int t = threadIdx.x;
  int gid = blockIdx.x;
  int b = (gid >> 1) & 3;
  int n0 = ((((gid >> 3) << 1) | (gid & 1))) * 4;
  __shared__ __align__(16) float Sp[4*A1_RS];
  __shared__ float s2s[1024];
  __shared__ unsigned char adjm[4][1024];
  __shared__ float s1s[4];
  __shared__ __align__(16) float hpred[4][4][32];   // [wave][row][dim]
  __shared__ __align__(16) float xrow[4][256];
  for (int r = 0; r < 4; ++r) {
    int base = (b*1024 + n0 + r) * 1024;
    for (int j = 0; j < 4; ++j) {
      int m = t + 256*j;
      adjm[r][m] = (adj[base + m] > 0) ? 1 : 0;
    }
  }
  int w = t >> 6, lane = t & 63;
  float eacc[16];
  #pragma unroll
  for (int j = 0; j < 16; ++j) eacc[j] = 0.0f;
  for (int h = 0; h < 8; ++h) {
    const float* s2p = ws + S2_OFF + h*4096 + b*1024;
    for (int j = 0; j < 4; ++j) s2s[t + 256*j] = s2p[t + 256*j];
    if (t < 4) s1s[t] = ws[S1_OFF + h*4096 + b*1024 + n0 + t];
    __syncthreads();
    #pragma unroll
    for (int r = 0; r < 4; ++r) {
      float s1v = s1s[r];
      #pragma unroll
      for (int j = 0; j < 4; ++j) {
        int m = t + 256*j;
        float ev = s1v + s2s[m];
        ev = (ev >= 0.0f) ? ev : 0.1f*ev;
        Sp[r*A1_RS + (m >> 5)*A1_CS + (m & 31)] = adjm[r][m] ? ev : NEGC;
      }
    }
    __syncthreads();
    // softmax: wave w <-> row w; e_out accumulates in registers
    {
      float* Sr = Sp + w*A1_RS;
      float mx = -3.4e38f;
      #pragma unroll
      for (int j = 0; j < 16; ++j) {
        int m = lane + 64*j;
        mx = fmaxf(mx, Sr[(m >> 5)*A1_CS + (m & 31)]);
      }
      #pragma unroll
      for (int off = 32; off > 0; off >>= 1) mx = fmaxf(mx, __shfl_xor(mx, off));
      float s = 0.0f;
      #pragma unroll
      for (int j = 0; j < 16; ++j) {
        int m = lane + 64*j;
        int a = (m >> 5)*A1_CS + (m & 31);
        float p = __expf(Sr[a] - mx);
        Sr[a] = p;
        s += p;
      }
      #pragma unroll
      for (int off = 32; off > 0; off >>= 1) s += __shfl_xor(s, off);
      float rs = 1.0f / s;
      #pragma unroll
      for (int j = 0; j < 16; ++j) {
        int m = lane + 64*j;
        int a = (m >> 5)*A1_CS + (m & 31);
        float p = Sr[a] * rs;
        Sr[a] = p;
        eacc[j] += 0.125f * p;
      }
    }
    __syncthreads();
    // PV: thread = (chunk c of 32 keys, dim-quad d4); float4 Wh loads
    {
      int d4 = t & 7, c = t >> 3;
      const float* whp = ws + A_OFF + h*131072 + b*32768 + d4*4;
      float4 o[4] = {};
      #pragma unroll
      for (int mq = 0; mq < 8; ++mq) {
        int m = c*32 + mq*4;
        float4 w0 = *(const float4*)(whp + (m+0)*32);
        float4 w1 = *(const float4*)(whp + (m+1)*32);
        float4 w2 = *(const float4*)(whp + (m+2)*32);
        float4 w3 = *(const float4*)(whp + (m+3)*32);
        #pragma unroll
        for (int r = 0; r < 4; ++r) {
          float4 s = *(const float4*)&Sp[r*A1_RS + c*A1_CS + mq*4];
          o[r].x += s.x*w0.x + s.y*w1.x + s.z*w2.x + s.w*w3.x;
          o[r].y += s.x*w0.y + s.y*w1.y + s.z*w2.y + s.w*w3.y;
          o[r].z += s.x*w0.z + s.y*w1.z + s.z*w2.z + s.w*w3.z;
          o[r].w += s.x*w0.w + s.y*w1.w + s.z*w2.w + s.w*w3.w;
        }
      }
      #pragma unroll
      for (int off = 8; off <= 32; off <<= 1) {
        #pragma unroll
        for (int r = 0; r < 4; ++r) {
          o[r].x += __shfl_xor(o[r].x, off);
          o[r].y += __shfl_xor(o[r].y, off);
          o[r].z += __shfl_xor(o[r].z, off);
          o[r].w += __shfl_xor(o[r].w, off);
        }
      }
      if (lane < 8) {   // lane == d4 here
        #pragma unroll
        for (int r = 0; r < 4; ++r)
          *(float4*)&hpred[w][r][lane*4] = o[r];
      }
    }
    __syncthreads();
    if (t < 128) {
      int r = t >> 5, dd = t & 31;
      float sum = hpred[0][r][dd] + hpred[1][r][dd] + hpred[2][r][dd] + hpred[3][r][dd];
      float hv = (sum >= 0.0f) ? sum : 0.01f*sum;
      long idx = (long)(b*1024 + n0 + r)*256 + h*32 + dd;
      xrow[r][h*32 + dd] = ldin(x, idx, bf) + hv;
    }
    __syncthreads();
  }
  // fused rownorm (ddof=1): wave w handles row w
  float vals[4]; float s = 0.0f;
  #pragma unroll
  for (int j = 0; j < 4; ++j) { vals[j] = xrow[w][lane + 64*j]; s += vals[j]; }
  #pragma unroll
  for (int off = 32; off > 0; off >>= 1) s += __shfl_xor(s, off);
  float mean = s * (1.0f/256.0f);
  float ss = 0.0f;
  #pragma unroll
  for (int j = 0; j < 4; ++j) { float d = vals[j] - mean; ss += d*d; }
  #pragma unroll
  for (int off = 32; off > 0; off >>= 1) ss += __shfl_xor(ss, off);
  float inv = 1.0f / (sqrtf(ss * (1.0f/255.0f)) + 1e-6f);
  float* Bp = ws + B_OFF + (b*1024 + n0 + w)*256;
  #pragma unroll
  for (int j = 0; j < 4; ++j) Bp[lane + 64*j] = (vals[j] - mean) * inv;
  // e_out: wave w writes row w from registers
  {
    long base = 1048576L + (long)(b*1024 + n0 + w)*1024;
    #pragma unroll
    for (int j = 0; j < 16; ++j)
      stout(dout, base + lane + 64*j, eacc[j], bf);
  }
}

// ---------------- column (axis=1) stats, ddof=1 ----------------------------
__global__ __launch_bounds__(256) void colstatsA_kernel(const float* in, float* cs) {
  int t = threadIdx.x;
  int j = blockIdx.x & 15;
  int b = blockIdx.x >> 4;
  float s = 0, ss = 0;
  for (int n = j*64; n < j*64 + 64; ++n) {
    float v = in[(b*1024 + n)*256 + t];
    s += v; ss += v*v;
  }
  cs[(b*16 + j)*256 + t] = s;
  cs[16384 + (b*16 + j)*256 + t] = ss;
}

__global__ __launch_bounds__(256) void colstatsB_kernel(const float* cs, float* st) {
  int t = threadIdx.x;
  int b = blockIdx.x;
  float s = 0, ss = 0;
  for (int j = 0; j < 16; ++j) {
    s  += cs[(b*16 + j)*256 + t];
    ss += cs[16384 + (b*16 + j)*256 + t];
  }
  float mean = s * (1.0f/1024.0f);
  float var = fmaxf((ss - s*mean) * (1.0f/1023.0f), 0.0f);
  st[b*256 + t] = mean;
  st[1024 + b*256 + t] = 1.0f / (sqrtf(var) + 1e-6f);
}

// ---------------- row GEMM, bf16 quad weights ------------------------------
// IN_MODE 0: plain fp32 [row][256]; 1: fp32 + colnorm(st); 2: float-input src
//   permuted (n,b,e)->(b,n,e); 3: fp32 head-major [b][h][n][32]
// RN 1: fused rownorm on output
// OUTM 0: fp32 [row][256]; 1: d_out (dtype per flag); 2: fp32 head-major;
//      3: bf16 head-major (ushort)
template<int IN_MODE, int RN, int OUTM>
__global__ __launch_bounds__(256) void gemm_kernel(const void* inp,
    const unsigned short* wmat, const float* bias, const float* st, void* outp,
    const int* flagp) {
  const int bf = *flagp;
  int t = threadIdx.x;
  int r0 = blockIdx.x * 8;
  __shared__ __align__(16) float U[8][256];
  #pragma unroll
  for (int r = 0; r < 8; ++r) {
    int row = r0 + r;
    float v;
    if (IN_MODE == 0) {
      v = ((const float*)inp)[row*256 + t];
    } else if (IN_MODE == 1) {
      int b = row >> 10;
      v = (((const float*)inp)[row*256 + t] - st[b*256 + t]) * st[1024 + b*256 + t];
    } else if (IN_MODE == 2) {
      int b = row >> 10, n = row & 1023;
      v = ldin(inp, (long)(n*4 + b)*256 + t, bf);
    } else {
      int b = row >> 10, n = row & 1023;
      v = ((const float*)inp)[((b*8 + (t >> 5))*1024 + n)*32 + (t & 31)];
    }
    U[r][t] = v;
  }
  __syncthreads();
  float bv = bias[t];
  float acc[8];
  #pragma unroll
  for (int r = 0; r < 8; ++r) acc[r] = bv;
  const ushort4* w4 = (const ushort4*)wmat;
  for (int e4 = 0; e4 < 64; ++e4) {
    ushort4 u = w4[e4*256 + t];
    float w0 = bf2f(u.x), w1 = bf2f(u.y), w2 = bf2f(u.z), w3 = bf2f(u.w);
    #pragma unroll
    for (int r = 0; r < 8; ++r) {
      float4 uu = *(const float4*)&U[r][e4*4];
      acc[r] += uu.x*w0 + uu.y*w1 + uu.z*w2 + uu.w*w3;
    }
  }
  if (RN == 0) {
    #pragma unroll
    for (int r = 0; r < 8; ++r) {
      int row = r0 + r;
      if (OUTM == 0) ((float*)outp)[row*256 + t] = acc[r];
      else if (OUTM == 1) stout(outp, (long)row*256 + t, acc[r], bf);
      else if (OUTM == 2) {
        int b = row >> 10, n = row & 1023;
        ((float*)outp)[((b*8 + (t >> 5))*1024 + n)*32 + (t & 31)] = acc[r];
      } else {
        int b = row >> 10, n = row & 1023;
        ((unsigned short*)outp)[((b*8 + (t >> 5))*1024 + n)*32 + (t & 31)] = f2bf(acc[r]);
      }
    }
  } else {
    __syncthreads();
    #pragma unroll
    for (int r = 0; r < 8; ++r) U[r][t] = acc[r];
    __syncthreads();
    int w = t >> 6, lane = t & 63;
    for (int rr = w; rr < 8; rr += 4) {
      float vals[4]; float s = 0.0f;
      #pragma unroll
      for (int j = 0; j < 4; ++j) { vals[j] = U[rr][lane + 64*j]; s += vals[j]; }
      #pragma unroll
      for (int off = 32; off > 0; off >>= 1) s += __shfl_xor(s, off);
      float mean = s * (1.0f/256.0f);
      float ss = 0.0f;
      #pragma unroll
      for (int j = 0; j < 4; ++j) { float d = vals[j] - mean; ss += d*d; }
      #pragma unroll
      for (int off = 32; off > 0; off >>= 1) ss += __shfl_xor(ss, off);
      float inv = 1.0f / (sqrtf(ss * (1.0f/255.0f)) + 1e-6f);
      #pragma unroll
      for (int j = 0; j < 4; ++j)
        ((float*)outp)[(r0 + rr)*256 + lane + 64*j] = (vals[j] - mean) * inv;
    }
  }
}

// ---------------- standard MHA, bf16 K/V, 8 q-rows per block ---------------
// GRID MUST BE 4096: 128 row-groups x 4 b x 8 h.
// 1-D grid, XCD-swizzled (low 3 bits = head). Q fp32 head-major at A_OFF
// (o overwrites q, exclusive slots); K,V bf16 head-major at B_OFF/C_OFF.
// SP_CS is a multiple of 4 (PV float4 reads stay 16B-aligned).
#define SP_CS 36      // chunk stride (words): 32 data + 4 pad
#define SP_RS 1152    // row stride = 32*SP_CS
__global__ __launch_bounds__(256) void attn2_kernel(float* ws) {
  int t = threadIdx.x;
  int gid = blockIdx.x;
  int h = gid & 7;
  int b = (gid >> 3) & 3;
  int n0 = (gid >> 5) << 3;   // 8 q-rows per block; gid>>5 in 0..127
  __shared__ __align__(16) float Sp[8*SP_RS];
  __shared__ __align__(16) float qs[8][32];
  __shared__ __align__(16) float hpw[4][8][32];
  float* qq = ws + A_OFF;
  const unsigned short* kk = (const unsigned short*)(ws + B_OFF);
  const unsigned short* vv = (const unsigned short*)(ws + C_OFF);
  int base_bh = (b*8 + h)*1024;
  int w = t >> 6, lane = t & 63;
  const float scl = 0.17677669529663687f; // 1/sqrt(32)
  qs[t >> 5][t & 31] = qq[(base_bh + n0 + (t >> 5))*32 + (t & 31)];
  __syncthreads();
  // ---- QK: thread owns keys {t, t+256, t+512, t+768} ----------------------
  {
    float acc[4][8] = {};
    #pragma unroll
    for (int p = 0; p < 8; ++p) {
      float4 kf[4];
      #pragma unroll
      for (int j = 0; j < 4; ++j) {
        ushort4 u = *(const ushort4*)(kk + (base_bh + t + 256*j)*32 + p*4);
        kf[j].x = bf2f(u.x); kf[j].y = bf2f(u.y);
        kf[j].z = bf2f(u.z); kf[j].w = bf2f(u.w);
      }
      #pragma unroll
      for (int r = 0; r < 8; ++r) {
        float4 q = *(const float4*)&qs[r][p*4];
        #pragma unroll
        for (int j = 0; j < 4; ++j)
          acc[j][r] += q.x*kf[j].x + q.y*kf[j].y + q.z*kf[j].z + q.w*kf[j].w;
      }
    }
    #pragma unroll
    for (int j = 0; j < 4; ++j) {
      int key = t + 256*j;
      int base = (key >> 5)*SP_CS + (key & 31);
      #pragma unroll
      for (int r = 0; r < 8; ++r)
        Sp[r*SP_RS + base] = acc[j][r] * scl;
    }
  }
  __syncthreads();
  // ---- softmax: wave w handles rows w and w+4 -----------------------------
  #pragma unroll
  for (int rr = 0; rr < 2; ++rr) {
    float* Sr = Sp + (w + 4*rr)*SP_RS;
    float mx = -3.4e38f;
    #pragma unroll
    for (int j = 0; j < 16; ++j) {
      int m = lane + 64*j;
      mx = fmaxf(mx, Sr[(m >> 5)*SP_CS + (m & 31)]);
    }
    #pragma unroll
    for (int off = 32; off > 0; off >>= 1) mx = fmaxf(mx, __shfl_xor(mx, off));
    float s = 0.0f;
    #pragma unroll
    for (int j = 0; j < 16; ++j) {
      int m = lane + 64*j;
      int a = (m >> 5)*SP_CS + (m & 31);
      float p = __expf(Sr[a] - mx);
      Sr[a] = p;
      s += p;
    }
    #pragma unroll
    for (int off = 32; off > 0; off >>= 1) s += __shfl_xor(s, off);
    float rs = 1.0f / s;
    #pragma unroll
    for (int j = 0; j < 16; ++j) {
      int m = lane + 64*j;
      Sr[(m >> 5)*SP_CS + (m & 31)] *= rs;
    }
  }
  __syncthreads();
  // ---- PV: thread = (chunk c of 32 keys, dim-quad d4) ---------------------
  {
    int d4 = t & 7, c = t >> 3;
    const unsigned short* vbase = vv + base_bh*32 + d4*4;
    float4 o[8] = {};
    #pragma unroll
    for (int mq = 0; mq < 8; ++mq) {
      int m = c*32 + mq*4;
      float4 v0, v1, v2, v3;
      {
        ushort4 u0 = *(const ushort4*)(vbase + (m+0)*32);
        ushort4 u1 = *(const ushort4*)(vbase + (m+1)*32);
        ushort4 u2 = *(const ushort4*)(vbase + (m+2)*32);
        ushort4 u3 = *(const ushort4*)(vbase + (m+3)*32);
        v0.x = bf2f(u0.x); v0.y = bf2f(u0.y); v0.z = bf2f(u0.z); v0.w = bf2f(u0.w);
        v1.x = bf2f(u1.x); v1.y = bf2f(u1.y); v1.z = bf2f(u1.z); v1.w = bf2f(u1.w);
        v2.x = bf2f(u2.x); v2.y = bf2f(u2.y); v2.z = bf2f(u2.z); v2.w = bf2f(u2.w);
        v3.x = bf2f(u3.x); v3.y = bf2f(u3.y); v3.z = bf2f(u3.z); v3.w = bf2f(u3.w);
      }
      #pragma unroll
      for (int r = 0; r < 8; ++r) {
        float4 s = *(const float4*)&Sp[r*SP_RS + c*SP_CS + mq*4];
        o[r].x += s.x*v0.x + s.y*v1.x + s.z*v2.x + s.w*v3.x;
        o[r].y += s.x*v0.y + s.y*v1.y + s.z*v2.y + s.w*v3.y;
        o[r].z += s.x*v0.z + s.y*v1.z + s.z*v2.z + s.w*v3.z;
        o[r].w += s.x*v0.w + s.y*v1.w + s.z*v2.w + s.w*v3.w;
      }
    }
    // butterfly over lane bits 3..5 (the 8 chunks resident in this wave)
    #pragma unroll
    for (int off = 8; off <= 32; off <<= 1) {
      #pragma unroll
      for (int r = 0; r < 8; ++r) {
        o[r].x += __shfl_xor(o[r].x, off);
        o[r].y += __shfl_xor(o[r].y, off);
        o[r].z += __shfl_xor(o[r].z, off);
        o[r].w += __shfl_xor(o[r].w, off);
      }
    }
    if (lane < 8) {     // lane == d4 for these lanes
      #pragma unroll
      for (int r = 0; r < 8; ++r)
        *(float4*)&hpw[w][r][lane*4] = o[r];
    }
  }
  __syncthreads();
  {
    int r = t >> 5, d = t & 31;
    float sum = hpw[0][r][d] + hpw[1][r][d] + hpw[2][r][d] + hpw[3][r][d];
    qq[(base_bh + n0 + r)*32 + d] = sum;   // o over q (own slots)
  }
}

extern "C" void kernel_launch(void* const* d_in, const int* in_sizes, int n_in,
                              void* d_out, int out_size, void* d_ws, size_t ws_size,
                              hipStream_t stream) {
  const void* x   = d_in[0];
  const void* src = d_in[1];
  const int* adj  = (const int*)d_in[2];
  const void* wg  = d_in[3];
  const void* a1  = d_in[4];
  const void* a2  = d_in[5];
  const void* lw  = d_in[6];
  const void* lb  = d_in[7];
  const void* ipw = d_in[8];
  const void* ipb = d_in[9];
  const void* opw = d_in[10];
  const void* opb = d_in[11];
  float* ws = (float*)d_ws;
  const unsigned short* wbf = (const unsigned short*)d_ws;
  int* flagp = (int*)(ws + FLAG_F);

  detect_kernel<<<1, 64, 0, stream>>>((const unsigned short*)x, flagp);
  prep_kernel<<<dim3(256, 7), 256, 0, stream>>>(wg, lw, ipw, opw, lb, ipb, opb,
                                                a1, a2, ws, flagp);
  whs_kernel<<<512, 256, 0, stream>>>(x, ws, flagp);
  attn1_kernel<<<1024, 256, 0, stream>>>(x, adj, ws, d_out, flagp);
  colstatsA_kernel<<<64, 256, 0, stream>>>(ws + B_OFF, ws + CS_OFF);
  colstatsB_kernel<<<4, 256, 0, stream>>>(ws + CS_OFF, ws + ST1_OFF);
  gemm_kernel<1,1,0><<<512, 256, 0, stream>>>(ws + B_OFF, wbf + 1*65536,
      ws + BIAS_OFF, ws + ST1_OFF, ws + C_OFF, flagp);
  colstatsA_kernel<<<64, 256, 0, stream>>>(ws + C_OFF, ws + CS_OFF);
  colstatsB_kernel<<<4, 256, 0, stream>>>(ws + CS_OFF, ws + ST2_OFF);
  gemm_kernel<1,0,2><<<512, 256, 0, stream>>>(ws + C_OFF, wbf + 2*65536,
      ws + BIAS_OFF + 256, ws + ST2_OFF, ws + A_OFF, flagp);   // Q fp32 hm
  gemm_kernel<1,0,3><<<512, 256, 0, stream>>>(ws + C_OFF, wbf + 3*65536,
      ws + BIAS_OFF + 512, ws + ST2_OFF, ws + B_OFF, flagp);   // K bf16 hm
  gemm_kernel<2,0,3><<<512, 256, 0, stream>>>(src, wbf + 4*65536,
      ws + BIAS_OFF + 768, nullptr, ws + C_OFF, flagp);        // V bf16 hm
  attn2_kernel<<<4096, 256, 0, stream>>>(ws);                  // o -> A_OFF
  gemm_kernel<3,0,1><<<512, 256, 0, stream>>>(ws + A_OFF, wbf + 5*65536,
      ws + BIAS_OFF + 1024, nullptr, d_out, flagp);            // out-proj
}

// Round 12
// 378.122 us; speedup vs baseline: 2.2389x; 1.1070x over previous
//
#include <hip/hip_runtime.h>
#include <hip/hip_bf16.h>

// B=4, N=1024, E=256, H=8, D=32. Float tensors may be bf16 OR fp32 in d_in /
// d_out (detected at runtime on-device); adj is int32.
// Output: x_out [4,1024,256] then e_out [4,1024,1024] (element offsets).
//
// ws float offsets:
//   [0 .. 196608)   : 6 weight matrices, transposed, bf16, quad-interleaved
//                     matrix m at ushort offset m*65536; element (e,o) at
//                     ((e>>2)*256 + o)*4 + (e&3).  m: 0=Wcat 1=LIN 2=WQ 3=WK 4=WV 5=WO
#define BIAS_OFF 196608   // lin_b, bq, bk, bv, bo, a1, a2  (7*256 fp32)
#define S1_OFF   198400   // [h][4096]
#define S2_OFF   231168
#define CS_OFF   263936   // 32768: column partial sums+sumsq (reused twice)
#define ST1_OFF  296704   // mean[1024] + inv[1024]
#define ST2_OFF  298752
#define A_OFF    300800   // 4 MB: Wh [h][row][32] -> later Q,o fp32 head-major
#define B_OFF    1349376  // 4 MB: rownorm(xa)     -> later K bf16 head-major [b][h][n][32]
#define C_OFF    2397952  // 4 MB: rownorm(lin)    -> later V^T bf16 head-major [b][h][d][n]
#define FLAG_F   3446528  // int: 1 = bf16 tensors, 0 = fp32 tensors
// end 3446529 floats = 13.8 MB

#define NEGC (-9.0e15f)

typedef __attribute__((ext_vector_type(8))) short bf16x8s;
typedef __attribute__((ext_vector_type(4))) float f32x4;

static __device__ __forceinline__ float bf2f(unsigned short u) {
  union { unsigned int i; float f; } v; v.i = ((unsigned int)u) << 16; return v.f;
}
static __device__ __forceinline__ unsigned short f2bf(float f) {
  union { float f; unsigned int u; } v; v.f = f;
  unsigned int r = (v.u + 0x7FFFu + ((v.u >> 16) & 1u)) >> 16;   // RNE
  return (unsigned short)r;
}
static __device__ __forceinline__ float ldin(const void* p, long i, int bf) {
  return bf ? bf2f(((const unsigned short*)p)[i]) : ((const float*)p)[i];
}
static __device__ __forceinline__ unsigned short rdbf(const void* p, long i, int bf) {
  if (bf) return ((const unsigned short*)p)[i];
  return f2bf(((const float*)p)[i]);
}
static __device__ __forceinline__ void stout(void* p, long i, float v, int bf) {
  if (bf) ((unsigned short*)p)[i] = f2bf(v);
  else    ((float*)p)[i] = v;
}

// ---------------- dtype detector -------------------------------------------
__global__ __launch_bounds__(64) void detect_kernel(const unsigned short* x, int* flag) {
  int lane = threadIdx.x;
  unsigned short u = x[2 * lane];
  int e = (u >> 7) & 0xFF;
  bool good = (e >= 100 && e <= 140);
  unsigned long long m = __ballot(good);
  if (lane == 0) *flag = (__popcll(m) >= 48) ? 1 : 0;
}

// ---------------- prep: weights -> transposed quad bf16; biases -> fp32 ----
__global__ __launch_bounds__(256) void prep_kernel(
    const void* wg, const void* lin_w, const void* inp_w, const void* out_w,
    const void* lin_b, const void* inp_b, const void* out_b,
    const void* a1, const void* a2, float* ws, const int* flagp) {
  const int bf = *flagp;
  unsigned short* wbf = (unsigned short*)ws;
  int t = threadIdx.x;
  int f = blockIdx.x;
  int m = blockIdx.y;
  int dst = m*65536 + ((f >> 2)*256 + t)*4 + (f & 3);
  if (m == 0) {
    int h = t >> 5, d = t & 31;
    wbf[dst] = rdbf(wg, h*8192 + f*32 + d, bf);
  } else if (m == 1) wbf[dst] = rdbf(lin_w, t*256 + f, bf);
  else if (m == 2)   wbf[dst] = rdbf(inp_w, t*256 + f, bf);
  else if (m == 3)   wbf[dst] = rdbf(inp_w, (256 + t)*256 + f, bf);
  else if (m == 4)   wbf[dst] = rdbf(inp_w, (512 + t)*256 + f, bf);
  else if (m == 5)   wbf[dst] = rdbf(out_w, t*256 + f, bf);
  else if (f == 0) {
    ws[BIAS_OFF + t]        = ldin(lin_b, t, bf);
    ws[BIAS_OFF + 256 + t]  = ldin(inp_b, t, bf);
    ws[BIAS_OFF + 512 + t]  = ldin(inp_b, 256 + t, bf);
    ws[BIAS_OFF + 768 + t]  = ldin(inp_b, 512 + t, bf);
    ws[BIAS_OFF + 1024 + t] = ldin(out_b, t, bf);
    ws[BIAS_OFF + 1280 + t] = ldin(a1, t, bf);
    ws[BIAS_OFF + 1536 + t] = ldin(a2, t, bf);
  }
}

// ---------------- Wh = x @ Wcat, plus s1/s2 head reductions ----------------
__global__ __launch_bounds__(256) void whs_kernel(const void* x, float* ws,
                                                  const int* flagp) {
  const int bf = *flagp;
  int t = threadIdx.x;
  int r0 = blockIdx.x * 8;
  __shared__ __align__(16) float U[8][256];
  #pragma unroll
  for (int r = 0; r < 8; ++r)
    U[r][t] = ldin(x, (long)(r0 + r)*256 + t, bf);
  __syncthreads();
  const ushort4* w4 = (const ushort4*)ws;
  float acc[8] = {0,0,0,0,0,0,0,0};
  for (int e4 = 0; e4 < 64; ++e4) {
    ushort4 u = w4[e4*256 + t];
    float w0 = bf2f(u.x), w1 = bf2f(u.y), w2 = bf2f(u.z), w3 = bf2f(u.w);
    #pragma unroll
    for (int r = 0; r < 8; ++r) {
      float4 uu = *(const float4*)&U[r][e4*4];
      acc[r] += uu.x*w0 + uu.y*w1 + uu.z*w2 + uu.w*w3;
    }
  }
  int h = t >> 5, d = t & 31;
  float a1v = ws[BIAS_OFF + 1280 + t];
  float a2v = ws[BIAS_OFF + 1536 + t];
  #pragma unroll
  for (int r = 0; r < 8; ++r) {
    int row = r0 + r;
    ws[A_OFF + h*131072 + row*32 + d] = acc[r];
    float p1 = acc[r]*a1v, p2 = acc[r]*a2v;
    #pragma unroll
    for (int off = 16; off > 0; off >>= 1) {
      p1 += __shfl_xor(p1, off, 32);
      p2 += __shfl_xor(p2, off, 32);
    }
    if (d == 0) {
      ws[S1_OFF + h*4096 + row] = p1;
      ws[S2_OFF + h*4096 + row] = p2;
    }
  }
}

// ------- graph attention + residual + fused rownorm; e_out = mean_h attn ---
// 1-D grid (1024), XCD-swizzled: low 3 bits = (b*2 + n0-parity).
#define A1_CS 36
#define A1_RS 1152   // 32*A1_CS
__global__ __launch_bounds__(256) void attn1_kernel(const void* x, const int* adj,
                                                    float* ws, void* dout,
                                                    const int* flagp) {
  const int bf = *flagp;
  int t = threadIdx.x;
  int gid = blockIdx.x;
  int b = (gid >> 1) & 3;
  int n0 = ((((gid >> 3) << 1) | (gid & 1))) * 4;
  __shared__ __align__(16) float Sp[4*A1_RS];
  __shared__ float s2s[1024];
  __shared__ unsigned char adjm[4][1024];
  __shared__ float s1s[4];
  __shared__ __align__(16) float hpred[4][4][32];   // [wave][row][dim]
  __shared__ __align__(16) float xrow[4][256];
  for (int r = 0; r < 4; ++r) {
    int base = (b*1024 + n0 + r) * 1024;
    for (int j = 0; j < 4; ++j) {
      int m = t + 256*j;
      adjm[r][m] = (adj[base + m] > 0) ? 1 : 0;
    }
  }
  int w = t >> 6, lane = t & 63;
  float eacc[16];
  #pragma unroll
  for (int j = 0; j < 16; ++j) eacc[j] = 0.0f;
  for (int h = 0; h < 8; ++h) {
    const float* s2p = ws + S2_OFF + h*4096 + b*1024;
    for (int j = 0; j < 4; ++j) s2s[t + 256*j] = s2p[t + 256*j];
    if (t < 4) s1s[t] = ws[S1_OFF + h*4096 + b*1024 + n0 + t];
    __syncthreads();
    #pragma unroll
    for (int r = 0; r < 4; ++r) {
      float s1v = s1s[r];
      #pragma unroll
      for (int j = 0; j < 4; ++j) {
        int m = t + 256*j;
        float ev = s1v + s2s[m];
        ev = (ev >= 0.0f) ? ev : 0.1f*ev;
        Sp[r*A1_RS + (m >> 5)*A1_CS + (m & 31)] = adjm[r][m] ? ev : NEGC;
      }
    }
    __syncthreads();
    {
      float* Sr = Sp + w*A1_RS;
      float mx = -3.4e38f;
      #pragma unroll
      for (int j = 0; j < 16; ++j) {
        int m = lane + 64*j;
        mx = fmaxf(mx, Sr[(m >> 5)*A1_CS + (m & 31)]);
      }
      #pragma unroll
      for (int off = 32; off > 0; off >>= 1) mx = fmaxf(mx, __shfl_xor(mx, off));
      float s = 0.0f;
      #pragma unroll
      for (int j = 0; j < 16; ++j) {
        int m = lane + 64*j;
        int a = (m >> 5)*A1_CS + (m & 31);
        float p = __expf(Sr[a] - mx);
        Sr[a] = p;
        s += p;
      }
      #pragma unroll
      for (int off = 32; off > 0; off >>= 1) s += __shfl_xor(s, off);
      float rs = 1.0f / s;
      #pragma unroll
      for (int j = 0; j < 16; ++j) {
        int m = lane + 64*j;
        int a = (m >> 5)*A1_CS + (m & 31);
        float p = Sr[a] * rs;
        Sr[a] = p;
        eacc[j] += 0.125f * p;
      }
    }
    __syncthreads();
    {
      int d4 = t & 7, c = t >> 3;
      const float* whp = ws + A_OFF + h*131072 + b*32768 + d4*4;
      float4 o[4] = {};
      #pragma unroll
      for (int mq = 0; mq < 8; ++mq) {
        int m = c*32 + mq*4;
        float4 w0 = *(const float4*)(whp + (m+0)*32);
        float4 w1 = *(const float4*)(whp + (m+1)*32);
        float4 w2 = *(const float4*)(whp + (m+2)*32);
        float4 w3 = *(const float4*)(whp + (m+3)*32);
        #pragma unroll
        for (int r = 0; r < 4; ++r) {
          float4 s = *(const float4*)&Sp[r*A1_RS + c*A1_CS + mq*4];
          o[r].x += s.x*w0.x + s.y*w1.x + s.z*w2.x + s.w*w3.x;
          o[r].y += s.x*w0.y + s.y*w1.y + s.z*w2.y + s.w*w3.y;
          o[r].z += s.x*w0.z + s.y*w1.z + s.z*w2.z + s.w*w3.z;
          o[r].w += s.x*w0.w + s.y*w1.w + s.z*w2.w + s.w*w3.w;
        }
      }
      #pragma unroll
      for (int off = 8; off <= 32; off <<= 1) {
        #pragma unroll
        for (int r = 0; r < 4; ++r) {
          o[r].x += __shfl_xor(o[r].x, off);
          o[r].y += __shfl_xor(o[r].y, off);
          o[r].z += __shfl_xor(o[r].z, off);
          o[r].w += __shfl_xor(o[r].w, off);
        }
      }
      if (lane < 8) {
        #pragma unroll
        for (int r = 0; r < 4; ++r)
          *(float4*)&hpred[w][r][lane*4] = o[r];
      }
    }
    __syncthreads();
    if (t < 128) {
      int r = t >> 5, dd = t & 31;
      float sum = hpred[0][r][dd] + hpred[1][r][dd] + hpred[2][r][dd] + hpred[3][r][dd];
      float hv = (sum >= 0.0f) ? sum : 0.01f*sum;
      long idx = (long)(b*1024 + n0 + r)*256 + h*32 + dd;
      xrow[r][h*32 + dd] = ldin(x, idx, bf) + hv;
    }
    __syncthreads();
  }
  float vals[4]; float s = 0.0f;
  #pragma unroll
  for (int j = 0; j < 4; ++j) { vals[j] = xrow[w][lane + 64*j]; s += vals[j]; }
  #pragma unroll
  for (int off = 32; off > 0; off >>= 1) s += __shfl_xor(s, off);
  float mean = s * (1.0f/256.0f);
  float ss = 0.0f;
  #pragma unroll
  for (int j = 0; j < 4; ++j) { float d = vals[j] - mean; ss += d*d; }
  #pragma unroll
  for (int off = 32; off > 0; off >>= 1) ss += __shfl_xor(ss, off);
  float inv = 1.0f / (sqrtf(ss * (1.0f/255.0f)) + 1e-6f);
  float* Bp = ws + B_OFF + (b*1024 + n0 + w)*256;
  #pragma unroll
  for (int j = 0; j < 4; ++j) Bp[lane + 64*j] = (vals[j] - mean) * inv;
  {
    long base = 1048576L + (long)(b*1024 + n0 + w)*1024;
    #pragma unroll
    for (int j = 0; j < 16; ++j)
      stout(dout, base + lane + 64*j, eacc[j], bf);
  }
}

// ---------------- column (axis=1) stats, ddof=1 ----------------------------
__global__ __launch_bounds__(256) void colstatsA_kernel(const float* in, float* cs) {
  int t = threadIdx.x;
  int j = blockIdx.x & 15;
  int b = blockIdx.x >> 4;
  float s = 0, ss = 0;
  for (int n = j*64; n < j*64 + 64; ++n) {
    float v = in[(b*1024 + n)*256 + t];
    s += v; ss += v*v;
  }
  cs[(b*16 + j)*256 + t] = s;
  cs[16384 + (b*16 + j)*256 + t] = ss;
}

__global__ __launch_bounds__(256) void colstatsB_kernel(const float* cs, float* st) {
  int t = threadIdx.x;
  int b = blockIdx.x;
  float s = 0, ss = 0;
  for (int j = 0; j < 16; ++j) {
    s  += cs[(b*16 + j)*256 + t];
    ss += cs[16384 + (b*16 + j)*256 + t];
  }
  float mean = s * (1.0f/1024.0f);
  float var = fmaxf((ss - s*mean) * (1.0f/1023.0f), 0.0f);
  st[b*256 + t] = mean;
  st[1024 + b*256 + t] = 1.0f / (sqrtf(var) + 1e-6f);
}

// ---------------- row GEMM, bf16 quad weights ------------------------------
// IN_MODE 0: plain fp32 [row][256]; 1: fp32 + colnorm(st); 2: float-input src
//   permuted (n,b,e)->(b,n,e); 3: fp32 head-major [b][h][n][32]
// RN 1: fused rownorm on output
// OUTM 0: fp32 [row][256]; 1: d_out (dtype per flag); 2: fp32 head-major;
//      3: bf16 head-major; 4: bf16 TRANSPOSED head-major [b][h][d][n]
template<int IN_MODE, int RN, int OUTM>
__global__ __launch_bounds__(256) void gemm_kernel(const void* inp,
    const unsigned short* wmat, const float* bias, const float* st, void* outp,
    const int* flagp) {
  const int bf = *flagp;
  int t = threadIdx.x;
  int r0 = blockIdx.x * 8;
  __shared__ __align__(16) float U[8][256];
  #pragma unroll
  for (int r = 0; r < 8; ++r) {
    int row = r0 + r;
    float v;
    if (IN_MODE == 0) {
      v = ((const float*)inp)[row*256 + t];
    } else if (IN_MODE == 1) {
      int b = row >> 10;
      v = (((const float*)inp)[row*256 + t] - st[b*256 + t]) * st[1024 + b*256 + t];
    } else if (IN_MODE == 2) {
      int b = row >> 10, n = row & 1023;
      v = ldin(inp, (long)(n*4 + b)*256 + t, bf);
    } else {
      int b = row >> 10, n = row & 1023;
      v = ((const float*)inp)[((b*8 + (t >> 5))*1024 + n)*32 + (t & 31)];
    }
    U[r][t] = v;
  }
  __syncthreads();
  float bv = bias[t];
  float acc[8];
  #pragma unroll
  for (int r = 0; r < 8; ++r) acc[r] = bv;
  const ushort4* w4 = (const ushort4*)wmat;
  for (int e4 = 0; e4 < 64; ++e4) {
    ushort4 u = w4[e4*256 + t];
    float w0 = bf2f(u.x), w1 = bf2f(u.y), w2 = bf2f(u.z), w3 = bf2f(u.w);
    #pragma unroll
    for (int r = 0; r < 8; ++r) {
      float4 uu = *(const float4*)&U[r][e4*4];
      acc[r] += uu.x*w0 + uu.y*w1 + uu.z*w2 + uu.w*w3;
    }
  }
  if (RN == 0) {
    #pragma unroll
    for (int r = 0; r < 8; ++r) {
      int row = r0 + r;
      if (OUTM == 0) ((float*)outp)[row*256 + t] = acc[r];
      else if (OUTM == 1) stout(outp, (long)row*256 + t, acc[r], bf);
      else if (OUTM == 2) {
        int b = row >> 10, n = row & 1023;
        ((float*)outp)[((b*8 + (t >> 5))*1024 + n)*32 + (t & 31)] = acc[r];
      } else if (OUTM == 3) {
        int b = row >> 10, n = row & 1023;
        ((unsigned short*)outp)[((b*8 + (t >> 5))*1024 + n)*32 + (t & 31)] = f2bf(acc[r]);
      } else {
        int b = row >> 10, n = row & 1023;
        ((unsigned short*)outp)[((b*8 + (t >> 5))*32 + (t & 31))*1024 + n] = f2bf(acc[r]);
      }
    }
  } else {
    __syncthreads();
    #pragma unroll
    for (int r = 0; r < 8; ++r) U[r][t] = acc[r];
    __syncthreads();
    int w = t >> 6, lane = t & 63;
    for (int rr = w; rr < 8; rr += 4) {
      float vals[4]; float s = 0.0f;
      #pragma unroll
      for (int j = 0; j < 4; ++j) { vals[j] = U[rr][lane + 64*j]; s += vals[j]; }
      #pragma unroll
      for (int off = 32; off > 0; off >>= 1) s += __shfl_xor(s, off);
      float mean = s * (1.0f/256.0f);
      float ss = 0.0f;
      #pragma unroll
      for (int j = 0; j < 4; ++j) { float d = vals[j] - mean; ss += d*d; }
      #pragma unroll
      for (int off = 32; off > 0; off >>= 1) ss += __shfl_xor(ss, off);
      float inv = 1.0f / (sqrtf(ss * (1.0f/255.0f)) + 1e-6f);
      #pragma unroll
      for (int j = 0; j < 4; ++j)
        ((float*)outp)[(r0 + rr)*256 + lane + 64*j] = (vals[j] - mean) * inv;
    }
  }
}

// ---------------- MHA via MFMA, bf16 K/V, 8 q-rows per block ---------------
// GRID MUST BE 4096: 128 row-groups x 4 b x 8 h. h in low 3 bits (XCD-L2).
// Q fp32 head-major [b][h][n][32] at A_OFF (o overwrites q, exclusive slots);
// K bf16 [b][h][n][32] at B_OFF; V^T bf16 [b][h][d][n] at C_OFF.
// mfma_f32_16x16x32_bf16 layouts (m89-verified):
//   A[m=lane&15][k=(lane>>4)*8+j]; B[k=(lane>>4)*8+j][n=lane&15];
//   D col=lane&15, row=(lane>>4)*4+i.
// Only 8 of 16 M-rows are real (rows dup via lane&7; garbage rows ignored).
// SP_RS=1156 (not mult of 32 words): PV A-frag row reads spread all banks.
#define SP_CS 36
#define SP_RS 1156
__global__ __launch_bounds__(256) void attn2_kernel(float* ws) {
  int t = threadIdx.x;
  int gid = blockIdx.x;
  int h = gid & 7;
  int b = (gid >> 3) & 3;
  int n0 = (gid >> 5) << 3;   // 8 q-rows per block; gid>>5 in 0..127
  __shared__ __align__(16) float Sp[8*SP_RS];
  __shared__ __align__(16) float opart[4][8][16];
  float* qq = ws + A_OFF;
  const unsigned short* kk = (const unsigned short*)(ws + B_OFF);
  const unsigned short* vt = (const unsigned short*)(ws + C_OFF);
  int base_bh = (b*8 + h)*1024;
  int w = t >> 6, lane = t & 63;
  int m = lane & 15, quad = lane >> 4;
  const float scl = 0.17677669529663687f; // 1/sqrt(32)
  // ---- QK via MFMA: wave w covers keys w*256 .. +255 ----------------------
  {
    // A frag: Q row n0 + (lane&7) (dup m>=8), dims quad*8..+7
    const float* qp = qq + (base_bh + n0 + (lane & 7))*32 + quad*8;
    bf16x8s aq;
    #pragma unroll
    for (int j = 0; j < 8; ++j) ((unsigned short*)&aq)[j] = f2bf(qp[j]);
    f32x4 zero = {0.0f, 0.0f, 0.0f, 0.0f};
    #pragma unroll
    for (int kt = 0; kt < 16; ++kt) {
      int kbase = w*256 + kt*16;
      bf16x8s bk = *(const bf16x8s*)(kk + (base_bh + kbase + m)*32 + quad*8);
      f32x4 d = __builtin_amdgcn_mfma_f32_16x16x32_bf16(aq, bk, zero, 0, 0, 0);
      if (lane < 32) {                  // quads 0,1 hold real rows 0..7
        int key = kbase + m;
        int a = (key >> 5)*SP_CS + (key & 31);
        #pragma unroll
        for (int i = 0; i < 4; ++i)
          Sp[(quad*4 + i)*SP_RS + a] = d[i] * scl;
      }
    }
  }
  __syncthreads();
  // ---- softmax: wave w handles rows w and w+4 -----------------------------
  #pragma unroll
  for (int rr = 0; rr < 2; ++rr) {
    float* Sr = Sp + (w + 4*rr)*SP_RS;
    float mx = -3.4e38f;
    #pragma unroll
    for (int j = 0; j < 16; ++j) {
      int mm = lane + 64*j;
      mx = fmaxf(mx, Sr[(mm >> 5)*SP_CS + (mm & 31)]);
    }
    #pragma unroll
    for (int off = 32; off > 0; off >>= 1) mx = fmaxf(mx, __shfl_xor(mx, off));
    float s = 0.0f;
    #pragma unroll
    for (int j = 0; j < 16; ++j) {
      int mm = lane + 64*j;
      int a = (mm >> 5)*SP_CS + (mm & 31);
      float p = __expf(Sr[a] - mx);
      Sr[a] = p;
      s += p;
    }
    #pragma unroll
    for (int off = 32; off > 0; off >>= 1) s += __shfl_xor(s, off);
    float rs = 1.0f / s;
    #pragma unroll
    for (int j = 0; j < 16; ++j) {
      int mm = lane + 64*j;
      Sr[(mm >> 5)*SP_CS + (mm & 31)] *= rs;
    }
  }
  __syncthreads();
  // ---- PV via MFMA: wave w -> N-tile (w&1), k-tiles (w>>1)*16 .. +15 ------
  {
    int ntile = w & 1;
    int ktbase = (w >> 1) * 16;
    int vd = ntile*16 + m;              // output dim for B frag
    const unsigned short* vrow = vt + base_bh*32 + vd*1024;
    f32x4 acc = {0.0f, 0.0f, 0.0f, 0.0f};
    #pragma unroll
    for (int kt2 = 0; kt2 < 16; ++kt2) {
      int kt = ktbase + kt2;
      const float* pp = Sp + (lane & 7)*SP_RS + kt*SP_CS + quad*8;
      bf16x8s ap;
      #pragma unroll
      for (int j = 0; j < 8; ++j) ((unsigned short*)&ap)[j] = f2bf(pp[j]);
      bf16x8s bv = *(const bf16x8s*)(vrow + kt*32 + quad*8);
      acc = __builtin_amdgcn_mfma_f32_16x16x32_bf16(ap, bv, acc, 0, 0, 0);
    }
    if (lane < 32) {                    // real rows 0..7
      #pragma unroll
      for (int i = 0; i < 4; ++i)
        opart[w][quad*4 + i][m] = acc[i];
    }
  }
  __syncthreads();
  {
    int r = t >> 5, d = t & 31;
    int nt = d >> 4, c = d & 15;
    float sum = opart[nt][r][c] + opart[nt + 2][r][c];
    qq[(base_bh + n0 + r)*32 + d] = sum;   // o over q (own slots)
  }
}

extern "C" void kernel_launch(void* const* d_in, const int* in_sizes, int n_in,
                              void* d_out, int out_size, void* d_ws, size_t ws_size,
                              hipStream_t stream) {
  const void* x   = d_in[0];
  const void* src = d_in[1];
  const int* adj  = (const int*)d_in[2];
  const void* wg  = d_in[3];
  const void* a1  = d_in[4];
  const void* a2  = d_in[5];
  const void* lw  = d_in[6];
  const void* lb  = d_in[7];
  const void* ipw = d_in[8];
  const void* ipb = d_in[9];
  const void* opw = d_in[10];
  const void* opb = d_in[11];
  float* ws = (float*)d_ws;
  const unsigned short* wbf = (const unsigned short*)d_ws;
  int* flagp = (int*)(ws + FLAG_F);

  detect_kernel<<<1, 64, 0, stream>>>((const unsigned short*)x, flagp);
  prep_kernel<<<dim3(256, 7), 256, 0, stream>>>(wg, lw, ipw, opw, lb, ipb, opb,
                                                a1, a2, ws, flagp);
  whs_kernel<<<512, 256, 0, stream>>>(x, ws, flagp);
  attn1_kernel<<<1024, 256, 0, stream>>>(x, adj, ws, d_out, flagp);
  colstatsA_kernel<<<64, 256, 0, stream>>>(ws + B_OFF, ws + CS_OFF);
  colstatsB_kernel<<<4, 256, 0, stream>>>(ws + CS_OFF, ws + ST1_OFF);
  gemm_kernel<1,1,0><<<512, 256, 0, stream>>>(ws + B_OFF, wbf + 1*65536,
      ws + BIAS_OFF, ws + ST1_OFF, ws + C_OFF, flagp);
  colstatsA_kernel<<<64, 256, 0, stream>>>(ws + C_OFF, ws + CS_OFF);
  colstatsB_kernel<<<4, 256, 0, stream>>>(ws + CS_OFF, ws + ST2_OFF);
  gemm_kernel<1,0,2><<<512, 256, 0, stream>>>(ws + C_OFF, wbf + 2*65536,
      ws + BIAS_OFF + 256, ws + ST2_OFF, ws + A_OFF, flagp);   // Q fp32 hm
  gemm_kernel<1,0,3><<<512, 256, 0, stream>>>(ws + C_OFF, wbf + 3*65536,
      ws + BIAS_OFF + 512, ws + ST2_OFF, ws + B_OFF, flagp);   // K bf16 hm
  gemm_kernel<2,0,4><<<512, 256, 0, stream>>>(src, wbf + 4*65536,
      ws + BIAS_OFF + 768, nullptr, ws + C_OFF, flagp);        // V^T bf16 hm
  attn2_kernel<<<4096, 256, 0, stream>>>(ws);                  // o -> A_OFF
  gemm_kernel<3,0,1><<<512, 256, 0, stream>>>(ws + A_OFF, wbf + 5*65536,
      ws + BIAS_OFF + 1024, nullptr, d_out, flagp);            // out-proj
}

// Round 13
// 357.027 us; speedup vs baseline: 2.3712x; 1.0591x over previous
//
#include <hip/hip_runtime.h>
#include <hip/hip_bf16.h>

// B=4, N=1024, E=256, H=8, D=32. Float tensors may be bf16 OR fp32 in d_in /
// d_out (detected at runtime on-device); adj is int32.
// Output: x_out [4,1024,256] then e_out [4,1024,1024] (element offsets).
//
// ws float offsets:
//   [0 .. 196608)   : 6 weight matrices, transposed, bf16, quad-interleaved
//                     matrix m at ushort offset m*65536; element (e,o) at
//                     ((e>>2)*256 + o)*4 + (e&3).  m: 0=Wcat 1=LIN 2=WQ 3=WK 4=WV 5=WO
#define BIAS_OFF 196608   // lin_b, bq, bk, bv, bo, a1, a2  (7*256 fp32)
#define S1_OFF   198400   // [h][4096]
#define S2_OFF   231168
#define CS_OFF   263936   // 32768: column partial sums+sumsq (reused twice)
#define ST1_OFF  296704   // mean[1024] + inv[1024]
#define ST2_OFF  298752
#define A_OFF    300800   // WhT bf16 [h][b][d][n] (2 MB) -> later Q,o fp32 head-major
#define B_OFF    1349376  // 4 MB: rownorm(xa)     -> later K bf16 head-major [b][h][n][32]
#define C_OFF    2397952  // 4 MB: rownorm(lin)    -> later V^T bf16 head-major [b][h][d][n]
#define FLAG_F   3446528  // int: 1 = bf16 tensors, 0 = fp32 tensors
// end 3446529 floats = 13.8 MB

#define NEGC (-9.0e15f)

typedef __attribute__((ext_vector_type(8))) short bf16x8s;
typedef __attribute__((ext_vector_type(4))) float f32x4;

static __device__ __forceinline__ float bf2f(unsigned short u) {
  union { unsigned int i; float f; } v; v.i = ((unsigned int)u) << 16; return v.f;
}
static __device__ __forceinline__ unsigned short f2bf(float f) {
  union { float f; unsigned int u; } v; v.f = f;
  unsigned int r = (v.u + 0x7FFFu + ((v.u >> 16) & 1u)) >> 16;   // RNE
  return (unsigned short)r;
}
static __device__ __forceinline__ float ldin(const void* p, long i, int bf) {
  return bf ? bf2f(((const unsigned short*)p)[i]) : ((const float*)p)[i];
}
static __device__ __forceinline__ unsigned short rdbf(const void* p, long i, int bf) {
  if (bf) return ((const unsigned short*)p)[i];
  return f2bf(((const float*)p)[i]);
}
static __device__ __forceinline__ void stout(void* p, long i, float v, int bf) {
  if (bf) ((unsigned short*)p)[i] = f2bf(v);
  else    ((float*)p)[i] = v;
}

// ---------------- dtype detector -------------------------------------------
__global__ __launch_bounds__(64) void detect_kernel(const unsigned short* x, int* flag) {
  int lane = threadIdx.x;
  unsigned short u = x[2 * lane];
  int e = (u >> 7) & 0xFF;
  bool good = (e >= 100 && e <= 140);
  unsigned long long m = __ballot(good);
  if (lane == 0) *flag = (__popcll(m) >= 48) ? 1 : 0;
}

// ---------------- prep: weights -> transposed quad bf16; biases -> fp32 ----
__global__ __launch_bounds__(256) void prep_kernel(
    const void* wg, const void* lin_w, const void* inp_w, const void* out_w,
    const void* lin_b, const void* inp_b, const void* out_b,
    const void* a1, const void* a2, float* ws, const int* flagp) {
  const int bf = *flagp;
  unsigned short* wbf = (unsigned short*)ws;
  int t = threadIdx.x;
  int f = blockIdx.x;
  int m = blockIdx.y;
  int dst = m*65536 + ((f >> 2)*256 + t)*4 + (f & 3);
  if (m == 0) {
    int h = t >> 5, d = t & 31;
    wbf[dst] = rdbf(wg, h*8192 + f*32 + d, bf);
  } else if (m == 1) wbf[dst] = rdbf(lin_w, t*256 + f, bf);
  else if (m == 2)   wbf[dst] = rdbf(inp_w, t*256 + f, bf);
  else if (m == 3)   wbf[dst] = rdbf(inp_w, (256 + t)*256 + f, bf);
  else if (m == 4)   wbf[dst] = rdbf(inp_w, (512 + t)*256 + f, bf);
  else if (m == 5)   wbf[dst] = rdbf(out_w, t*256 + f, bf);
  else if (f == 0) {
    ws[BIAS_OFF + t]        = ldin(lin_b, t, bf);
    ws[BIAS_OFF + 256 + t]  = ldin(inp_b, t, bf);
    ws[BIAS_OFF + 512 + t]  = ldin(inp_b, 256 + t, bf);
    ws[BIAS_OFF + 768 + t]  = ldin(inp_b, 512 + t, bf);
    ws[BIAS_OFF + 1024 + t] = ldin(out_b, t, bf);
    ws[BIAS_OFF + 1280 + t] = ldin(a1, t, bf);
    ws[BIAS_OFF + 1536 + t] = ldin(a2, t, bf);
  }
}

// -------- Wh = x @ Wcat -> WhT bf16 [h][b][d][n]; s1/s2 head reductions ----
__global__ __launch_bounds__(256) void whs_kernel(const void* x, float* ws,
                                                  const int* flagp) {
  const int bf = *flagp;
  int t = threadIdx.x;
  int r0 = blockIdx.x * 8;
  __shared__ __align__(16) float U[8][256];
  #pragma unroll
  for (int r = 0; r < 8; ++r)
    U[r][t] = ldin(x, (long)(r0 + r)*256 + t, bf);
  __syncthreads();
  const ushort4* w4 = (const ushort4*)ws;
  float acc[8] = {0,0,0,0,0,0,0,0};
  for (int e4 = 0; e4 < 64; ++e4) {
    ushort4 u = w4[e4*256 + t];
    float w0 = bf2f(u.x), w1 = bf2f(u.y), w2 = bf2f(u.z), w3 = bf2f(u.w);
    #pragma unroll
    for (int r = 0; r < 8; ++r) {
      float4 uu = *(const float4*)&U[r][e4*4];
      acc[r] += uu.x*w0 + uu.y*w1 + uu.z*w2 + uu.w*w3;
    }
  }
  int h = t >> 5, d = t & 31;
  float a1v = ws[BIAS_OFF + 1280 + t];
  float a2v = ws[BIAS_OFF + 1536 + t];
  unsigned short wvals[8];
  #pragma unroll
  for (int r = 0; r < 8; ++r) {
    int row = r0 + r;
    wvals[r] = f2bf(acc[r]);
    float p1 = acc[r]*a1v, p2 = acc[r]*a2v;
    #pragma unroll
    for (int off = 16; off > 0; off >>= 1) {
      p1 += __shfl_xor(p1, off, 32);
      p2 += __shfl_xor(p2, off, 32);
    }
    if (d == 0) {
      ws[S1_OFF + h*4096 + row] = p1;
      ws[S2_OFF + h*4096 + row] = p2;
    }
  }
  // WhT[h][b][d][n], 8 contiguous n per thread (16B store)
  {
    unsigned short* wht = (unsigned short*)(ws + A_OFF);
    int bb = r0 >> 10, nn = r0 & 1023;
    *(bf16x8s*)(wht + ((long)((h*4 + bb)*32 + d))*1024 + nn) = *(bf16x8s*)wvals;
  }
}

// ------- graph attention + residual + fused rownorm; e_out = mean_h attn ---
// 1-D grid (1024), XCD-swizzled: low 3 bits = (b*2 + n0-parity).
// Scores+softmax register-resident (wave w owns row w); P stored bf16 in Pb;
// PV via mfma_f32_16x16x32_bf16 against WhT (attn2-proven layouts, 4 real
// rows dup x4). e_out accumulated in registers.
#define PB_S 1032    // Pb row stride (ushorts); 2064B = 129*16, rows +4 banks
__global__ __launch_bounds__(256) void attn1_kernel(const void* x, const int* adj,
                                                    float* ws, void* dout,
                                                    const int* flagp) {
  const int bf = *flagp;
  int t = threadIdx.x;
  int gid = blockIdx.x;
  int b = (gid >> 1) & 3;
  int n0 = ((((gid >> 3) << 1) | (gid & 1))) * 4;
  __shared__ float s2s[1024];
  __shared__ unsigned char adjm[4][1024];
  __shared__ float s1s[4];
  __shared__ __align__(16) unsigned short Pb[4][PB_S];
  __shared__ __align__(16) float opart[4][4][16];
  __shared__ __align__(16) float xrow[4][256];
  for (int r = 0; r < 4; ++r) {
    int base = (b*1024 + n0 + r) * 1024;
    for (int j = 0; j < 4; ++j) {
      int m = t + 256*j;
      adjm[r][m] = (adj[base + m] > 0) ? 1 : 0;
    }
  }
  int w = t >> 6, lane = t & 63;
  int fm = lane & 15, quad = lane >> 4;
  float eacc[16];
  #pragma unroll
  for (int j = 0; j < 16; ++j) eacc[j] = 0.0f;
  const unsigned short* wht = (const unsigned short*)(ws + A_OFF);
  for (int h = 0; h < 8; ++h) {
    const float* s2p = ws + S2_OFF + h*4096 + b*1024;
    for (int j = 0; j < 4; ++j) s2s[t + 256*j] = s2p[t + 256*j];
    if (t < 4) s1s[t] = ws[S1_OFF + h*4096 + b*1024 + n0 + t];
    __syncthreads();
    // scores + softmax in registers: wave w owns row w
    {
      float s1v = s1s[w];
      float p[16];
      float mx = -3.4e38f;
      #pragma unroll
      for (int j = 0; j < 16; ++j) {
        int m = lane + 64*j;
        float ev = s1v + s2s[m];
        ev = (ev >= 0.0f) ? ev : 0.1f*ev;
        ev = adjm[w][m] ? ev : NEGC;
        p[j] = ev;
        mx = fmaxf(mx, ev);
      }
      #pragma unroll
      for (int off = 32; off > 0; off >>= 1) mx = fmaxf(mx, __shfl_xor(mx, off));
      float s = 0.0f;
      #pragma unroll
      for (int j = 0; j < 16; ++j) { p[j] = __expf(p[j] - mx); s += p[j]; }
      #pragma unroll
      for (int off = 32; off > 0; off >>= 1) s += __shfl_xor(s, off);
      float rs = 1.0f / s;
      #pragma unroll
      for (int j = 0; j < 16; ++j) {
        float pv = p[j] * rs;
        Pb[w][lane + 64*j] = f2bf(pv);
        eacc[j] += 0.125f * pv;
      }
    }
    __syncthreads();
    // PV via MFMA: wave w -> ntile (w&1), k-tiles (w>>1)*16 .. +15
    {
      int ntile = w & 1;
      int ktbase = (w >> 1) * 16;
      int vd = ntile*16 + fm;
      const unsigned short* wrow = wht + ((long)((h*4 + b)*32 + vd))*1024;
      f32x4 acc = {0.0f, 0.0f, 0.0f, 0.0f};
      #pragma unroll
      for (int kt2 = 0; kt2 < 16; ++kt2) {
        int kt = ktbase + kt2;
        bf16x8s ap = *(const bf16x8s*)&Pb[fm & 3][kt*32 + quad*8];
        bf16x8s bw = *(const bf16x8s*)(wrow + kt*32 + quad*8);
        acc = __builtin_amdgcn_mfma_f32_16x16x32_bf16(ap, bw, acc, 0, 0, 0);
      }
      if (quad == 0) {            // D rows 0..3 are the real query rows
        #pragma unroll
        for (int i = 0; i < 4; ++i) opart[w][i][fm] = acc[i];
      }
    }
    __syncthreads();
    if (t < 128) {
      int r = t >> 5, dd = t & 31;
      int nt = dd >> 4, c = dd & 15;
      float sum = opart[nt][r][c] + opart[nt + 2][r][c];
      float hv = (sum >= 0.0f) ? sum : 0.01f*sum;
      long idx = (long)(b*1024 + n0 + r)*256 + h*32 + dd;
      xrow[r][h*32 + dd] = ldin(x, idx, bf) + hv;
    }
    __syncthreads();
  }
  // fused rownorm (ddof=1): wave w handles row w
  float vals[4]; float s = 0.0f;
  #pragma unroll
  for (int j = 0; j < 4; ++j) { vals[j] = xrow[w][lane + 64*j]; s += vals[j]; }
  #pragma unroll
  for (int off = 32; off > 0; off >>= 1) s += __shfl_xor(s, off);
  float mean = s * (1.0f/256.0f);
  float ss = 0.0f;
  #pragma unroll
  for (int j = 0; j < 4; ++j) { float d = vals[j] - mean; ss += d*d; }
  #pragma unroll
  for (int off = 32; off > 0; off >>= 1) ss += __shfl_xor(ss, off);
  float inv = 1.0f / (sqrtf(ss * (1.0f/255.0f)) + 1e-6f);
  float* Bp = ws + B_OFF + (b*1024 + n0 + w)*256;
  #pragma unroll
  for (int j = 0; j < 4; ++j) Bp[lane + 64*j] = (vals[j] - mean) * inv;
  // e_out: wave w writes row w from registers
  {
    long base = 1048576L + (long)(b*1024 + n0 + w)*1024;
    #pragma unroll
    for (int j = 0; j < 16; ++j)
      stout(dout, base + lane + 64*j, eacc[j], bf);
  }
}

// ---------------- column (axis=1) stats, ddof=1 ----------------------------
__global__ __launch_bounds__(256) void colstatsA_kernel(const float* in, float* cs) {
  int t = threadIdx.x;
  int j = blockIdx.x & 15;
  int b = blockIdx.x >> 4;
  float s = 0, ss = 0;
  for (int n = j*64; n < j*64 + 64; ++n) {
    float v = in[(b*1024 + n)*256 + t];
    s += v; ss += v*v;
  }
  cs[(b*16 + j)*256 + t] = s;
  cs[16384 + (b*16 + j)*256 + t] = ss;
}

__global__ __launch_bounds__(256) void colstatsB_kernel(const float* cs, float* st) {
  int t = threadIdx.x;
  int b = blockIdx.x;
  float s = 0, ss = 0;
  for (int j = 0; j < 16; ++j) {
    s  += cs[(b*16 + j)*256 + t];
    ss += cs[16384 + (b*16 + j)*256 + t];
  }
  float mean = s * (1.0f/1024.0f);
  float var = fmaxf((ss - s*mean) * (1.0f/1023.0f), 0.0f);
  st[b*256 + t] = mean;
  st[1024 + b*256 + t] = 1.0f / (sqrtf(var) + 1e-6f);
}

// ---------------- row GEMM, bf16 quad weights ------------------------------
// IN_MODE 0: plain fp32 [row][256]; 1: fp32 + colnorm(st); 2: float-input src
//   permuted (n,b,e)->(b,n,e); 3: fp32 head-major [b][h][n][32]
// RN 1: fused rownorm on output
// OUTM 0: fp32 [row][256]; 1: d_out (dtype per flag); 2: fp32 head-major;
//      3: bf16 head-major; 4: bf16 TRANSPOSED head-major [b][h][d][n]
template<int IN_MODE, int RN, int OUTM>
__global__ __launch_bounds__(256) void gemm_kernel(const void* inp,
    const unsigned short* wmat, const float* bias, const float* st, void* outp,
    const int* flagp) {
  const int bf = *flagp;
  int t = threadIdx.x;
  int r0 = blockIdx.x * 8;
  __shared__ __align__(16) float U[8][256];
  #pragma unroll
  for (int r = 0; r < 8; ++r) {
    int row = r0 + r;
    float v;
    if (IN_MODE == 0) {
      v = ((const float*)inp)[row*256 + t];
    } else if (IN_MODE == 1) {
      int b = row >> 10;
      v = (((const float*)inp)[row*256 + t] - st[b*256 + t]) * st[1024 + b*256 + t];
    } else if (IN_MODE == 2) {
      int b = row >> 10, n = row & 1023;
      v = ldin(inp, (long)(n*4 + b)*256 + t, bf);
    } else {
      int b = row >> 10, n = row & 1023;
      v = ((const float*)inp)[((b*8 + (t >> 5))*1024 + n)*32 + (t & 31)];
    }
    U[r][t] = v;
  }
  __syncthreads();
  float bv = bias[t];
  float acc[8];
  #pragma unroll
  for (int r = 0; r < 8; ++r) acc[r] = bv;
  const ushort4* w4 = (const ushort4*)wmat;
  for (int e4 = 0; e4 < 64; ++e4) {
    ushort4 u = w4[e4*256 + t];
    float w0 = bf2f(u.x), w1 = bf2f(u.y), w2 = bf2f(u.z), w3 = bf2f(u.w);
    #pragma unroll
    for (int r = 0; r < 8; ++r) {
      float4 uu = *(const float4*)&U[r][e4*4];
      acc[r] += uu.x*w0 + uu.y*w1 + uu.z*w2 + uu.w*w3;
    }
  }
  if (RN == 0) {
    #pragma unroll
    for (int r = 0; r < 8; ++r) {
      int row = r0 + r;
      if (OUTM == 0) ((float*)outp)[row*256 + t] = acc[r];
      else if (OUTM == 1) stout(outp, (long)row*256 + t, acc[r], bf);
      else if (OUTM == 2) {
        int b = row >> 10, n = row & 1023;
        ((float*)outp)[((b*8 + (t >> 5))*1024 + n)*32 + (t & 31)] = acc[r];
      } else if (OUTM == 3) {
        int b = row >> 10, n = row & 1023;
        ((unsigned short*)outp)[((b*8 + (t >> 5))*1024 + n)*32 + (t & 31)] = f2bf(acc[r]);
      } else {
        int b = row >> 10, n = row & 1023;
        ((unsigned short*)outp)[((b*8 + (t >> 5))*32 + (t & 31))*1024 + n] = f2bf(acc[r]);
      }
    }
  } else {
    __syncthreads();
    #pragma unroll
    for (int r = 0; r < 8; ++r) U[r][t] = acc[r];
    __syncthreads();
    int w = t >> 6, lane = t & 63;
    for (int rr = w; rr < 8; rr += 4) {
      float vals[4]; float s = 0.0f;
      #pragma unroll
      for (int j = 0; j < 4; ++j) { vals[j] = U[rr][lane + 64*j]; s += vals[j]; }
      #pragma unroll
      for (int off = 32; off > 0; off >>= 1) s += __shfl_xor(s, off);
      float mean = s * (1.0f/256.0f);
      float ss = 0.0f;
      #pragma unroll
      for (int j = 0; j < 4; ++j) { float d = vals[j] - mean; ss += d*d; }
      #pragma unroll
      for (int off = 32; off > 0; off >>= 1) ss += __shfl_xor(ss, off);
      float inv = 1.0f / (sqrtf(ss * (1.0f/255.0f)) + 1e-6f);
      #pragma unroll
      for (int j = 0; j < 4; ++j)
        ((float*)outp)[(r0 + rr)*256 + lane + 64*j] = (vals[j] - mean) * inv;
    }
  }
}

// ---------------- MHA via MFMA, bf16 K/V, 8 q-rows per block ---------------
// GRID MUST BE 4096: 128 row-groups x 4 b x 8 h. h in low 3 bits (XCD-L2).
// Q fp32 head-major [b][h][n][32] at A_OFF (o overwrites q, exclusive slots);
// K bf16 [b][h][n][32] at B_OFF; V^T bf16 [b][h][d][n] at C_OFF.
// mfma_f32_16x16x32_bf16 layouts (m89-verified):
//   A[m=lane&15][k=(lane>>4)*8+j]; B[k=(lane>>4)*8+j][n=lane&15];
//   D col=lane&15, row=(lane>>4)*4+i.
#define SP_CS 36
#define SP_RS 1156
__global__ __launch_bounds__(256) void attn2_kernel(float* ws) {
  int t = threadIdx.x;
  int gid = blockIdx.x;
  int h = gid & 7;
  int b = (gid >> 3) & 3;
  int n0 = (gid >> 5) << 3;   // 8 q-rows per block; gid>>5 in 0..127
  __shared__ __align__(16) float Sp[8*SP_RS];
  __shared__ __align__(16) float opart[4][8][16];
  float* qq = ws + A_OFF;
  const unsigned short* kk = (const unsigned short*)(ws + B_OFF);
  const unsigned short* vt = (const unsigned short*)(ws + C_OFF);
  int base_bh = (b*8 + h)*1024;
  int w = t >> 6, lane = t & 63;
  int m = lane & 15, quad = lane >> 4;
  const float scl = 0.17677669529663687f; // 1/sqrt(32)
  // ---- QK via MFMA: wave w covers keys w*256 .. +255 ----------------------
  {
    const float* qp = qq + (base_bh + n0 + (lane & 7))*32 + quad*8;
    bf16x8s aq;
    #pragma unroll
    for (int j = 0; j < 8; ++j) ((unsigned short*)&aq)[j] = f2bf(qp[j]);
    f32x4 zero = {0.0f, 0.0f, 0.0f, 0.0f};
    #pragma unroll
    for (int kt = 0; kt < 16; ++kt) {
      int kbase = w*256 + kt*16;
      bf16x8s bk = *(const bf16x8s*)(kk + (base_bh + kbase + m)*32 + quad*8);
      f32x4 d = __builtin_amdgcn_mfma_f32_16x16x32_bf16(aq, bk, zero, 0, 0, 0);
      if (lane < 32) {
        int key = kbase + m;
        int a = (key >> 5)*SP_CS + (key & 31);
        #pragma unroll
        for (int i = 0; i < 4; ++i)
          Sp[(quad*4 + i)*SP_RS + a] = d[i] * scl;
      }
    }
  }
  __syncthreads();
  // ---- softmax: wave w handles rows w and w+4 -----------------------------
  #pragma unroll
  for (int rr = 0; rr < 2; ++rr) {
    float* Sr = Sp + (w + 4*rr)*SP_RS;
    float mx = -3.4e38f;
    #pragma unroll
    for (int j = 0; j < 16; ++j) {
      int mm = lane + 64*j;
      mx = fmaxf(mx, Sr[(mm >> 5)*SP_CS + (mm & 31)]);
    }
    #pragma unroll
    for (int off = 32; off > 0; off >>= 1) mx = fmaxf(mx, __shfl_xor(mx, off));
    float s = 0.0f;
    #pragma unroll
    for (int j = 0; j < 16; ++j) {
      int mm = lane + 64*j;
      int a = (mm >> 5)*SP_CS + (mm & 31);
      float p = __expf(Sr[a] - mx);
      Sr[a] = p;
      s += p;
    }
    #pragma unroll
    for (int off = 32; off > 0; off >>= 1) s += __shfl_xor(s, off);
    float rs = 1.0f / s;
    #pragma unroll
    for (int j = 0; j < 16; ++j) {
      int mm = lane + 64*j;
      Sr[(mm >> 5)*SP_CS + (mm & 31)] *= rs;
    }
  }
  __syncthreads();
  // ---- PV via MFMA: wave w -> N-tile (w&1), k-tiles (w>>1)*16 .. +15 ------
  {
    int ntile = w & 1;
    int ktbase = (w >> 1) * 16;
    int vd = ntile*16 + m;
    const unsigned short* vrow = vt + base_bh*32 + vd*1024;
    f32x4 acc = {0.0f, 0.0f, 0.0f, 0.0f};
    #pragma unroll
    for (int kt2 = 0; kt2 < 16; ++kt2) {
      int kt = ktbase + kt2;
      const float* pp = Sp + (lane & 7)*SP_RS + kt*SP_CS + quad*8;
      bf16x8s ap;
      #pragma unroll
      for (int j = 0; j < 8; ++j) ((unsigned short*)&ap)[j] = f2bf(pp[j]);
      bf16x8s bv = *(const bf16x8s*)(vrow + kt*32 + quad*8);
      acc = __builtin_amdgcn_mfma_f32_16x16x32_bf16(ap, bv, acc, 0, 0, 0);
    }
    if (lane < 32) {
      #pragma unroll
      for (int i = 0; i < 4; ++i)
        opart[w][quad*4 + i][m] = acc[i];
    }
  }
  __syncthreads();
  {
    int r = t >> 5, d = t & 31;
    int nt = d >> 4, c = d & 15;
    float sum = opart[nt][r][c] + opart[nt + 2][r][c];
    qq[(base_bh + n0 + r)*32 + d] = sum;   // o over q (own slots)
  }
}

extern "C" void kernel_launch(void* const* d_in, const int* in_sizes, int n_in,
                              void* d_out, int out_size, void* d_ws, size_t ws_size,
                              hipStream_t stream) {
  const void* x   = d_in[0];
  const void* src = d_in[1];
  const int* adj  = (const int*)d_in[2];
  const void* wg  = d_in[3];
  const void* a1  = d_in[4];
  const void* a2  = d_in[5];
  const void* lw  = d_in[6];
  const void* lb  = d_in[7];
  const void* ipw = d_in[8];
  const void* ipb = d_in[9];
  const void* opw = d_in[10];
  const void* opb = d_in[11];
  float* ws = (float*)d_ws;
  const unsigned short* wbf = (const unsigned short*)d_ws;
  int* flagp = (int*)(ws + FLAG_F);

  detect_kernel<<<1, 64, 0, stream>>>((const unsigned short*)x, flagp);
  prep_kernel<<<dim3(256, 7), 256, 0, stream>>>(wg, lw, ipw, opw, lb, ipb, opb,
                                                a1, a2, ws, flagp);
  whs_kernel<<<512, 256, 0, stream>>>(x, ws, flagp);
  attn1_kernel<<<1024, 256, 0, stream>>>(x, adj, ws, d_out, flagp);
  colstatsA_kernel<<<64, 256, 0, stream>>>(ws + B_OFF, ws + CS_OFF);
  colstatsB_kernel<<<4, 256, 0, stream>>>(ws + CS_OFF, ws + ST1_OFF);
  gemm_kernel<1,1,0><<<512, 256, 0, stream>>>(ws + B_OFF, wbf + 1*65536,
      ws + BIAS_OFF, ws + ST1_OFF, ws + C_OFF, flagp);
  colstatsA_kernel<<<64, 256, 0, stream>>>(ws + C_OFF, ws + CS_OFF);
  colstatsB_kernel<<<4, 256, 0, stream>>>(ws + CS_OFF, ws + ST2_OFF);
  gemm_kernel<1,0,2><<<512, 256, 0, stream>>>(ws + C_OFF, wbf + 2*65536,
      ws + BIAS_OFF + 256, ws + ST2_OFF, ws + A_OFF, flagp);   // Q fp32 hm
  gemm_kernel<1,0,3><<<512, 256, 0, stream>>>(ws + C_OFF, wbf + 3*65536,
      ws + BIAS_OFF + 512, ws + ST2_OFF, ws + B_OFF, flagp);   // K bf16 hm
  gemm_kernel<2,0,4><<<512, 256, 0, stream>>>(src, wbf + 4*65536,
      ws + BIAS_OFF + 768, nullptr, ws + C_OFF, flagp);        // V^T bf16 hm
  attn2_kernel<<<4096, 256, 0, stream>>>(ws);                  // o -> A_OFF
  gemm_kernel<3,0,1><<<512, 256, 0, stream>>>(ws + A_OFF, wbf + 5*65536,
      ws + BIAS_OFF + 1024, nullptr, d_out, flagp);            // out-proj
}